// Round 1
// baseline (1193.186 us; speedup 1.0000x reference)
//
#include <hip/hip_runtime.h>
#include <hip/hip_bf16.h>
#include <math.h>

// Problem dims (fixed by setup_inputs)
#define Bz 4
#define Nn 1024
#define Cc 768
#define Hh 12
#define Dd 64
#define Pp 5
#define BN 4096          // B*N
#define NC 16            // chunks per sequence
#define BH 48            // B*H
#define OUT_ELEMS 3145728  // BN*C

// ---------------- workspace layout (floats) ----------------
#define WS_QKV     0u
#define WS_IDOUT   9437184u
#define WS_HDN     12582912u
#define WS_PL      15728640u
#define WS_IG      15974400u
#define WS_GL      16023552u
#define WS_QS      16072704u
#define WS_KNT     19218432u
#define WS_U       22364160u
#define WS_W       25509888u
#define WS_AT      28655616u
#define WS_DELTA   31801344u
#define WS_CTX     34947072u
#define WS_ENT     38092800u

__device__ __forceinline__ float sigmoidf_(float x) { return 1.f / (1.f + __expf(-x)); }
__device__ __forceinline__ float geluf_(float x) {
    float t = tanhf(0.7978845608028654f * (x + 0.044715f * x * x * x));
    return 0.5f * x * (1.f + t);
}

// ---------------- generic tiled f32 GEMM: C = act(A@B + bias) ----------------
// A [M,K] rowmajor, B [K,N] rowmajor. BM=128, BN=64, BK=16, 256 threads, 8x4/thread.
__global__ __launch_bounds__(256) void gemm_kernel(const float* __restrict__ A,
        const float* __restrict__ Bm, const float* __restrict__ bias,
        float* __restrict__ Cm, int M, int K, int N, int act) {
    __shared__ float As[16][128];
    __shared__ float Bs[16][68];
    const int tid = threadIdx.x;
    const int tm = tid >> 4, tn = tid & 15;
    const int row0 = blockIdx.y * 128, col0 = blockIdx.x * 64;
    float acc[8][4];
#pragma unroll
    for (int i = 0; i < 8; ++i)
#pragma unroll
        for (int j = 0; j < 4; ++j) acc[i][j] = 0.f;

    for (int k0 = 0; k0 < K; k0 += 16) {
        // A tile: 128x16 = 512 float4
#pragma unroll
        for (int f = tid; f < 512; f += 256) {
            int r = f >> 2, kq = (f & 3) * 4;
            const float4 a = *(const float4*)&A[(size_t)(row0 + r) * K + k0 + kq];
            As[kq + 0][r] = a.x; As[kq + 1][r] = a.y;
            As[kq + 2][r] = a.z; As[kq + 3][r] = a.w;
        }
        // B tile: 16x64 = 256 float4
        {
            int kk = tid >> 4, nq = (tid & 15) * 4;
            int col = col0 + nq;
            float4 b4;
            if (col + 3 < N) {
                b4 = *(const float4*)&Bm[(size_t)(k0 + kk) * N + col];
            } else {
                b4.x = (col + 0 < N) ? Bm[(size_t)(k0 + kk) * N + col + 0] : 0.f;
                b4.y = (col + 1 < N) ? Bm[(size_t)(k0 + kk) * N + col + 1] : 0.f;
                b4.z = (col + 2 < N) ? Bm[(size_t)(k0 + kk) * N + col + 2] : 0.f;
                b4.w = (col + 3 < N) ? Bm[(size_t)(k0 + kk) * N + col + 3] : 0.f;
            }
            *(float4*)&Bs[kk][nq] = b4;
        }
        __syncthreads();
#pragma unroll
        for (int kk = 0; kk < 16; ++kk) {
            float a[8], b[4];
            *(float4*)&a[0] = *(const float4*)&As[kk][tm * 8];
            *(float4*)&a[4] = *(const float4*)&As[kk][tm * 8 + 4];
            *(float4*)&b[0] = *(const float4*)&Bs[kk][tn * 4];
#pragma unroll
            for (int i = 0; i < 8; ++i)
#pragma unroll
                for (int j = 0; j < 4; ++j) acc[i][j] += a[i] * b[j];
        }
        __syncthreads();
    }
    // epilogue
#pragma unroll
    for (int i = 0; i < 8; ++i) {
        int r = row0 + tm * 8 + i;
        int cc0 = col0 + tn * 4;
        float v[4];
#pragma unroll
        for (int j = 0; j < 4; ++j) {
            v[j] = acc[i][j] + ((bias && cc0 + j < N) ? bias[cc0 + j] : 0.f);
            if (act == 1) v[j] = geluf_(v[j]);
        }
        if (cc0 + 3 < N) {
            float4 o; o.x = v[0]; o.y = v[1]; o.z = v[2]; o.w = v[3];
            *(float4*)&Cm[(size_t)r * N + cc0] = o;
        } else {
#pragma unroll
            for (int j = 0; j < 4; ++j)
                if (cc0 + j < N) Cm[(size_t)r * N + cc0 + j] = v[j];
        }
    }
}

// ---------------- delta-rule preprocessing: per (b,h,chunk) ----------------
// Computes Qs (scaled q), KnT (normalized k transposed), W=T@Kn, U=T@V,
// At=tril(Q Kn^T), where T=(I+tril(Kn Kn^T,-1))^{-1}.
__global__ __launch_bounds__(256) void pre_kernel(const float* __restrict__ qkv,
        float* __restrict__ Qs, float* __restrict__ KnT, float* __restrict__ U,
        float* __restrict__ W, float* __restrict__ At) {
    __shared__ float ks[64][64];   // normalized k rows
    __shared__ float kst[64][64];  // k transposed, XOR-swizzled: (d,r) at kst[d][r^(d&31)]
    __shared__ float ts[64][64];   // A then T (row 0 temporarily holds inv norms)
    __shared__ float xs[64][64];   // q (scaled), later v
    const int blk = blockIdx.x;
    const int c = blk & 15, bh = blk >> 4;
    const int b = bh / Hh, h = bh % Hh;
    const int tid = threadIdx.x;
    const size_t rowbase = ((size_t)(b * Nn + c * 64)) * (3 * Cc) + h * 64;
    const size_t base2 = (size_t)blk * 4096;

    // load q (scaled by D^-0.5) and raw k
    for (int e4 = tid; e4 < 1024; e4 += 256) {
        int r = e4 >> 4, d4 = (e4 & 15) * 4;
        const float4 qv = *(const float4*)&qkv[rowbase + (size_t)r * 2304 + d4];
        const float4 kv = *(const float4*)&qkv[rowbase + (size_t)r * 2304 + 768 + d4];
        xs[r][d4 + 0] = qv.x * 0.125f; xs[r][d4 + 1] = qv.y * 0.125f;
        xs[r][d4 + 2] = qv.z * 0.125f; xs[r][d4 + 3] = qv.w * 0.125f;
        ks[r][d4 + 0] = kv.x; ks[r][d4 + 1] = kv.y;
        ks[r][d4 + 2] = kv.z; ks[r][d4 + 3] = kv.w;
    }
    __syncthreads();
    // transpose raw k into swizzled kst
    for (int e = tid; e < 4096; e += 256) {
        int r = e >> 6, d = e & 63;
        kst[d][r ^ (d & 31)] = ks[r][d];
    }
    __syncthreads();
    float* inv = &ts[0][0];  // ts unused until A step; reuse row 0 for inv norms
    if (tid < 64) {
        int r = tid;
        float s = 0.f;
        for (int d = 0; d < 64; ++d) { float kk = kst[d][r ^ (d & 31)]; s += kk * kk; }
        inv[r] = 1.f / (sqrtf(s) + 1e-6f);
    }
    __syncthreads();
    // scale ks in place; write Qs
    for (int e = tid; e < 4096; e += 256) {
        int r = e >> 6, d = e & 63;
        ks[r][d] *= inv[r];
        Qs[base2 + e] = xs[r][d];
    }
    // scale kst in place; write KnT (layout [d][r])
    for (int e = tid; e < 4096; e += 256) {
        int dd = e >> 6, rr = e & 63;
        float v = kst[dd][rr ^ (dd & 31)] * inv[rr];
        kst[dd][rr ^ (dd & 31)] = v;
        KnT[base2 + e] = v;
    }
    __syncthreads();
    // A = tril(Kn Kn^T, -1) into ts
    for (int e = tid; e < 4096; e += 256) {
        int i = e >> 6, j = e & 63;
        float s = 0.f;
        if (j < i) {
            for (int d = 0; d < 64; ++d) s += ks[i][d] * kst[d][j ^ (d & 31)];
        }
        ts[i][j] = s;
    }
    __syncthreads();
    // T = (I+A)^{-1} via forward substitution, in place.
    // Upper triangle of converted rows is 0, so full m-loop is safe for all j.
    for (int i = 0; i < 64; ++i) {
        float val = 0.f;
        if (tid < 64) {
            int j = tid;
            float s = 0.f;
            for (int m = 0; m < i; ++m) s += ts[i][m] * ts[m][j];
            val = ((j == i) ? 1.f : 0.f) - s;
        }
        __syncthreads();
        if (tid < 64) ts[i][tid] = val;
        __syncthreads();
    }
    // W = T @ Kn ; At = tril(Q Kn^T)
    for (int e = tid; e < 4096; e += 256) {
        int r = e >> 6, j = e & 63;
        float sw = 0.f;
        for (int m = 0; m <= r; ++m) sw += ts[r][m] * ks[m][j];
        W[base2 + e] = sw;
        float sa = 0.f;
        if (j <= r) {
            for (int d = 0; d < 64; ++d) sa += xs[r][d] * kst[d][j ^ (d & 31)];
        }
        At[base2 + e] = sa;
    }
    __syncthreads();
    // reload v into xs, then U = T @ V
    for (int e4 = tid; e4 < 1024; e4 += 256) {
        int r = e4 >> 4, d4 = (e4 & 15) * 4;
        const float4 vv = *(const float4*)&qkv[rowbase + (size_t)r * 2304 + 1536 + d4];
        xs[r][d4 + 0] = vv.x; xs[r][d4 + 1] = vv.y;
        xs[r][d4 + 2] = vv.z; xs[r][d4 + 3] = vv.w;
    }
    __syncthreads();
    for (int e = tid; e < 4096; e += 256) {
        int r = e >> 6, j = e & 63;
        float su = 0.f;
        for (int m = 0; m <= r; ++m) su += ts[r][m] * xs[m][j];
        U[base2 + e] = su;
    }
}

// ---------------- sequential chunk scan, split over 16 value-dims per block ----
__global__ __launch_bounds__(256) void scan_kernel(const float* __restrict__ Qs,
        const float* __restrict__ KnT, const float* __restrict__ U,
        const float* __restrict__ W, const float* __restrict__ At,
        float* __restrict__ delta) {
    __shared__ float t0[64][68];
    __shared__ float t1[64][68];
    __shared__ float S[64][16];
    __shared__ float ut[64][16];
    const int bh = blockIdx.x;
    const int b = bh / Hh, h = bh % Hh;
    const int g0 = blockIdx.y * 16;
    const int tid = threadIdx.x;
    const int r = tid >> 2, dq = (tid & 3) * 4;
    for (int e = tid; e < 1024; e += 256) ((float*)S)[e] = 0.f;
    __syncthreads();
    for (int c = 0; c < 16; ++c) {
        const size_t base = ((size_t)(bh * 16 + c)) * 4096;
        for (int e4 = tid; e4 < 1024; e4 += 256) {
            int rr = e4 >> 4, d4 = (e4 & 15) * 4;
            *(float4*)&t0[rr][d4] = *(const float4*)&W[base + rr * 64 + d4];
            *(float4*)&t1[rr][d4] = *(const float4*)&Qs[base + rr * 64 + d4];
        }
        const float4 uv = *(const float4*)&U[base + r * 64 + g0 + dq];
        __syncthreads();
        // phase A: ut = u - w@S ; o1 = q@S   (old S)
        float4 o1 = make_float4(0.f, 0.f, 0.f, 0.f);
        float4 utv = uv;
#pragma unroll 4
        for (int m = 0; m < 64; m += 4) {
            float wv[4], qv[4];
            *(float4*)&wv[0] = *(const float4*)&t0[r][m];
            *(float4*)&qv[0] = *(const float4*)&t1[r][m];
#pragma unroll
            for (int mm = 0; mm < 4; ++mm) {
                const float4 sv = *(const float4*)&S[m + mm][dq];
                utv.x -= wv[mm] * sv.x; utv.y -= wv[mm] * sv.y;
                utv.z -= wv[mm] * sv.z; utv.w -= wv[mm] * sv.w;
                o1.x += qv[mm] * sv.x; o1.y += qv[mm] * sv.y;
                o1.z += qv[mm] * sv.z; o1.w += qv[mm] * sv.w;
            }
        }
        *(float4*)&ut[r][dq] = utv;
        __syncthreads();
        for (int e4 = tid; e4 < 1024; e4 += 256) {
            int rr = e4 >> 4, d4 = (e4 & 15) * 4;
            *(float4*)&t0[rr][d4] = *(const float4*)&At[base + rr * 64 + d4];
            *(float4*)&t1[rr][d4] = *(const float4*)&KnT[base + rr * 64 + d4];
        }
        __syncthreads();
        // phase B: o = o1 + attn@ut ; S += k^T@ut
        float4 o2 = o1;
        float4 sacc = *(const float4*)&S[r][dq];
#pragma unroll 4
        for (int m = 0; m < 64; m += 4) {
            float av[4], kv[4];
            *(float4*)&av[0] = *(const float4*)&t0[r][m];
            *(float4*)&kv[0] = *(const float4*)&t1[r][m];
#pragma unroll
            for (int mm = 0; mm < 4; ++mm) {
                const float4 uvm = *(const float4*)&ut[m + mm][dq];
                o2.x += av[mm] * uvm.x; o2.y += av[mm] * uvm.y;
                o2.z += av[mm] * uvm.z; o2.w += av[mm] * uvm.w;
                sacc.x += kv[mm] * uvm.x; sacc.y += kv[mm] * uvm.y;
                sacc.z += kv[mm] * uvm.z; sacc.w += kv[mm] * uvm.w;
            }
        }
        *(float4*)&S[r][dq] = sacc;
        const size_t orow = ((size_t)(b * Nn + c * 64 + r)) * Cc + h * 64 + g0 + dq;
        *(float4*)&delta[orow] = o2;
        __syncthreads();
    }
}

// ---------------- FIR + head-mix + prune softmax + gates + entropies ----------
__global__ __launch_bounds__(256) void paths_kernel(const float* __restrict__ qkv,
        const float* __restrict__ delta, const float* __restrict__ idout,
        const float* __restrict__ pl, const float* __restrict__ ig,
        const float* __restrict__ gl, const float* __restrict__ firs,
        const float* __restrict__ firl, const float* __restrict__ mixw,
        const float* __restrict__ idst, float* __restrict__ context,
        float* __restrict__ ent_acc) {
    __shared__ float fs[768], fl[768], vrow[768];
    __shared__ float wts_s[60], gate_s[12], idg_s[12], e1_s[12], e2_s[12];
    const int bn = blockIdx.x;
    const int b = bn >> 10, n = bn & 1023;
    const int tid = threadIdx.x;
#pragma unroll
    for (int e = tid; e < 768; e += 256) {
        float acc_s = 0.f, acc_l = 0.f, vv = 0.f;
        const float* wl = &firl[e * 7];
        const float* ws = &firs[e * 3];
#pragma unroll
        for (int t = 0; t < 7; ++t) {
            int np = n + t - 6;
            if (np >= 0) {
                float v = qkv[((size_t)(b * Nn + np)) * 2304 + 1536 + e];
                acc_l += wl[t] * v;
                if (t >= 4) acc_s += ws[t - 4] * v;
                if (t == 6) vv = v;
            }
        }
        fs[e] = acc_s; fl[e] = acc_l; vrow[e] = vv;
    }
    if (tid < 12) {
        int h = tid;
        float lg[5]; float mx = -1e30f;
#pragma unroll
        for (int p = 0; p < 5; ++p) { lg[p] = pl[(size_t)bn * 60 + h * 5 + p]; mx = fmaxf(mx, lg[p]); }
        float sum = 0.f;
#pragma unroll
        for (int p = 0; p < 5; ++p) { lg[p] = __expf(lg[p] - mx); sum += lg[p]; }
        float e1 = 0.f;
#pragma unroll
        for (int p = 0; p < 5; ++p) {
            float wv = lg[p] / sum;
            wts_s[h * 5 + p] = wv;
            e1 += wv * logf(wv + 1e-8f);
        }
        e1_s[h] = e1;
        float g = sigmoidf_(gl[(size_t)bn * 12 + h]);
        gate_s[h] = g;
        e2_s[h] = g * logf(g + 1e-8f) + (1.f - g) * logf(1.f - g + 1e-8f);
        idg_s[h] = sigmoidf_(ig[(size_t)bn * 12 + h]) * sigmoidf_(idst[h]);
    }
    __syncthreads();
#pragma unroll
    for (int e = tid; e < 768; e += 256) {
        int h = e >> 6, d = e & 63;
        float ms = fs[e], ml = fl[e];
#pragma unroll
        for (int hh = 0; hh < 12; ++hh) {
            float mw = mixw[hh * 12 + h];
            ms += fs[hh * 64 + d] * mw;
            ml += fl[hh * 64 + d] * mw;
        }
        float dl = delta[(size_t)bn * 768 + e];
        float vv = vrow[e];
        float idv = idout[(size_t)bn * 768 + e] * idg_s[h];
        const float* wp = &wts_s[h * 5];
        float pr = ms * wp[0] + ml * wp[1] + dl * wp[2] + vv * wp[3] + idv * wp[4];
        context[(size_t)bn * 768 + e] = pr * gate_s[h];
    }
    if (tid == 0) {
        float s1 = 0.f, s2 = 0.f;
#pragma unroll
        for (int h = 0; h < 12; ++h) { s1 += e1_s[h]; s2 += e2_s[h]; }
        atomicAdd(&ent_acc[0], s1);
        atomicAdd(&ent_acc[1], s2);
    }
}

__global__ void finalize_kernel(const float* __restrict__ ent_acc, float* __restrict__ out) {
    out[OUT_ELEMS] = -(ent_acc[0] + ent_acc[1]) * (1.f / 49152.f);
}

extern "C" void kernel_launch(void* const* d_in, const int* in_sizes, int n_in,
                              void* d_out, int out_size, void* d_ws, size_t ws_size,
                              hipStream_t stream) {
    const float* x        = (const float*)d_in[0];
    const float* w_qkv    = (const float*)d_in[1];
    const float* w_proj   = (const float*)d_in[2];
    const float* b_proj   = (const float*)d_in[3];
    const float* fir_s_w  = (const float*)d_in[4];
    const float* fir_l_w  = (const float*)d_in[5];
    const float* mixw     = (const float*)d_in[6];
    const float* w_prune  = (const float*)d_in[7];
    const float* b_prune  = (const float*)d_in[8];
    const float* w_g1     = (const float*)d_in[9];
    const float* b_g1     = (const float*)d_in[10];
    const float* w_g2     = (const float*)d_in[11];
    const float* b_g2     = (const float*)d_in[12];
    const float* w_id     = (const float*)d_in[13];
    const float* id_st    = (const float*)d_in[14];
    const float* w_idgate = (const float*)d_in[15];
    const float* b_idgate = (const float*)d_in[16];
    float* out = (float*)d_out;
    float* ws  = (float*)d_ws;

    float* qkv   = ws + WS_QKV;
    float* idout = ws + WS_IDOUT;
    float* hdn   = ws + WS_HDN;
    float* pl    = ws + WS_PL;
    float* ig    = ws + WS_IG;
    float* gl    = ws + WS_GL;
    float* Qs    = ws + WS_QS;
    float* KnT   = ws + WS_KNT;
    float* Ub    = ws + WS_U;
    float* Wb    = ws + WS_W;
    float* Atb   = ws + WS_AT;
    float* delta = ws + WS_DELTA;
    float* ctx   = ws + WS_CTX;
    float* ent   = ws + WS_ENT;

    hipMemsetAsync(ent, 0, 2 * sizeof(float), stream);

    // big projections
    gemm_kernel<<<dim3(36, 32), 256, 0, stream>>>(x, w_qkv, nullptr, qkv, BN, Cc, 3 * Cc, 0);
    gemm_kernel<<<dim3(12, 32), 256, 0, stream>>>(x, w_id, nullptr, idout, BN, Cc, Cc, 0);
    gemm_kernel<<<dim3(12, 32), 256, 0, stream>>>(x, w_g1, b_g1, hdn, BN, Cc, Cc, 1);
    // skinny projections
    gemm_kernel<<<dim3(1, 32), 256, 0, stream>>>(x, w_prune, b_prune, pl, BN, Cc, 60, 0);
    gemm_kernel<<<dim3(1, 32), 256, 0, stream>>>(x, w_idgate, b_idgate, ig, BN, Cc, 12, 0);
    gemm_kernel<<<dim3(1, 32), 256, 0, stream>>>(hdn, w_g2, b_g2, gl, BN, Cc, 12, 0);
    // delta rule (beta == 1 identically: softmax row-sums)
    pre_kernel<<<dim3(BH * NC), 256, 0, stream>>>(qkv, Qs, KnT, Ub, Wb, Atb);
    scan_kernel<<<dim3(BH, 4), 256, 0, stream>>>(Qs, KnT, Ub, Wb, Atb, delta);
    // FIR + mix + prune + gates + entropies
    paths_kernel<<<dim3(BN), 256, 0, stream>>>(qkv, delta, idout, pl, ig, gl,
                                               fir_s_w, fir_l_w, mixw, id_st, ctx, ent);
    // output projection
    gemm_kernel<<<dim3(12, 32), 256, 0, stream>>>(ctx, w_proj, b_proj, out, BN, Cc, Cc, 0);
    finalize_kernel<<<1, 1, 0, stream>>>(ent, out);
}

// Round 2
// 816.069 us; speedup vs baseline: 1.4621x; 1.4621x over previous
//
#include <hip/hip_runtime.h>
#include <hip/hip_bf16.h>
#include <math.h>

// Problem dims (fixed by setup_inputs)
#define Bz 4
#define Nn 1024
#define Cc 768
#define Hh 12
#define Dd 64
#define Pp 5
#define BN 4096          // B*N
#define NC 16            // chunks per sequence
#define BH 48            // B*H
#define OUT_ELEMS 3145728  // BN*C

// ---------------- workspace layout (floats) ----------------
#define WS_QKV     0u
#define WS_IDOUT   9437184u
#define WS_HDN     12582912u
#define WS_PL      15728640u
#define WS_IG      15974400u
#define WS_GL      16023552u
#define WS_QS      16072704u
#define WS_KNT     19218432u
#define WS_U       22364160u
#define WS_W       25509888u
#define WS_AT      28655616u
#define WS_DELTA   31801344u
#define WS_CTX     34947072u
#define WS_ENT     38092800u
#define WS_BF16    38092816u   // float offset; shorts region starts here
// short offsets within the bf16 region:
#define SH_XB      0u
#define SH_WQKVT   3145728u
#define SH_WIDT    4915200u
#define SH_WG1T    5505024u
#define SH_WPROJT  6094848u
#define SH_CTXB    6684672u

typedef __attribute__((ext_vector_type(8))) short bf16x8;
typedef __attribute__((ext_vector_type(4))) float f32x4;

__device__ __forceinline__ float sigmoidf_(float x) { return 1.f / (1.f + __expf(-x)); }
__device__ __forceinline__ float geluf_(float x) {
    float t = tanhf(0.7978845608028654f * (x + 0.044715f * x * x * x));
    return 0.5f * x * (1.f + t);
}
__device__ __forceinline__ short bf16c(float f) {
    union { float f; unsigned u; } a; a.f = f;
    unsigned r = a.u + 0x7fffu + ((a.u >> 16) & 1u);
    return (short)(r >> 16);
}
__device__ __forceinline__ void gload16(const void* g, void* l) {
    __builtin_amdgcn_global_load_lds(
        (const __attribute__((address_space(1))) unsigned*)g,
        (__attribute__((address_space(3))) unsigned*)l, 16, 0, 0);
}

// ---------------- f32 -> bf16 row-preserving convert ----------------
__global__ __launch_bounds__(256) void convert_x_kernel(const float* __restrict__ src,
        short* __restrict__ dst, int n4) {
    int i = blockIdx.x * 256 + threadIdx.x;
    if (i < n4) {
        float4 v = *(const float4*)&src[(size_t)i * 4];
        short4 o;
        o.x = bf16c(v.x); o.y = bf16c(v.y); o.z = bf16c(v.z); o.w = bf16c(v.w);
        *(short4*)&dst[(size_t)i * 4] = o;
    }
}

// ---------------- weight transpose + bf16 convert: W[K,Nw] -> WT[Nw,K] ------
__global__ __launch_bounds__(256) void convert_w_kernel(const float* __restrict__ w_qkv,
        const float* __restrict__ w_id, const float* __restrict__ w_g1,
        const float* __restrict__ w_proj, short* __restrict__ wqkvT,
        short* __restrict__ widT, short* __restrict__ wg1T, short* __restrict__ wprojT) {
    __shared__ float t[64][65];
    const int z = blockIdx.z;
    const float* src; short* dst; int Nw;
    if (z == 0)      { src = w_qkv;  dst = wqkvT;  Nw = 2304; }
    else if (z == 1) { src = w_id;   dst = widT;   Nw = 768; }
    else if (z == 2) { src = w_g1;   dst = wg1T;   Nw = 768; }
    else             { src = w_proj; dst = wprojT; Nw = 768; }
    const int n0 = blockIdx.y * 64;
    if (n0 >= Nw) return;
    const int k0 = blockIdx.x * 64;
    const int tid = threadIdx.x;
    for (int e = tid; e < 1024; e += 256) {
        int r = e >> 4, c4 = (e & 15) * 4;
        float4 v = *(const float4*)&src[(size_t)(k0 + r) * Nw + n0 + c4];
        t[c4 + 0][r] = v.x; t[c4 + 1][r] = v.y;
        t[c4 + 2][r] = v.z; t[c4 + 3][r] = v.w;
    }
    __syncthreads();
    for (int e = tid; e < 1024; e += 256) {
        int r = e >> 4, c4 = (e & 15) * 4;
        short4 o;
        o.x = bf16c(t[r][c4 + 0]); o.y = bf16c(t[r][c4 + 1]);
        o.z = bf16c(t[r][c4 + 2]); o.w = bf16c(t[r][c4 + 3]);
        *(short4*)&dst[(size_t)(n0 + r) * 768 + k0 + c4] = o;
    }
}

// ---------------- bf16 MFMA GEMM: C[M,N] = act(A[M,K] @ BT[N,K]^T + bias) ----
// 128x128 tile, BK=64, 256 threads (4 waves, 2x2 of 64x64), 16x16x32 MFMA.
// LDS granule (row, g) holds global granule (row, g ^ (row&7)) -> ds_read_b128
// fragment reads are <=2-way bank aliased (free).  M,N %128==0, K %64==0.
__global__ __launch_bounds__(256) void gemm_mfma(const short* __restrict__ A,
        const short* __restrict__ BT, const float* __restrict__ bias,
        float* __restrict__ C, int M, int N, int K, int act) {
    __shared__ short As[128 * 64];
    __shared__ short Bs[128 * 64];
    const int tid = threadIdx.x;
    const int lane = tid & 63, w = tid >> 6;
    const int quad = lane >> 4, l15 = lane & 15;
    const int row0 = blockIdx.y * 128, col0 = blockIdx.x * 128;
    const int wm = (w >> 1) * 64, wn = (w & 1) * 64;

    // staging geometry (identical for A and B tiles)
    int srow[4]; int scol[4];
#pragma unroll
    for (int i = 0; i < 4; ++i) {
        int G = (w * 4 + i) * 64 + lane;
        int row = G >> 3, g = G & 7;
        srow[i] = row;
        scol[i] = (g ^ (row & 7)) * 8;
    }
    // fragment LDS byte offsets
    int aoff[4][2], boff[4][2];
#pragma unroll
    for (int mi = 0; mi < 4; ++mi)
#pragma unroll
        for (int kk = 0; kk < 2; ++kk) {
            int ra = wm + mi * 16 + l15;
            aoff[mi][kk] = ra * 128 + (((kk * 4 + quad) ^ (ra & 7)) * 16);
            int rb = wn + mi * 16 + l15;
            boff[mi][kk] = rb * 128 + (((kk * 4 + quad) ^ (rb & 7)) * 16);
        }

    f32x4 acc[4][4];
#pragma unroll
    for (int mi = 0; mi < 4; ++mi)
#pragma unroll
        for (int ni = 0; ni < 4; ++ni) acc[mi][ni] = (f32x4)0.f;

    for (int k0 = 0; k0 < K; k0 += 64) {
#pragma unroll
        for (int i = 0; i < 4; ++i) {
            gload16(&A[(size_t)(row0 + srow[i]) * K + k0 + scol[i]], &As[(w * 4 + i) * 512]);
            gload16(&BT[(size_t)(col0 + srow[i]) * K + k0 + scol[i]], &Bs[(w * 4 + i) * 512]);
        }
        __syncthreads();
#pragma unroll
        for (int kk = 0; kk < 2; ++kk) {
            bf16x8 af[4], bfr[4];
#pragma unroll
            for (int mi = 0; mi < 4; ++mi)
                af[mi] = *(const bf16x8*)((const char*)As + aoff[mi][kk]);
#pragma unroll
            for (int ni = 0; ni < 4; ++ni)
                bfr[ni] = *(const bf16x8*)((const char*)Bs + boff[ni][kk]);
#pragma unroll
            for (int mi = 0; mi < 4; ++mi)
#pragma unroll
                for (int ni = 0; ni < 4; ++ni)
                    acc[mi][ni] = __builtin_amdgcn_mfma_f32_16x16x32_bf16(
                        af[mi], bfr[ni], acc[mi][ni], 0, 0, 0);
        }
        __syncthreads();
    }
    // epilogue: C/D layout col=lane&15, row=quad*4+reg
#pragma unroll
    for (int ni = 0; ni < 4; ++ni) {
        int col = col0 + wn + ni * 16 + l15;
        float bv = bias ? bias[col] : 0.f;
#pragma unroll
        for (int mi = 0; mi < 4; ++mi) {
#pragma unroll
            for (int r = 0; r < 4; ++r) {
                int row = row0 + wm + mi * 16 + quad * 4 + r;
                float v = acc[mi][ni][r] + bv;
                if (act == 1) v = geluf_(v);
                C[(size_t)row * N + col] = v;
            }
        }
    }
}

// ---------------- generic tiled f32 GEMM (skinny outputs only) ----------------
__global__ __launch_bounds__(256) void gemm_kernel(const float* __restrict__ A,
        const float* __restrict__ Bm, const float* __restrict__ bias,
        float* __restrict__ Cm, int M, int K, int N, int act) {
    __shared__ float As[16][128];
    __shared__ float Bs[16][68];
    const int tid = threadIdx.x;
    const int tm = tid >> 4, tn = tid & 15;
    const int row0 = blockIdx.y * 128, col0 = blockIdx.x * 64;
    float acc[8][4];
#pragma unroll
    for (int i = 0; i < 8; ++i)
#pragma unroll
        for (int j = 0; j < 4; ++j) acc[i][j] = 0.f;

    for (int k0 = 0; k0 < K; k0 += 16) {
#pragma unroll
        for (int f = tid; f < 512; f += 256) {
            int r = f >> 2, kq = (f & 3) * 4;
            const float4 a = *(const float4*)&A[(size_t)(row0 + r) * K + k0 + kq];
            As[kq + 0][r] = a.x; As[kq + 1][r] = a.y;
            As[kq + 2][r] = a.z; As[kq + 3][r] = a.w;
        }
        {
            int kk = tid >> 4, nq = (tid & 15) * 4;
            int col = col0 + nq;
            float4 b4;
            if (col + 3 < N) {
                b4 = *(const float4*)&Bm[(size_t)(k0 + kk) * N + col];
            } else {
                b4.x = (col + 0 < N) ? Bm[(size_t)(k0 + kk) * N + col + 0] : 0.f;
                b4.y = (col + 1 < N) ? Bm[(size_t)(k0 + kk) * N + col + 1] : 0.f;
                b4.z = (col + 2 < N) ? Bm[(size_t)(k0 + kk) * N + col + 2] : 0.f;
                b4.w = (col + 3 < N) ? Bm[(size_t)(k0 + kk) * N + col + 3] : 0.f;
            }
            *(float4*)&Bs[kk][nq] = b4;
        }
        __syncthreads();
#pragma unroll
        for (int kk = 0; kk < 16; ++kk) {
            float a[8], b[4];
            *(float4*)&a[0] = *(const float4*)&As[kk][tm * 8];
            *(float4*)&a[4] = *(const float4*)&As[kk][tm * 8 + 4];
            *(float4*)&b[0] = *(const float4*)&Bs[kk][tn * 4];
#pragma unroll
            for (int i = 0; i < 8; ++i)
#pragma unroll
                for (int j = 0; j < 4; ++j) acc[i][j] += a[i] * b[j];
        }
        __syncthreads();
    }
#pragma unroll
    for (int i = 0; i < 8; ++i) {
        int r = row0 + tm * 8 + i;
        int cc0 = col0 + tn * 4;
        float v[4];
#pragma unroll
        for (int j = 0; j < 4; ++j) {
            v[j] = acc[i][j] + ((bias && cc0 + j < N) ? bias[cc0 + j] : 0.f);
            if (act == 1) v[j] = geluf_(v[j]);
        }
        if (cc0 + 3 < N) {
            float4 o; o.x = v[0]; o.y = v[1]; o.z = v[2]; o.w = v[3];
            *(float4*)&Cm[(size_t)r * N + cc0] = o;
        } else {
#pragma unroll
            for (int j = 0; j < 4; ++j)
                if (cc0 + j < N) Cm[(size_t)r * N + cc0 + j] = v[j];
        }
    }
}

// ---------------- delta-rule preprocessing: per (b,h,chunk) ----------------
__global__ __launch_bounds__(256) void pre_kernel(const float* __restrict__ qkv,
        float* __restrict__ Qs, float* __restrict__ KnT, float* __restrict__ U,
        float* __restrict__ W, float* __restrict__ At) {
    __shared__ float ks[64][64];   // normalized k rows
    __shared__ float kst[64][64];  // k transposed, XOR-swizzled: (d,r) at kst[d][r^(d&31)]
    __shared__ float ts[64][64];   // A then T (row 0 temporarily holds inv norms)
    __shared__ float xs[64][64];   // q (scaled), later v
    const int blk = blockIdx.x;
    const int c = blk & 15, bh = blk >> 4;
    const int b = bh / Hh, h = bh % Hh;
    const int tid = threadIdx.x;
    const size_t rowbase = ((size_t)(b * Nn + c * 64)) * (3 * Cc) + h * 64;
    const size_t base2 = (size_t)blk * 4096;

    for (int e4 = tid; e4 < 1024; e4 += 256) {
        int r = e4 >> 4, d4 = (e4 & 15) * 4;
        const float4 qv = *(const float4*)&qkv[rowbase + (size_t)r * 2304 + d4];
        const float4 kv = *(const float4*)&qkv[rowbase + (size_t)r * 2304 + 768 + d4];
        xs[r][d4 + 0] = qv.x * 0.125f; xs[r][d4 + 1] = qv.y * 0.125f;
        xs[r][d4 + 2] = qv.z * 0.125f; xs[r][d4 + 3] = qv.w * 0.125f;
        ks[r][d4 + 0] = kv.x; ks[r][d4 + 1] = kv.y;
        ks[r][d4 + 2] = kv.z; ks[r][d4 + 3] = kv.w;
    }
    __syncthreads();
    for (int e = tid; e < 4096; e += 256) {
        int r = e >> 6, d = e & 63;
        kst[d][r ^ (d & 31)] = ks[r][d];
    }
    __syncthreads();
    float* inv = &ts[0][0];
    if (tid < 64) {
        int r = tid;
        float s = 0.f;
        for (int d = 0; d < 64; ++d) { float kk = kst[d][r ^ (d & 31)]; s += kk * kk; }
        inv[r] = 1.f / (sqrtf(s) + 1e-6f);
    }
    __syncthreads();
    for (int e = tid; e < 4096; e += 256) {
        int r = e >> 6, d = e & 63;
        ks[r][d] *= inv[r];
        Qs[base2 + e] = xs[r][d];
    }
    for (int e = tid; e < 4096; e += 256) {
        int dd = e >> 6, rr = e & 63;
        float v = kst[dd][rr ^ (dd & 31)] * inv[rr];
        kst[dd][rr ^ (dd & 31)] = v;
        KnT[base2 + e] = v;
    }
    __syncthreads();
    for (int e = tid; e < 4096; e += 256) {
        int i = e >> 6, j = e & 63;
        float s = 0.f;
        if (j < i) {
            for (int d = 0; d < 64; ++d) s += ks[i][d] * kst[d][j ^ (d & 31)];
        }
        ts[i][j] = s;
    }
    __syncthreads();
    for (int i = 0; i < 64; ++i) {
        float val = 0.f;
        if (tid < 64) {
            int j = tid;
            float s = 0.f;
            for (int m = 0; m < i; ++m) s += ts[i][m] * ts[m][j];
            val = ((j == i) ? 1.f : 0.f) - s;
        }
        __syncthreads();
        if (tid < 64) ts[i][tid] = val;
        __syncthreads();
    }
    for (int e = tid; e < 4096; e += 256) {
        int r = e >> 6, j = e & 63;
        float sw = 0.f;
        for (int m = 0; m <= r; ++m) sw += ts[r][m] * ks[m][j];
        W[base2 + e] = sw;
        float sa = 0.f;
        if (j <= r) {
            for (int d = 0; d < 64; ++d) sa += xs[r][d] * kst[d][j ^ (d & 31)];
        }
        At[base2 + e] = sa;
    }
    __syncthreads();
    for (int e4 = tid; e4 < 1024; e4 += 256) {
        int r = e4 >> 4, d4 = (e4 & 15) * 4;
        const float4 vv = *(const float4*)&qkv[rowbase + (size_t)r * 2304 + 1536 + d4];
        xs[r][d4 + 0] = vv.x; xs[r][d4 + 1] = vv.y;
        xs[r][d4 + 2] = vv.z; xs[r][d4 + 3] = vv.w;
    }
    __syncthreads();
    for (int e = tid; e < 4096; e += 256) {
        int r = e >> 6, j = e & 63;
        float su = 0.f;
        for (int m = 0; m <= r; ++m) su += ts[r][m] * xs[m][j];
        U[base2 + e] = su;
    }
}

// ---------------- sequential chunk scan, split over 16 value-dims per block ----
__global__ __launch_bounds__(256) void scan_kernel(const float* __restrict__ Qs,
        const float* __restrict__ KnT, const float* __restrict__ U,
        const float* __restrict__ W, const float* __restrict__ At,
        float* __restrict__ delta) {
    __shared__ float t0[64][68];
    __shared__ float t1[64][68];
    __shared__ float S[64][16];
    __shared__ float ut[64][16];
    const int bh = blockIdx.x;
    const int b = bh / Hh, h = bh % Hh;
    const int g0 = blockIdx.y * 16;
    const int tid = threadIdx.x;
    const int r = tid >> 2, dq = (tid & 3) * 4;
    for (int e = tid; e < 1024; e += 256) ((float*)S)[e] = 0.f;
    __syncthreads();
    for (int c = 0; c < 16; ++c) {
        const size_t base = ((size_t)(bh * 16 + c)) * 4096;
        for (int e4 = tid; e4 < 1024; e4 += 256) {
            int rr = e4 >> 4, d4 = (e4 & 15) * 4;
            *(float4*)&t0[rr][d4] = *(const float4*)&W[base + rr * 64 + d4];
            *(float4*)&t1[rr][d4] = *(const float4*)&Qs[base + rr * 64 + d4];
        }
        const float4 uv = *(const float4*)&U[base + r * 64 + g0 + dq];
        __syncthreads();
        float4 o1 = make_float4(0.f, 0.f, 0.f, 0.f);
        float4 utv = uv;
#pragma unroll 4
        for (int m = 0; m < 64; m += 4) {
            float wv[4], qv[4];
            *(float4*)&wv[0] = *(const float4*)&t0[r][m];
            *(float4*)&qv[0] = *(const float4*)&t1[r][m];
#pragma unroll
            for (int mm = 0; mm < 4; ++mm) {
                const float4 sv = *(const float4*)&S[m + mm][dq];
                utv.x -= wv[mm] * sv.x; utv.y -= wv[mm] * sv.y;
                utv.z -= wv[mm] * sv.z; utv.w -= wv[mm] * sv.w;
                o1.x += qv[mm] * sv.x; o1.y += qv[mm] * sv.y;
                o1.z += qv[mm] * sv.z; o1.w += qv[mm] * sv.w;
            }
        }
        *(float4*)&ut[r][dq] = utv;
        __syncthreads();
        for (int e4 = tid; e4 < 1024; e4 += 256) {
            int rr = e4 >> 4, d4 = (e4 & 15) * 4;
            *(float4*)&t0[rr][d4] = *(const float4*)&At[base + rr * 64 + d4];
            *(float4*)&t1[rr][d4] = *(const float4*)&KnT[base + rr * 64 + d4];
        }
        __syncthreads();
        float4 o2 = o1;
        float4 sacc = *(const float4*)&S[r][dq];
#pragma unroll 4
        for (int m = 0; m < 64; m += 4) {
            float av[4], kv[4];
            *(float4*)&av[0] = *(const float4*)&t0[r][m];
            *(float4*)&kv[0] = *(const float4*)&t1[r][m];
#pragma unroll
            for (int mm = 0; mm < 4; ++mm) {
                const float4 uvm = *(const float4*)&ut[m + mm][dq];
                o2.x += av[mm] * uvm.x; o2.y += av[mm] * uvm.y;
                o2.z += av[mm] * uvm.z; o2.w += av[mm] * uvm.w;
                sacc.x += kv[mm] * uvm.x; sacc.y += kv[mm] * uvm.y;
                sacc.z += kv[mm] * uvm.z; sacc.w += kv[mm] * uvm.w;
            }
        }
        *(float4*)&S[r][dq] = sacc;
        const size_t orow = ((size_t)(b * Nn + c * 64 + r)) * Cc + h * 64 + g0 + dq;
        *(float4*)&delta[orow] = o2;
        __syncthreads();
    }
}

// ---------------- FIR + head-mix + prune softmax + gates + entropies ----------
__global__ __launch_bounds__(256) void paths_kernel(const float* __restrict__ qkv,
        const float* __restrict__ delta, const float* __restrict__ idout,
        const float* __restrict__ pl, const float* __restrict__ ig,
        const float* __restrict__ gl, const float* __restrict__ firs,
        const float* __restrict__ firl, const float* __restrict__ mixw,
        const float* __restrict__ idst, float* __restrict__ context,
        float* __restrict__ ent_acc) {
    __shared__ float fs[768], fl[768], vrow[768];
    __shared__ float wts_s[60], gate_s[12], idg_s[12], e1_s[12], e2_s[12];
    const int bn = blockIdx.x;
    const int b = bn >> 10, n = bn & 1023;
    const int tid = threadIdx.x;
#pragma unroll
    for (int e = tid; e < 768; e += 256) {
        float acc_s = 0.f, acc_l = 0.f, vv = 0.f;
        const float* wl = &firl[e * 7];
        const float* ws = &firs[e * 3];
#pragma unroll
        for (int t = 0; t < 7; ++t) {
            int np = n + t - 6;
            if (np >= 0) {
                float v = qkv[((size_t)(b * Nn + np)) * 2304 + 1536 + e];
                acc_l += wl[t] * v;
                if (t >= 4) acc_s += ws[t - 4] * v;
                if (t == 6) vv = v;
            }
        }
        fs[e] = acc_s; fl[e] = acc_l; vrow[e] = vv;
    }
    if (tid < 12) {
        int h = tid;
        float lg[5]; float mx = -1e30f;
#pragma unroll
        for (int p = 0; p < 5; ++p) { lg[p] = pl[(size_t)bn * 60 + h * 5 + p]; mx = fmaxf(mx, lg[p]); }
        float sum = 0.f;
#pragma unroll
        for (int p = 0; p < 5; ++p) { lg[p] = __expf(lg[p] - mx); sum += lg[p]; }
        float e1 = 0.f;
#pragma unroll
        for (int p = 0; p < 5; ++p) {
            float wv = lg[p] / sum;
            wts_s[h * 5 + p] = wv;
            e1 += wv * logf(wv + 1e-8f);
        }
        e1_s[h] = e1;
        float g = sigmoidf_(gl[(size_t)bn * 12 + h]);
        gate_s[h] = g;
        e2_s[h] = g * logf(g + 1e-8f) + (1.f - g) * logf(1.f - g + 1e-8f);
        idg_s[h] = sigmoidf_(ig[(size_t)bn * 12 + h]) * sigmoidf_(idst[h]);
    }
    __syncthreads();
#pragma unroll
    for (int e = tid; e < 768; e += 256) {
        int h = e >> 6, d = e & 63;
        float ms = fs[e], ml = fl[e];
#pragma unroll
        for (int hh = 0; hh < 12; ++hh) {
            float mw = mixw[hh * 12 + h];
            ms += fs[hh * 64 + d] * mw;
            ml += fl[hh * 64 + d] * mw;
        }
        float dl = delta[(size_t)bn * 768 + e];
        float vv = vrow[e];
        float idv = idout[(size_t)bn * 768 + e] * idg_s[h];
        const float* wp = &wts_s[h * 5];
        float pr = ms * wp[0] + ml * wp[1] + dl * wp[2] + vv * wp[3] + idv * wp[4];
        context[(size_t)bn * 768 + e] = pr * gate_s[h];
    }
    if (tid == 0) {
        float s1 = 0.f, s2 = 0.f;
#pragma unroll
        for (int h = 0; h < 12; ++h) { s1 += e1_s[h]; s2 += e2_s[h]; }
        atomicAdd(&ent_acc[0], s1);
        atomicAdd(&ent_acc[1], s2);
    }
}

__global__ void finalize_kernel(const float* __restrict__ ent_acc, float* __restrict__ out) {
    out[OUT_ELEMS] = -(ent_acc[0] + ent_acc[1]) * (1.f / 49152.f);
}

extern "C" void kernel_launch(void* const* d_in, const int* in_sizes, int n_in,
                              void* d_out, int out_size, void* d_ws, size_t ws_size,
                              hipStream_t stream) {
    const float* x        = (const float*)d_in[0];
    const float* w_qkv    = (const float*)d_in[1];
    const float* w_proj   = (const float*)d_in[2];
    const float* b_proj   = (const float*)d_in[3];
    const float* fir_s_w  = (const float*)d_in[4];
    const float* fir_l_w  = (const float*)d_in[5];
    const float* mixw     = (const float*)d_in[6];
    const float* w_prune  = (const float*)d_in[7];
    const float* b_prune  = (const float*)d_in[8];
    const float* w_g1     = (const float*)d_in[9];
    const float* b_g1     = (const float*)d_in[10];
    const float* w_g2     = (const float*)d_in[11];
    const float* b_g2     = (const float*)d_in[12];
    const float* w_id     = (const float*)d_in[13];
    const float* id_st    = (const float*)d_in[14];
    const float* w_idgate = (const float*)d_in[15];
    const float* b_idgate = (const float*)d_in[16];
    float* out = (float*)d_out;
    float* ws  = (float*)d_ws;

    float* qkv   = ws + WS_QKV;
    float* idout = ws + WS_IDOUT;
    float* hdn   = ws + WS_HDN;
    float* pl    = ws + WS_PL;
    float* ig    = ws + WS_IG;
    float* gl    = ws + WS_GL;
    float* Qs    = ws + WS_QS;
    float* KnT   = ws + WS_KNT;
    float* Ub    = ws + WS_U;
    float* Wb    = ws + WS_W;
    float* Atb   = ws + WS_AT;
    float* delta = ws + WS_DELTA;
    float* ctx   = ws + WS_CTX;
    float* ent   = ws + WS_ENT;
    short* wsh   = (short*)(ws + WS_BF16);
    short* xb     = wsh + SH_XB;
    short* wqkvT  = wsh + SH_WQKVT;
    short* widT   = wsh + SH_WIDT;
    short* wg1T   = wsh + SH_WG1T;
    short* wprojT = wsh + SH_WPROJT;
    short* ctxb   = wsh + SH_CTXB;

    hipMemsetAsync(ent, 0, 2 * sizeof(float), stream);

    // bf16 conversions: x (row-preserving) + 4 weights (transposed)
    convert_x_kernel<<<dim3(3072), 256, 0, stream>>>(x, xb, 786432);
    convert_w_kernel<<<dim3(12, 36, 4), 256, 0, stream>>>(w_qkv, w_id, w_g1, w_proj,
                                                          wqkvT, widT, wg1T, wprojT);
    // big projections: bf16 MFMA
    gemm_mfma<<<dim3(18, 32), 256, 0, stream>>>(xb, wqkvT, nullptr, qkv, BN, 2304, Cc, 0);
    gemm_mfma<<<dim3(6, 32), 256, 0, stream>>>(xb, widT, nullptr, idout, BN, Cc, Cc, 0);
    gemm_mfma<<<dim3(6, 32), 256, 0, stream>>>(xb, wg1T, b_g1, hdn, BN, Cc, Cc, 1);
    // skinny projections: f32
    gemm_kernel<<<dim3(1, 32), 256, 0, stream>>>(x, w_prune, b_prune, pl, BN, Cc, 60, 0);
    gemm_kernel<<<dim3(1, 32), 256, 0, stream>>>(x, w_idgate, b_idgate, ig, BN, Cc, 12, 0);
    gemm_kernel<<<dim3(1, 32), 256, 0, stream>>>(hdn, w_g2, b_g2, gl, BN, Cc, 12, 0);
    // delta rule (beta == 1 identically: softmax row-sums)
    pre_kernel<<<dim3(BH * NC), 256, 0, stream>>>(qkv, Qs, KnT, Ub, Wb, Atb);
    scan_kernel<<<dim3(BH, 4), 256, 0, stream>>>(Qs, KnT, Ub, Wb, Atb, delta);
    // FIR + mix + prune + gates + entropies
    paths_kernel<<<dim3(BN), 256, 0, stream>>>(qkv, delta, idout, pl, ig, gl,
                                               fir_s_w, fir_l_w, mixw, id_st, ctx, ent);
    // output projection: convert ctx -> bf16, then MFMA
    convert_x_kernel<<<dim3(3072), 256, 0, stream>>>(ctx, ctxb, 786432);
    gemm_mfma<<<dim3(6, 32), 256, 0, stream>>>(ctxb, wprojT, b_proj, out, BN, Cc, Cc, 0);
    finalize_kernel<<<1, 1, 0, stream>>>(ent, out);
}

// Round 3
// 632.584 us; speedup vs baseline: 1.8862x; 1.2901x over previous
//
#include <hip/hip_runtime.h>
#include <hip/hip_bf16.h>
#include <math.h>

// Problem dims (fixed by setup_inputs)
#define Bz 4
#define Nn 1024
#define Cc 768
#define Hh 12
#define Dd 64
#define Pp 5
#define BN 4096          // B*N
#define NC 16            // chunks per sequence
#define BH 48            // B*H
#define OUT_ELEMS 3145728  // BN*C

// ---------------- workspace layout (floats) ----------------
#define WS_QKV     0u
#define WS_IDOUT   9437184u
#define WS_HDN     12582912u
#define WS_PL      15728640u   // merged prune(60)+idgate(12) logits: [BN][72]
#define WS_GL      16023552u
#define WS_QS      16072704u   // also reused transiently for wcomb/bcomb (before pre_kernel)
#define WS_KNT     19218432u
#define WS_U       22364160u
#define WS_W       25509888u
#define WS_AT      28655616u
#define WS_DELTA   31801344u
#define WS_CTX     34947072u
#define WS_ENT     38092800u
#define WS_BF16    38092816u   // float offset; shorts region starts here
// short offsets within the bf16 region:
#define SH_XB      0u
#define SH_WQKVT   3145728u
#define SH_WIDT    4915200u
#define SH_WG1T    5505024u
#define SH_WPROJT  6094848u
#define SH_CTXB    6684672u

typedef __attribute__((ext_vector_type(8))) short bf16x8;
typedef __attribute__((ext_vector_type(4))) float f32x4;

__device__ __forceinline__ float sigmoidf_(float x) { return 1.f / (1.f + __expf(-x)); }
__device__ __forceinline__ float geluf_(float x) {
    float t = tanhf(0.7978845608028654f * (x + 0.044715f * x * x * x));
    return 0.5f * x * (1.f + t);
}
__device__ __forceinline__ short bf16c(float f) {
    union { float f; unsigned u; } a; a.f = f;
    unsigned r = a.u + 0x7fffu + ((a.u >> 16) & 1u);
    return (short)(r >> 16);
}
__device__ __forceinline__ void gload16(const void* g, void* l) {
    __builtin_amdgcn_global_load_lds(
        (const __attribute__((address_space(1))) unsigned*)g,
        (__attribute__((address_space(3))) unsigned*)l, 16, 0, 0);
}
// MFMA fragment read from a 64x64 bf16 LDS array with per-row XOR granule swizzle.
// Element (row, c) stored at row*64 + ((c>>3)^(row&7))*8 + (c&7).
__device__ __forceinline__ bf16x8 frag_(const short* arr, int row, int kc, int quad) {
    return *(const bf16x8*)&arr[row * 64 + (((kc * 4 + quad) ^ (row & 7)) << 3)];
}

// ---------------- f32 -> bf16 row-preserving convert ----------------
__global__ __launch_bounds__(256) void convert_x_kernel(const float* __restrict__ src,
        short* __restrict__ dst, int n4) {
    int i = blockIdx.x * 256 + threadIdx.x;
    if (i < n4) {
        float4 v = *(const float4*)&src[(size_t)i * 4];
        short4 o;
        o.x = bf16c(v.x); o.y = bf16c(v.y); o.z = bf16c(v.z); o.w = bf16c(v.w);
        *(short4*)&dst[(size_t)i * 4] = o;
    }
}

// ---------------- weight transpose + bf16 convert: W[K,Nw] -> WT[Nw,K] ------
__global__ __launch_bounds__(256) void convert_w_kernel(const float* __restrict__ w_qkv,
        const float* __restrict__ w_id, const float* __restrict__ w_g1,
        const float* __restrict__ w_proj, short* __restrict__ wqkvT,
        short* __restrict__ widT, short* __restrict__ wg1T, short* __restrict__ wprojT) {
    __shared__ float t[64][65];
    const int z = blockIdx.z;
    const float* src; short* dst; int Nw;
    if (z == 0)      { src = w_qkv;  dst = wqkvT;  Nw = 2304; }
    else if (z == 1) { src = w_id;   dst = widT;   Nw = 768; }
    else if (z == 2) { src = w_g1;   dst = wg1T;   Nw = 768; }
    else             { src = w_proj; dst = wprojT; Nw = 768; }
    const int n0 = blockIdx.y * 64;
    if (n0 >= Nw) return;
    const int k0 = blockIdx.x * 64;
    const int tid = threadIdx.x;
    for (int e = tid; e < 1024; e += 256) {
        int r = e >> 4, c4 = (e & 15) * 4;
        float4 v = *(const float4*)&src[(size_t)(k0 + r) * Nw + n0 + c4];
        t[c4 + 0][r] = v.x; t[c4 + 1][r] = v.y;
        t[c4 + 2][r] = v.z; t[c4 + 3][r] = v.w;
    }
    __syncthreads();
    for (int e = tid; e < 1024; e += 256) {
        int r = e >> 4, c4 = (e & 15) * 4;
        short4 o;
        o.x = bf16c(t[r][c4 + 0]); o.y = bf16c(t[r][c4 + 1]);
        o.z = bf16c(t[r][c4 + 2]); o.w = bf16c(t[r][c4 + 3]);
        *(short4*)&dst[(size_t)(n0 + r) * 768 + k0 + c4] = o;
    }
}

// ---------------- merge prune+idgate weights/biases into [768][72] ----------
__global__ __launch_bounds__(256) void merge_pw_kernel(const float* __restrict__ wp,
        const float* __restrict__ wig, const float* __restrict__ bp,
        const float* __restrict__ big, float* __restrict__ wcomb, float* __restrict__ bcomb) {
    int i = blockIdx.x * 256 + threadIdx.x;
    if (i < 768 * 72) {
        int k = i / 72, c = i % 72;
        wcomb[i] = (c < 60) ? wp[k * 60 + c] : wig[k * 12 + (c - 60)];
    }
    if (i < 72) bcomb[i] = (i < 60) ? bp[i] : big[i - 60];
}

// ---------------- bf16 MFMA GEMM: C[M,N] = act(A[M,K] @ BT[N,K]^T + bias) ----
__global__ __launch_bounds__(256) void gemm_mfma(const short* __restrict__ A,
        const short* __restrict__ BT, const float* __restrict__ bias,
        float* __restrict__ C, int M, int N, int K, int act) {
    __shared__ short As[128 * 64];
    __shared__ short Bs[128 * 64];
    const int tid = threadIdx.x;
    const int lane = tid & 63, w = tid >> 6;
    const int quad = lane >> 4, l15 = lane & 15;
    const int row0 = blockIdx.y * 128, col0 = blockIdx.x * 128;
    const int wm = (w >> 1) * 64, wn = (w & 1) * 64;

    int srow[4]; int scol[4];
#pragma unroll
    for (int i = 0; i < 4; ++i) {
        int G = (w * 4 + i) * 64 + lane;
        int row = G >> 3, g = G & 7;
        srow[i] = row;
        scol[i] = (g ^ (row & 7)) * 8;
    }
    int aoff[4][2], boff[4][2];
#pragma unroll
    for (int mi = 0; mi < 4; ++mi)
#pragma unroll
        for (int kk = 0; kk < 2; ++kk) {
            int ra = wm + mi * 16 + l15;
            aoff[mi][kk] = ra * 128 + (((kk * 4 + quad) ^ (ra & 7)) * 16);
            int rb = wn + mi * 16 + l15;
            boff[mi][kk] = rb * 128 + (((kk * 4 + quad) ^ (rb & 7)) * 16);
        }

    f32x4 acc[4][4];
#pragma unroll
    for (int mi = 0; mi < 4; ++mi)
#pragma unroll
        for (int ni = 0; ni < 4; ++ni) acc[mi][ni] = (f32x4)0.f;

    for (int k0 = 0; k0 < K; k0 += 64) {
#pragma unroll
        for (int i = 0; i < 4; ++i) {
            gload16(&A[(size_t)(row0 + srow[i]) * K + k0 + scol[i]], &As[(w * 4 + i) * 512]);
            gload16(&BT[(size_t)(col0 + srow[i]) * K + k0 + scol[i]], &Bs[(w * 4 + i) * 512]);
        }
        __syncthreads();
#pragma unroll
        for (int kk = 0; kk < 2; ++kk) {
            bf16x8 af[4], bfr[4];
#pragma unroll
            for (int mi = 0; mi < 4; ++mi)
                af[mi] = *(const bf16x8*)((const char*)As + aoff[mi][kk]);
#pragma unroll
            for (int ni = 0; ni < 4; ++ni)
                bfr[ni] = *(const bf16x8*)((const char*)Bs + boff[ni][kk]);
#pragma unroll
            for (int mi = 0; mi < 4; ++mi)
#pragma unroll
                for (int ni = 0; ni < 4; ++ni)
                    acc[mi][ni] = __builtin_amdgcn_mfma_f32_16x16x32_bf16(
                        af[mi], bfr[ni], acc[mi][ni], 0, 0, 0);
        }
        __syncthreads();
    }
#pragma unroll
    for (int ni = 0; ni < 4; ++ni) {
        int col = col0 + wn + ni * 16 + l15;
        float bv = bias ? bias[col] : 0.f;
#pragma unroll
        for (int mi = 0; mi < 4; ++mi) {
#pragma unroll
            for (int r = 0; r < 4; ++r) {
                int row = row0 + wm + mi * 16 + quad * 4 + r;
                float v = acc[mi][ni][r] + bv;
                if (act == 1) v = geluf_(v);
                C[(size_t)row * N + col] = v;
            }
        }
    }
}

// ---------------- generic tiled f32 GEMM (skinny outputs only) ----------------
__global__ __launch_bounds__(256) void gemm_kernel(const float* __restrict__ A,
        const float* __restrict__ Bm, const float* __restrict__ bias,
        float* __restrict__ Cm, int M, int K, int N, int act) {
    __shared__ float As[16][128];
    __shared__ float Bs[16][68];
    const int tid = threadIdx.x;
    const int tm = tid >> 4, tn = tid & 15;
    const int row0 = blockIdx.y * 128, col0 = blockIdx.x * 64;
    float acc[8][4];
#pragma unroll
    for (int i = 0; i < 8; ++i)
#pragma unroll
        for (int j = 0; j < 4; ++j) acc[i][j] = 0.f;

    for (int k0 = 0; k0 < K; k0 += 16) {
#pragma unroll
        for (int f = tid; f < 512; f += 256) {
            int r = f >> 2, kq = (f & 3) * 4;
            const float4 a = *(const float4*)&A[(size_t)(row0 + r) * K + k0 + kq];
            As[kq + 0][r] = a.x; As[kq + 1][r] = a.y;
            As[kq + 2][r] = a.z; As[kq + 3][r] = a.w;
        }
        {
            int kk = tid >> 4, nq = (tid & 15) * 4;
            int col = col0 + nq;
            float4 b4;
            if (col + 3 < N) {
                b4 = *(const float4*)&Bm[(size_t)(k0 + kk) * N + col];
            } else {
                b4.x = (col + 0 < N) ? Bm[(size_t)(k0 + kk) * N + col + 0] : 0.f;
                b4.y = (col + 1 < N) ? Bm[(size_t)(k0 + kk) * N + col + 1] : 0.f;
                b4.z = (col + 2 < N) ? Bm[(size_t)(k0 + kk) * N + col + 2] : 0.f;
                b4.w = (col + 3 < N) ? Bm[(size_t)(k0 + kk) * N + col + 3] : 0.f;
            }
            *(float4*)&Bs[kk][nq] = b4;
        }
        __syncthreads();
#pragma unroll
        for (int kk = 0; kk < 16; ++kk) {
            float a[8], b[4];
            *(float4*)&a[0] = *(const float4*)&As[kk][tm * 8];
            *(float4*)&a[4] = *(const float4*)&As[kk][tm * 8 + 4];
            *(float4*)&b[0] = *(const float4*)&Bs[kk][tn * 4];
#pragma unroll
            for (int i = 0; i < 8; ++i)
#pragma unroll
                for (int j = 0; j < 4; ++j) acc[i][j] += a[i] * b[j];
        }
        __syncthreads();
    }
#pragma unroll
    for (int i = 0; i < 8; ++i) {
        int r = row0 + tm * 8 + i;
        int cc0 = col0 + tn * 4;
        float v[4];
#pragma unroll
        for (int j = 0; j < 4; ++j) {
            v[j] = acc[i][j] + ((bias && cc0 + j < N) ? bias[cc0 + j] : 0.f);
            if (act == 1) v[j] = geluf_(v[j]);
        }
        if (cc0 + 3 < N) {
            float4 o; o.x = v[0]; o.y = v[1]; o.z = v[2]; o.w = v[3];
            *(float4*)&Cm[(size_t)r * N + cc0] = o;
        } else {
#pragma unroll
            for (int j = 0; j < 4; ++j)
                if (cc0 + j < N) Cm[(size_t)r * N + cc0 + j] = v[j];
        }
    }
}

// ---------------- delta-rule preprocessing (MFMA + blocked inversion) --------
// Per (b,h,chunk): Kn = l2norm(k), Qs = q*scale (f32 out), KnT (f32 out),
// A = tril(Kn Kn^T, -1); T = (I+A)^{-1} via 16-blocked forward substitution;
// W = T@Kn, U = T@V, At = tril(Qs Kn^T)  (all via bf16 MFMA, f32 out).
__global__ __launch_bounds__(256) void pre_kernel(const float* __restrict__ qkv,
        float* __restrict__ Qs, float* __restrict__ KnT, float* __restrict__ U,
        float* __restrict__ W, float* __restrict__ At) {
    __shared__ float ts[64][68];     // f32 A -> T
    __shared__ float zbuf[16][68];   // block-substitution staging
    __shared__ short kn[4096];       // bf16 Kn  [r][d], swizzled granules
    __shared__ short knt[4096];      // bf16 Kn^T [d][r]
    __shared__ short qsb[4096];      // bf16 Qs  [r][d]
    __shared__ short vtb[4096];      // bf16 V^T [d][r]
    __shared__ short tb[4096];       // bf16 T   [r][m]
    const int blk = blockIdx.x;
    const int c = blk & 15, bh = blk >> 4;
    const int b = bh / Hh, h = bh % Hh;
    const int tid = threadIdx.x;
    const int lane = tid & 63, w = tid >> 6;
    const int quad = lane >> 4, l15 = lane & 15;
    const int r = tid >> 2, d0 = (tid & 3) * 16;
    const size_t rowbase = ((size_t)(b * Nn + c * 64)) * (3 * Cc) + h * 64;
    const size_t base2 = (size_t)blk * 4096;

    // ---- Phase A: load k/q/v, normalize k, fill LDS operand arrays ----
    {
        float kf[16];
        const float* kp = &qkv[rowbase + (size_t)r * 2304 + 768 + d0];
#pragma unroll
        for (int t4 = 0; t4 < 4; ++t4) {
            float4 v = *(const float4*)&kp[t4 * 4];
            kf[t4 * 4 + 0] = v.x; kf[t4 * 4 + 1] = v.y;
            kf[t4 * 4 + 2] = v.z; kf[t4 * 4 + 3] = v.w;
        }
        float ss = 0.f;
#pragma unroll
        for (int t = 0; t < 16; ++t) ss += kf[t] * kf[t];
        ss += __shfl_xor(ss, 1);
        ss += __shfl_xor(ss, 2);
        float invn = 1.f / (sqrtf(ss) + 1e-6f);
#pragma unroll
        for (int t = 0; t < 16; ++t) kf[t] *= invn;
        // KnT f32 global (scattered)
#pragma unroll
        for (int t = 0; t < 16; ++t) KnT[base2 + (size_t)(d0 + t) * 64 + r] = kf[t];
        // kn LDS: two swizzled granules
        bf16x8 g0, g1;
#pragma unroll
        for (int t = 0; t < 8; ++t) { g0[t] = bf16c(kf[t]); g1[t] = bf16c(kf[8 + t]); }
        int gb = d0 >> 3;
        *(bf16x8*)&kn[r * 64 + (((gb + 0) ^ (r & 7)) << 3)] = g0;
        *(bf16x8*)&kn[r * 64 + (((gb + 1) ^ (r & 7)) << 3)] = g1;
        // knt LDS: transposed scalar stores
#pragma unroll
        for (int t = 0; t < 16; ++t) {
            int d = d0 + t;
            knt[d * 64 + (((r >> 3) ^ (d & 7)) << 3) + (r & 7)] = bf16c(kf[t]);
        }
    }
    {
        float qf[16];
        const float* qp = &qkv[rowbase + (size_t)r * 2304 + d0];
#pragma unroll
        for (int t4 = 0; t4 < 4; ++t4) {
            float4 v = *(const float4*)&qp[t4 * 4];
            qf[t4 * 4 + 0] = v.x * 0.125f; qf[t4 * 4 + 1] = v.y * 0.125f;
            qf[t4 * 4 + 2] = v.z * 0.125f; qf[t4 * 4 + 3] = v.w * 0.125f;
        }
#pragma unroll
        for (int t4 = 0; t4 < 4; ++t4) {
            float4 o; o.x = qf[t4 * 4]; o.y = qf[t4 * 4 + 1];
            o.z = qf[t4 * 4 + 2]; o.w = qf[t4 * 4 + 3];
            *(float4*)&Qs[base2 + (size_t)r * 64 + d0 + t4 * 4] = o;
        }
        bf16x8 g0, g1;
#pragma unroll
        for (int t = 0; t < 8; ++t) { g0[t] = bf16c(qf[t]); g1[t] = bf16c(qf[8 + t]); }
        int gb = d0 >> 3;
        *(bf16x8*)&qsb[r * 64 + (((gb + 0) ^ (r & 7)) << 3)] = g0;
        *(bf16x8*)&qsb[r * 64 + (((gb + 1) ^ (r & 7)) << 3)] = g1;
    }
    {
        const float* vp = &qkv[rowbase + (size_t)r * 2304 + 1536 + d0];
#pragma unroll
        for (int t4 = 0; t4 < 4; ++t4) {
            float4 v = *(const float4*)&vp[t4 * 4];
            int d = d0 + t4 * 4;
            vtb[(d + 0) * 64 + (((r >> 3) ^ ((d + 0) & 7)) << 3) + (r & 7)] = bf16c(v.x);
            vtb[(d + 1) * 64 + (((r >> 3) ^ ((d + 1) & 7)) << 3) + (r & 7)] = bf16c(v.y);
            vtb[(d + 2) * 64 + (((r >> 3) ^ ((d + 2) & 7)) << 3) + (r & 7)] = bf16c(v.z);
            vtb[(d + 3) * 64 + (((r >> 3) ^ ((d + 3) & 7)) << 3) + (r & 7)] = bf16c(v.w);
        }
    }
    __syncthreads();

    // ---- Phase B: MFMA  A_full = Kn Kn^T -> ts (tril -1), At = Qs Kn^T -> global (tril)
    {
        const int ar = w * 16 + l15;
        bf16x8 aK0 = frag_(kn, ar, 0, quad), aK1 = frag_(kn, ar, 1, quad);
        bf16x8 aQ0 = frag_(qsb, ar, 0, quad), aQ1 = frag_(qsb, ar, 1, quad);
        f32x4 accA[4], accT[4];
#pragma unroll
        for (int ni = 0; ni < 4; ++ni) {
            int br = ni * 16 + l15;
            bf16x8 b0 = frag_(kn, br, 0, quad), b1 = frag_(kn, br, 1, quad);
            accA[ni] = __builtin_amdgcn_mfma_f32_16x16x32_bf16(aK0, b0, (f32x4)0.f, 0, 0, 0);
            accA[ni] = __builtin_amdgcn_mfma_f32_16x16x32_bf16(aK1, b1, accA[ni], 0, 0, 0);
            accT[ni] = __builtin_amdgcn_mfma_f32_16x16x32_bf16(aQ0, b0, (f32x4)0.f, 0, 0, 0);
            accT[ni] = __builtin_amdgcn_mfma_f32_16x16x32_bf16(aQ1, b1, accT[ni], 0, 0, 0);
        }
#pragma unroll
        for (int ni = 0; ni < 4; ++ni)
#pragma unroll
            for (int reg = 0; reg < 4; ++reg) {
                int row = w * 16 + quad * 4 + reg;
                int col = ni * 16 + l15;
                ts[row][col] = (col < row) ? accA[ni][reg] : 0.f;
                At[base2 + (size_t)row * 64 + col] = (col <= row) ? accT[ni][reg] : 0.f;
            }
    }
    __syncthreads();

    // ---- Phase C1: invert 4 diagonal 16x16 unit-lower blocks, one per wave ----
    {
        const int R0 = w * 16;
        if (lane < 16) {
            const int j = lane;
#pragma unroll 1
            for (int i = 0; i < 16; ++i) {
                float s = 0.f;
                for (int m = 0; m < i; ++m) s += ts[R0 + i][R0 + m] * ts[R0 + m][R0 + j];
                ts[R0 + i][R0 + j] = ((j == i) ? 1.f : 0.f) - s;
            }
        }
    }
    __syncthreads();
    // ---- Phase C2: off-diagonal block rows I=1..3 ----
#pragma unroll 1
    for (int I = 1; I < 4; ++I) {
        const int ncol = I * 16;
        for (int e = tid; e < 16 * ncol; e += 256) {
            int i = e / ncol, jj = e % ncol;
            float s = 0.f;
            for (int m = jj; m < ncol; ++m) s += ts[ncol + i][m] * ts[m][jj];
            zbuf[i][jj] = s;
        }
        __syncthreads();
        for (int e = tid; e < 16 * ncol; e += 256) {
            int i = e / ncol, jj = e % ncol;
            float s = 0.f;
            for (int ml = 0; ml <= i; ++ml) s += ts[ncol + i][ncol + ml] * zbuf[ml][jj];
            ts[ncol + i][jj] = -s;
        }
        __syncthreads();
    }
    // ---- convert T -> bf16 tb ----
    for (int e = tid; e < 512; e += 256) {
        int row = e >> 3, g = e & 7;
        bf16x8 o;
#pragma unroll
        for (int t = 0; t < 8; ++t) o[t] = bf16c(ts[row][g * 8 + t]);
        *(bf16x8*)&tb[row * 64 + ((g ^ (row & 7)) << 3)] = o;
    }
    __syncthreads();

    // ---- Phase D: MFMA  W = T@Kn (B=knt), U = T@V (B=vtb) ----
    {
        const int ar = w * 16 + l15;
        bf16x8 aT0 = frag_(tb, ar, 0, quad), aT1 = frag_(tb, ar, 1, quad);
        f32x4 accW[4], accU[4];
#pragma unroll
        for (int ni = 0; ni < 4; ++ni) {
            int br = ni * 16 + l15;
            bf16x8 b0 = frag_(knt, br, 0, quad), b1 = frag_(knt, br, 1, quad);
            bf16x8 c0 = frag_(vtb, br, 0, quad), c1 = frag_(vtb, br, 1, quad);
            accW[ni] = __builtin_amdgcn_mfma_f32_16x16x32_bf16(aT0, b0, (f32x4)0.f, 0, 0, 0);
            accW[ni] = __builtin_amdgcn_mfma_f32_16x16x32_bf16(aT1, b1, accW[ni], 0, 0, 0);
            accU[ni] = __builtin_amdgcn_mfma_f32_16x16x32_bf16(aT0, c0, (f32x4)0.f, 0, 0, 0);
            accU[ni] = __builtin_amdgcn_mfma_f32_16x16x32_bf16(aT1, c1, accU[ni], 0, 0, 0);
        }
#pragma unroll
        for (int ni = 0; ni < 4; ++ni)
#pragma unroll
            for (int reg = 0; reg < 4; ++reg) {
                int row = w * 16 + quad * 4 + reg;
                int col = ni * 16 + l15;
                W[base2 + (size_t)row * 64 + col] = accW[ni][reg];
                U[base2 + (size_t)row * 64 + col] = accU[ni][reg];
            }
    }
}

// ---------------- sequential chunk scan, split over 16 value-dims per block ----
__global__ __launch_bounds__(256) void scan_kernel(const float* __restrict__ Qs,
        const float* __restrict__ KnT, const float* __restrict__ U,
        const float* __restrict__ W, const float* __restrict__ At,
        float* __restrict__ delta) {
    __shared__ float t0[64][68];
    __shared__ float t1[64][68];
    __shared__ float S[64][16];
    __shared__ float ut[64][16];
    const int bh = blockIdx.x;
    const int b = bh / Hh, h = bh % Hh;
    const int g0 = blockIdx.y * 16;
    const int tid = threadIdx.x;
    const int r = tid >> 2, dq = (tid & 3) * 4;
    for (int e = tid; e < 1024; e += 256) ((float*)S)[e] = 0.f;
    __syncthreads();
    for (int c = 0; c < 16; ++c) {
        const size_t base = ((size_t)(bh * 16 + c)) * 4096;
        for (int e4 = tid; e4 < 1024; e4 += 256) {
            int rr = e4 >> 4, d4 = (e4 & 15) * 4;
            *(float4*)&t0[rr][d4] = *(const float4*)&W[base + rr * 64 + d4];
            *(float4*)&t1[rr][d4] = *(const float4*)&Qs[base + rr * 64 + d4];
        }
        const float4 uv = *(const float4*)&U[base + r * 64 + g0 + dq];
        __syncthreads();
        float4 o1 = make_float4(0.f, 0.f, 0.f, 0.f);
        float4 utv = uv;
#pragma unroll 4
        for (int m = 0; m < 64; m += 4) {
            float wv[4], qv[4];
            *(float4*)&wv[0] = *(const float4*)&t0[r][m];
            *(float4*)&qv[0] = *(const float4*)&t1[r][m];
#pragma unroll
            for (int mm = 0; mm < 4; ++mm) {
                const float4 sv = *(const float4*)&S[m + mm][dq];
                utv.x -= wv[mm] * sv.x; utv.y -= wv[mm] * sv.y;
                utv.z -= wv[mm] * sv.z; utv.w -= wv[mm] * sv.w;
                o1.x += qv[mm] * sv.x; o1.y += qv[mm] * sv.y;
                o1.z += qv[mm] * sv.z; o1.w += qv[mm] * sv.w;
            }
        }
        *(float4*)&ut[r][dq] = utv;
        __syncthreads();
        for (int e4 = tid; e4 < 1024; e4 += 256) {
            int rr = e4 >> 4, d4 = (e4 & 15) * 4;
            *(float4*)&t0[rr][d4] = *(const float4*)&At[base + rr * 64 + d4];
            *(float4*)&t1[rr][d4] = *(const float4*)&KnT[base + rr * 64 + d4];
        }
        __syncthreads();
        float4 o2 = o1;
        float4 sacc = *(const float4*)&S[r][dq];
#pragma unroll 4
        for (int m = 0; m < 64; m += 4) {
            float av[4], kv[4];
            *(float4*)&av[0] = *(const float4*)&t0[r][m];
            *(float4*)&kv[0] = *(const float4*)&t1[r][m];
#pragma unroll
            for (int mm = 0; mm < 4; ++mm) {
                const float4 uvm = *(const float4*)&ut[m + mm][dq];
                o2.x += av[mm] * uvm.x; o2.y += av[mm] * uvm.y;
                o2.z += av[mm] * uvm.z; o2.w += av[mm] * uvm.w;
                sacc.x += kv[mm] * uvm.x; sacc.y += kv[mm] * uvm.y;
                sacc.z += kv[mm] * uvm.z; sacc.w += kv[mm] * uvm.w;
            }
        }
        *(float4*)&S[r][dq] = sacc;
        const size_t orow = ((size_t)(b * Nn + c * 64 + r)) * Cc + h * 64 + g0 + dq;
        *(float4*)&delta[orow] = o2;
        __syncthreads();
    }
}

// ---------------- FIR + head-mix + prune softmax + gates + entropies ----------
__global__ __launch_bounds__(256) void paths_kernel(const float* __restrict__ qkv,
        const float* __restrict__ delta, const float* __restrict__ idout,
        const float* __restrict__ plig, const float* __restrict__ gl,
        const float* __restrict__ firs, const float* __restrict__ firl,
        const float* __restrict__ mixw, const float* __restrict__ idst,
        float* __restrict__ context, float* __restrict__ ent_acc) {
    __shared__ float fs[768], fl[768], vrow[768];
    __shared__ float wts_s[60], gate_s[12], idg_s[12], e1_s[12], e2_s[12];
    const int bn = blockIdx.x;
    const int b = bn >> 10, n = bn & 1023;
    const int tid = threadIdx.x;
#pragma unroll
    for (int e = tid; e < 768; e += 256) {
        float acc_s = 0.f, acc_l = 0.f, vv = 0.f;
        const float* wl = &firl[e * 7];
        const float* ws = &firs[e * 3];
#pragma unroll
        for (int t = 0; t < 7; ++t) {
            int np = n + t - 6;
            if (np >= 0) {
                float v = qkv[((size_t)(b * Nn + np)) * 2304 + 1536 + e];
                acc_l += wl[t] * v;
                if (t >= 4) acc_s += ws[t - 4] * v;
                if (t == 6) vv = v;
            }
        }
        fs[e] = acc_s; fl[e] = acc_l; vrow[e] = vv;
    }
    if (tid < 12) {
        int h = tid;
        float lg[5]; float mx = -1e30f;
#pragma unroll
        for (int p = 0; p < 5; ++p) { lg[p] = plig[(size_t)bn * 72 + h * 5 + p]; mx = fmaxf(mx, lg[p]); }
        float sum = 0.f;
#pragma unroll
        for (int p = 0; p < 5; ++p) { lg[p] = __expf(lg[p] - mx); sum += lg[p]; }
        float e1 = 0.f;
#pragma unroll
        for (int p = 0; p < 5; ++p) {
            float wv = lg[p] / sum;
            wts_s[h * 5 + p] = wv;
            e1 += wv * logf(wv + 1e-8f);
        }
        e1_s[h] = e1;
        float g = sigmoidf_(gl[(size_t)bn * 12 + h]);
        gate_s[h] = g;
        e2_s[h] = g * logf(g + 1e-8f) + (1.f - g) * logf(1.f - g + 1e-8f);
        idg_s[h] = sigmoidf_(plig[(size_t)bn * 72 + 60 + h]) * sigmoidf_(idst[h]);
    }
    __syncthreads();
#pragma unroll
    for (int e = tid; e < 768; e += 256) {
        int h = e >> 6, d = e & 63;
        float ms = fs[e], ml = fl[e];
#pragma unroll
        for (int hh = 0; hh < 12; ++hh) {
            float mw = mixw[hh * 12 + h];
            ms += fs[hh * 64 + d] * mw;
            ml += fl[hh * 64 + d] * mw;
        }
        float dl = delta[(size_t)bn * 768 + e];
        float vv = vrow[e];
        float idv = idout[(size_t)bn * 768 + e] * idg_s[h];
        const float* wp = &wts_s[h * 5];
        float pr = ms * wp[0] + ml * wp[1] + dl * wp[2] + vv * wp[3] + idv * wp[4];
        context[(size_t)bn * 768 + e] = pr * gate_s[h];
    }
    if (tid == 0) {
        float s1 = 0.f, s2 = 0.f;
#pragma unroll
        for (int h = 0; h < 12; ++h) { s1 += e1_s[h]; s2 += e2_s[h]; }
        atomicAdd(&ent_acc[0], s1);
        atomicAdd(&ent_acc[1], s2);
    }
}

__global__ void finalize_kernel(const float* __restrict__ ent_acc, float* __restrict__ out) {
    out[OUT_ELEMS] = -(ent_acc[0] + ent_acc[1]) * (1.f / 49152.f);
}

extern "C" void kernel_launch(void* const* d_in, const int* in_sizes, int n_in,
                              void* d_out, int out_size, void* d_ws, size_t ws_size,
                              hipStream_t stream) {
    const float* x        = (const float*)d_in[0];
    const float* w_qkv    = (const float*)d_in[1];
    const float* w_proj   = (const float*)d_in[2];
    const float* b_proj   = (const float*)d_in[3];
    const float* fir_s_w  = (const float*)d_in[4];
    const float* fir_l_w  = (const float*)d_in[5];
    const float* mixw     = (const float*)d_in[6];
    const float* w_prune  = (const float*)d_in[7];
    const float* b_prune  = (const float*)d_in[8];
    const float* w_g1     = (const float*)d_in[9];
    const float* b_g1     = (const float*)d_in[10];
    const float* w_g2     = (const float*)d_in[11];
    const float* b_g2     = (const float*)d_in[12];
    const float* w_id     = (const float*)d_in[13];
    const float* id_st    = (const float*)d_in[14];
    const float* w_idgate = (const float*)d_in[15];
    const float* b_idgate = (const float*)d_in[16];
    float* out = (float*)d_out;
    float* ws  = (float*)d_ws;

    float* qkv   = ws + WS_QKV;
    float* idout = ws + WS_IDOUT;
    float* hdn   = ws + WS_HDN;
    float* plig  = ws + WS_PL;
    float* gl    = ws + WS_GL;
    float* Qs    = ws + WS_QS;
    float* KnT   = ws + WS_KNT;
    float* Ub    = ws + WS_U;
    float* Wb    = ws + WS_W;
    float* Atb   = ws + WS_AT;
    float* delta = ws + WS_DELTA;
    float* ctx   = ws + WS_CTX;
    float* ent   = ws + WS_ENT;
    // transient (consumed before pre_kernel overwrites Qs region):
    float* wcomb = ws + WS_QS;
    float* bcomb = ws + WS_QS + 55296;
    short* wsh   = (short*)(ws + WS_BF16);
    short* xb     = wsh + SH_XB;
    short* wqkvT  = wsh + SH_WQKVT;
    short* widT   = wsh + SH_WIDT;
    short* wg1T   = wsh + SH_WG1T;
    short* wprojT = wsh + SH_WPROJT;
    short* ctxb   = wsh + SH_CTXB;

    hipMemsetAsync(ent, 0, 2 * sizeof(float), stream);

    // bf16 conversions + weight merge
    convert_x_kernel<<<dim3(3072), 256, 0, stream>>>(x, xb, 786432);
    convert_w_kernel<<<dim3(12, 36, 4), 256, 0, stream>>>(w_qkv, w_id, w_g1, w_proj,
                                                          wqkvT, widT, wg1T, wprojT);
    merge_pw_kernel<<<dim3(216), 256, 0, stream>>>(w_prune, w_idgate, b_prune, b_idgate,
                                                   wcomb, bcomb);
    // big projections: bf16 MFMA
    gemm_mfma<<<dim3(18, 32), 256, 0, stream>>>(xb, wqkvT, nullptr, qkv, BN, 2304, Cc, 0);
    gemm_mfma<<<dim3(6, 32), 256, 0, stream>>>(xb, widT, nullptr, idout, BN, Cc, Cc, 0);
    gemm_mfma<<<dim3(6, 32), 256, 0, stream>>>(xb, wg1T, b_g1, hdn, BN, Cc, Cc, 1);
    // skinny projections: f32 (plig BEFORE pre_kernel — wcomb aliases Qs region)
    gemm_kernel<<<dim3(2, 32), 256, 0, stream>>>(x, wcomb, bcomb, plig, BN, Cc, 72, 0);
    gemm_kernel<<<dim3(1, 32), 256, 0, stream>>>(hdn, w_g2, b_g2, gl, BN, Cc, 12, 0);
    // delta rule (beta == 1 identically: softmax row-sums)
    pre_kernel<<<dim3(BH * NC), 256, 0, stream>>>(qkv, Qs, KnT, Ub, Wb, Atb);
    scan_kernel<<<dim3(BH, 4), 256, 0, stream>>>(Qs, KnT, Ub, Wb, Atb, delta);
    // FIR + mix + prune + gates + entropies
    paths_kernel<<<dim3(BN), 256, 0, stream>>>(qkv, delta, idout, plig, gl,
                                               fir_s_w, fir_l_w, mixw, id_st, ctx, ent);
    // output projection: convert ctx -> bf16, then MFMA
    convert_x_kernel<<<dim3(3072), 256, 0, stream>>>(ctx, ctxb, 786432);
    gemm_mfma<<<dim3(6, 32), 256, 0, stream>>>(ctxb, wprojT, b_proj, out, BN, Cc, Cc, 0);
    finalize_kernel<<<1, 1, 0, stream>>>(ent, out);
}

// Round 4
// 371.338 us; speedup vs baseline: 3.2132x; 1.7035x over previous
//
#include <hip/hip_runtime.h>
#include <hip/hip_bf16.h>
#include <math.h>

// Problem dims (fixed by setup_inputs)
#define Bz 4
#define Nn 1024
#define Cc 768
#define Hh 12
#define Dd 64
#define BN 4096          // B*N
#define NC 16            // chunks per sequence
#define BH 48            // B*H
#define OUT_ELEMS 3145728  // BN*C

// ---------------- workspace layout (floats) ----------------
#define WS_QKV     0u          // [BN][2304]
#define WS_WSP     9437184u    // fused wide gemm out [BN][1664]: idout|hdn|plig(+pad)
#define WS_GL      16252928u   // gate logits [BN][128] (12 used)
#define WS_QS      16777216u
#define WS_KNT     19922944u
#define WS_U       23068672u
#define WS_W       26214400u
#define WS_AT      29360128u
#define WS_DELTA   32505856u
#define WS_CTX     35651584u
#define WS_ENT     38797312u   // [1024] per-block entropy slots
#define WS_FIRST   38798336u   // firsT [3][768]
#define WS_FIRLT   38800640u   // firlT [7][768]
#define WS_CBIAS   38806016u   // [1664]
#define WS_GBIAS   38807680u   // [128]
#define WS_BF16    38807808u   // float offset; shorts region starts here
// short offsets within the bf16 region:
#define SH_XB      0u          // [BN][768]
#define SH_WQKVT   3145728u    // [2304][768]
#define SH_WCATT   4915200u    // [1664][768]: w_idT | w_g1T | wcombT(72)+pad
#define SH_G2T     6193152u    // [128][768]
#define SH_WPROJT  6291456u    // [768][768]
#define SH_HDNB    6881280u    // [BN][768]
#define SH_CTXB    10027008u   // [BN][768]

typedef __attribute__((ext_vector_type(8))) short bf16x8;
typedef __attribute__((ext_vector_type(4))) float f32x4;

__device__ __forceinline__ float sigmoidf_(float x) { return 1.f / (1.f + __expf(-x)); }
__device__ __forceinline__ float geluf_(float x) {
    float t = tanhf(0.7978845608028654f * (x + 0.044715f * x * x * x));
    return 0.5f * x * (1.f + t);
}
__device__ __forceinline__ short bf16c(float f) {
    union { float f; unsigned u; } a; a.f = f;
    unsigned r = a.u + 0x7fffu + ((a.u >> 16) & 1u);
    return (short)(r >> 16);
}
__device__ __forceinline__ void gload16(const void* g, void* l) {
    __builtin_amdgcn_global_load_lds(
        (const __attribute__((address_space(1))) unsigned*)g,
        (__attribute__((address_space(3))) unsigned*)l, 16, 0, 0);
}
// MFMA fragment read from a 64x64 bf16 LDS array with per-row XOR granule swizzle.
__device__ __forceinline__ bf16x8 frag_(const short* arr, int row, int kc, int quad) {
    return *(const bf16x8*)&arr[row * 64 + (((kc * 4 + quad) ^ (row & 7)) << 3)];
}

// ---------------- f32 -> bf16 row-preserving convert ----------------
__global__ __launch_bounds__(256) void convert_x_kernel(const float* __restrict__ src,
        short* __restrict__ dst, int n4) {
    int i = blockIdx.x * 256 + threadIdx.x;
    if (i < n4) {
        float4 v = *(const float4*)&src[(size_t)i * 4];
        short4 o;
        o.x = bf16c(v.x); o.y = bf16c(v.y); o.z = bf16c(v.z); o.w = bf16c(v.w);
        *(short4*)&dst[(size_t)i * 4] = o;
    }
}

// ---------------- weight transpose + bf16 convert: W[K,Nw] -> WT[Nw,K] ------
__global__ __launch_bounds__(256) void convert_w_kernel(const float* __restrict__ w_qkv,
        const float* __restrict__ w_id, const float* __restrict__ w_g1,
        const float* __restrict__ w_proj, short* __restrict__ wqkvT,
        short* __restrict__ wcatT, short* __restrict__ wprojT) {
    __shared__ float t[64][65];
    const int z = blockIdx.z;
    const float* src; short* dst; int Nw;
    if (z == 0)      { src = w_qkv;  dst = wqkvT;              Nw = 2304; }
    else if (z == 1) { src = w_id;   dst = wcatT;              Nw = 768; }
    else if (z == 2) { src = w_g1;   dst = wcatT + 768 * 768;  Nw = 768; }
    else             { src = w_proj; dst = wprojT;             Nw = 768; }
    const int n0 = blockIdx.y * 64;
    if (n0 >= Nw) return;
    const int k0 = blockIdx.x * 64;
    const int tid = threadIdx.x;
    for (int e = tid; e < 1024; e += 256) {
        int r = e >> 4, c4 = (e & 15) * 4;
        float4 v = *(const float4*)&src[(size_t)(k0 + r) * Nw + n0 + c4];
        t[c4 + 0][r] = v.x; t[c4 + 1][r] = v.y;
        t[c4 + 2][r] = v.z; t[c4 + 3][r] = v.w;
    }
    __syncthreads();
    for (int e = tid; e < 1024; e += 256) {
        int r = e >> 4, c4 = (e & 15) * 4;
        short4 o;
        o.x = bf16c(t[r][c4 + 0]); o.y = bf16c(t[r][c4 + 1]);
        o.z = bf16c(t[r][c4 + 2]); o.w = bf16c(t[r][c4 + 3]);
        *(short4*)&dst[(size_t)(n0 + r) * 768 + k0 + c4] = o;
    }
}

// ---------------- small prep: wcombT into wcatT tail, g2T, biases, FIR^T -----
__global__ __launch_bounds__(256) void prep_kernel(const float* __restrict__ wp,
        const float* __restrict__ wig, const float* __restrict__ bp,
        const float* __restrict__ big, const float* __restrict__ bg1,
        const float* __restrict__ bg2, const float* __restrict__ wg2,
        const float* __restrict__ firs, const float* __restrict__ firl,
        short* __restrict__ wcatT, short* __restrict__ g2T,
        float* __restrict__ cbias, float* __restrict__ gbias,
        float* __restrict__ firsT, float* __restrict__ firlT) {
    int i = blockIdx.x * 256 + threadIdx.x;
    if (i < 98304) {
        int r = i / 768, k = i % 768;
        float wv = 0.f;
        if (r < 60) wv = wp[k * 60 + r];
        else if (r < 72) wv = wig[k * 12 + (r - 60)];
        wcatT[(size_t)(1536 + r) * 768 + k] = (r < 72) ? bf16c(wv) : (short)0;
        g2T[(size_t)r * 768 + k] = (r < 12) ? bf16c(wg2[k * 12 + r]) : (short)0;
    }
    if (i < 1664) {
        float bv = 0.f;
        if (i >= 768 && i < 1536) bv = bg1[i - 768];
        else if (i >= 1536 && i < 1596) bv = bp[i - 1536];
        else if (i >= 1596 && i < 1608) bv = big[i - 1596];
        cbias[i] = bv;
    }
    if (i < 128) gbias[i] = (i < 12) ? bg2[i] : 0.f;
    if (i < 2304) { int t = i / 768, e = i % 768; firsT[t * 768 + e] = firs[e * 3 + t]; }
    if (i < 5376) { int t = i / 768, e = i % 768; firlT[t * 768 + e] = firl[e * 7 + t]; }
}

// ---------------- bf16 MFMA GEMM: C[M,N] = A[M,K] @ BT[N,K]^T + bias ---------
// gelu applied for cols in [glo,ghi); if C2 != null, bf16 copy of that range
// written to C2[row][col-glo] (width 768). M%128==0, N%128==0, K%64==0.
__global__ __launch_bounds__(256) void gemm_mfma(const short* __restrict__ A,
        const short* __restrict__ BT, const float* __restrict__ bias,
        float* __restrict__ C, int M, int N, int K, int glo, int ghi,
        short* __restrict__ C2) {
    __shared__ short As[128 * 64];
    __shared__ short Bs[128 * 64];
    const int tid = threadIdx.x;
    const int lane = tid & 63, w = tid >> 6;
    const int quad = lane >> 4, l15 = lane & 15;
    const int row0 = blockIdx.y * 128, col0 = blockIdx.x * 128;
    const int wm = (w >> 1) * 64, wn = (w & 1) * 64;

    int srow[4]; int scol[4];
#pragma unroll
    for (int i = 0; i < 4; ++i) {
        int G = (w * 4 + i) * 64 + lane;
        int row = G >> 3, g = G & 7;
        srow[i] = row;
        scol[i] = (g ^ (row & 7)) * 8;
    }
    int aoff[4][2], boff[4][2];
#pragma unroll
    for (int mi = 0; mi < 4; ++mi)
#pragma unroll
        for (int kk = 0; kk < 2; ++kk) {
            int ra = wm + mi * 16 + l15;
            aoff[mi][kk] = ra * 128 + (((kk * 4 + quad) ^ (ra & 7)) * 16);
            int rb = wn + mi * 16 + l15;
            boff[mi][kk] = rb * 128 + (((kk * 4 + quad) ^ (rb & 7)) * 16);
        }

    f32x4 acc[4][4];
#pragma unroll
    for (int mi = 0; mi < 4; ++mi)
#pragma unroll
        for (int ni = 0; ni < 4; ++ni) acc[mi][ni] = (f32x4)0.f;

    for (int k0 = 0; k0 < K; k0 += 64) {
#pragma unroll
        for (int i = 0; i < 4; ++i) {
            gload16(&A[(size_t)(row0 + srow[i]) * K + k0 + scol[i]], &As[(w * 4 + i) * 512]);
            gload16(&BT[(size_t)(col0 + srow[i]) * K + k0 + scol[i]], &Bs[(w * 4 + i) * 512]);
        }
        __syncthreads();
#pragma unroll
        for (int kk = 0; kk < 2; ++kk) {
            bf16x8 af[4], bfr[4];
#pragma unroll
            for (int mi = 0; mi < 4; ++mi)
                af[mi] = *(const bf16x8*)((const char*)As + aoff[mi][kk]);
#pragma unroll
            for (int ni = 0; ni < 4; ++ni)
                bfr[ni] = *(const bf16x8*)((const char*)Bs + boff[ni][kk]);
#pragma unroll
            for (int mi = 0; mi < 4; ++mi)
#pragma unroll
                for (int ni = 0; ni < 4; ++ni)
                    acc[mi][ni] = __builtin_amdgcn_mfma_f32_16x16x32_bf16(
                        af[mi], bfr[ni], acc[mi][ni], 0, 0, 0);
        }
        __syncthreads();
    }
#pragma unroll
    for (int ni = 0; ni < 4; ++ni) {
        int col = col0 + wn + ni * 16 + l15;
        float bv = bias ? bias[col] : 0.f;
        bool gel = (col >= glo) && (col < ghi);
#pragma unroll
        for (int mi = 0; mi < 4; ++mi) {
#pragma unroll
            for (int r = 0; r < 4; ++r) {
                int row = row0 + wm + mi * 16 + quad * 4 + r;
                float v = acc[mi][ni][r] + bv;
                if (gel) v = geluf_(v);
                C[(size_t)row * N + col] = v;
                if (C2 && gel) C2[(size_t)row * 768 + (col - glo)] = bf16c(v);
            }
        }
    }
}

// ---------------- delta-rule preprocessing (MFMA + blocked inversion) --------
__global__ __launch_bounds__(256) void pre_kernel(const float* __restrict__ qkv,
        float* __restrict__ Qs, float* __restrict__ KnT, float* __restrict__ U,
        float* __restrict__ W, float* __restrict__ At) {
    __shared__ float ts[64][68];
    __shared__ float zbuf[16][68];
    __shared__ short kn[4096];
    __shared__ short knt[4096];
    __shared__ short qsb[4096];
    __shared__ short vtb[4096];
    __shared__ short tb[4096];
    const int blk = blockIdx.x;
    const int c = blk & 15, bh = blk >> 4;
    const int b = bh / Hh, h = bh % Hh;
    const int tid = threadIdx.x;
    const int lane = tid & 63, w = tid >> 6;
    const int quad = lane >> 4, l15 = lane & 15;
    const int r = tid >> 2, d0 = (tid & 3) * 16;
    const size_t rowbase = ((size_t)(b * Nn + c * 64)) * (3 * Cc) + h * 64;
    const size_t base2 = (size_t)blk * 4096;

    {
        float kf[16];
        const float* kp = &qkv[rowbase + (size_t)r * 2304 + 768 + d0];
#pragma unroll
        for (int t4 = 0; t4 < 4; ++t4) {
            float4 v = *(const float4*)&kp[t4 * 4];
            kf[t4 * 4 + 0] = v.x; kf[t4 * 4 + 1] = v.y;
            kf[t4 * 4 + 2] = v.z; kf[t4 * 4 + 3] = v.w;
        }
        float ss = 0.f;
#pragma unroll
        for (int t = 0; t < 16; ++t) ss += kf[t] * kf[t];
        ss += __shfl_xor(ss, 1);
        ss += __shfl_xor(ss, 2);
        float invn = 1.f / (sqrtf(ss) + 1e-6f);
#pragma unroll
        for (int t = 0; t < 16; ++t) kf[t] *= invn;
#pragma unroll
        for (int t = 0; t < 16; ++t) KnT[base2 + (size_t)(d0 + t) * 64 + r] = kf[t];
        bf16x8 g0, g1;
#pragma unroll
        for (int t = 0; t < 8; ++t) { g0[t] = bf16c(kf[t]); g1[t] = bf16c(kf[8 + t]); }
        int gb = d0 >> 3;
        *(bf16x8*)&kn[r * 64 + (((gb + 0) ^ (r & 7)) << 3)] = g0;
        *(bf16x8*)&kn[r * 64 + (((gb + 1) ^ (r & 7)) << 3)] = g1;
#pragma unroll
        for (int t = 0; t < 16; ++t) {
            int d = d0 + t;
            knt[d * 64 + (((r >> 3) ^ (d & 7)) << 3) + (r & 7)] = bf16c(kf[t]);
        }
    }
    {
        float qf[16];
        const float* qp = &qkv[rowbase + (size_t)r * 2304 + d0];
#pragma unroll
        for (int t4 = 0; t4 < 4; ++t4) {
            float4 v = *(const float4*)&qp[t4 * 4];
            qf[t4 * 4 + 0] = v.x * 0.125f; qf[t4 * 4 + 1] = v.y * 0.125f;
            qf[t4 * 4 + 2] = v.z * 0.125f; qf[t4 * 4 + 3] = v.w * 0.125f;
        }
#pragma unroll
        for (int t4 = 0; t4 < 4; ++t4) {
            float4 o; o.x = qf[t4 * 4]; o.y = qf[t4 * 4 + 1];
            o.z = qf[t4 * 4 + 2]; o.w = qf[t4 * 4 + 3];
            *(float4*)&Qs[base2 + (size_t)r * 64 + d0 + t4 * 4] = o;
        }
        bf16x8 g0, g1;
#pragma unroll
        for (int t = 0; t < 8; ++t) { g0[t] = bf16c(qf[t]); g1[t] = bf16c(qf[8 + t]); }
        int gb = d0 >> 3;
        *(bf16x8*)&qsb[r * 64 + (((gb + 0) ^ (r & 7)) << 3)] = g0;
        *(bf16x8*)&qsb[r * 64 + (((gb + 1) ^ (r & 7)) << 3)] = g1;
    }
    {
        const float* vp = &qkv[rowbase + (size_t)r * 2304 + 1536 + d0];
#pragma unroll
        for (int t4 = 0; t4 < 4; ++t4) {
            float4 v = *(const float4*)&vp[t4 * 4];
            int d = d0 + t4 * 4;
            vtb[(d + 0) * 64 + (((r >> 3) ^ ((d + 0) & 7)) << 3) + (r & 7)] = bf16c(v.x);
            vtb[(d + 1) * 64 + (((r >> 3) ^ ((d + 1) & 7)) << 3) + (r & 7)] = bf16c(v.y);
            vtb[(d + 2) * 64 + (((r >> 3) ^ ((d + 2) & 7)) << 3) + (r & 7)] = bf16c(v.z);
            vtb[(d + 3) * 64 + (((r >> 3) ^ ((d + 3) & 7)) << 3) + (r & 7)] = bf16c(v.w);
        }
    }
    __syncthreads();

    {
        const int ar = w * 16 + l15;
        bf16x8 aK0 = frag_(kn, ar, 0, quad), aK1 = frag_(kn, ar, 1, quad);
        bf16x8 aQ0 = frag_(qsb, ar, 0, quad), aQ1 = frag_(qsb, ar, 1, quad);
        f32x4 accA[4], accT[4];
#pragma unroll
        for (int ni = 0; ni < 4; ++ni) {
            int br = ni * 16 + l15;
            bf16x8 b0 = frag_(kn, br, 0, quad), b1 = frag_(kn, br, 1, quad);
            accA[ni] = __builtin_amdgcn_mfma_f32_16x16x32_bf16(aK0, b0, (f32x4)0.f, 0, 0, 0);
            accA[ni] = __builtin_amdgcn_mfma_f32_16x16x32_bf16(aK1, b1, accA[ni], 0, 0, 0);
            accT[ni] = __builtin_amdgcn_mfma_f32_16x16x32_bf16(aQ0, b0, (f32x4)0.f, 0, 0, 0);
            accT[ni] = __builtin_amdgcn_mfma_f32_16x16x32_bf16(aQ1, b1, accT[ni], 0, 0, 0);
        }
#pragma unroll
        for (int ni = 0; ni < 4; ++ni)
#pragma unroll
            for (int reg = 0; reg < 4; ++reg) {
                int row = w * 16 + quad * 4 + reg;
                int col = ni * 16 + l15;
                ts[row][col] = (col < row) ? accA[ni][reg] : 0.f;
                At[base2 + (size_t)row * 64 + col] = (col <= row) ? accT[ni][reg] : 0.f;
            }
    }
    __syncthreads();

    {
        const int R0 = w * 16;
        if (lane < 16) {
            const int j = lane;
#pragma unroll 1
            for (int i = 0; i < 16; ++i) {
                float s = 0.f;
                for (int m = 0; m < i; ++m) s += ts[R0 + i][R0 + m] * ts[R0 + m][R0 + j];
                ts[R0 + i][R0 + j] = ((j == i) ? 1.f : 0.f) - s;
            }
        }
    }
    __syncthreads();
#pragma unroll 1
    for (int I = 1; I < 4; ++I) {
        const int ncol = I * 16;
        for (int e = tid; e < 16 * ncol; e += 256) {
            int i = e / ncol, jj = e % ncol;
            float s = 0.f;
            for (int m = jj; m < ncol; ++m) s += ts[ncol + i][m] * ts[m][jj];
            zbuf[i][jj] = s;
        }
        __syncthreads();
        for (int e = tid; e < 16 * ncol; e += 256) {
            int i = e / ncol, jj = e % ncol;
            float s = 0.f;
            for (int ml = 0; ml <= i; ++ml) s += ts[ncol + i][ncol + ml] * zbuf[ml][jj];
            ts[ncol + i][jj] = -s;
        }
        __syncthreads();
    }
    for (int e = tid; e < 512; e += 256) {
        int row = e >> 3, g = e & 7;
        bf16x8 o;
#pragma unroll
        for (int t = 0; t < 8; ++t) o[t] = bf16c(ts[row][g * 8 + t]);
        *(bf16x8*)&tb[row * 64 + ((g ^ (row & 7)) << 3)] = o;
    }
    __syncthreads();

    {
        const int ar = w * 16 + l15;
        bf16x8 aT0 = frag_(tb, ar, 0, quad), aT1 = frag_(tb, ar, 1, quad);
        f32x4 accW[4], accU[4];
#pragma unroll
        for (int ni = 0; ni < 4; ++ni) {
            int br = ni * 16 + l15;
            bf16x8 b0 = frag_(knt, br, 0, quad), b1 = frag_(knt, br, 1, quad);
            bf16x8 c0 = frag_(vtb, br, 0, quad), c1 = frag_(vtb, br, 1, quad);
            accW[ni] = __builtin_amdgcn_mfma_f32_16x16x32_bf16(aT0, b0, (f32x4)0.f, 0, 0, 0);
            accW[ni] = __builtin_amdgcn_mfma_f32_16x16x32_bf16(aT1, b1, accW[ni], 0, 0, 0);
            accU[ni] = __builtin_amdgcn_mfma_f32_16x16x32_bf16(aT0, c0, (f32x4)0.f, 0, 0, 0);
            accU[ni] = __builtin_amdgcn_mfma_f32_16x16x32_bf16(aT1, c1, accU[ni], 0, 0, 0);
        }
#pragma unroll
        for (int ni = 0; ni < 4; ++ni)
#pragma unroll
            for (int reg = 0; reg < 4; ++reg) {
                int row = w * 16 + quad * 4 + reg;
                int col = ni * 16 + l15;
                W[base2 + (size_t)row * 64 + col] = accW[ni][reg];
                U[base2 + (size_t)row * 64 + col] = accU[ni][reg];
            }
    }
}

// ---------------- sequential chunk scan, split over 16 value-dims per block ----
__global__ __launch_bounds__(256) void scan_kernel(const float* __restrict__ Qs,
        const float* __restrict__ KnT, const float* __restrict__ U,
        const float* __restrict__ W, const float* __restrict__ At,
        float* __restrict__ delta) {
    __shared__ float t0[64][68];
    __shared__ float t1[64][68];
    __shared__ float S[64][16];
    __shared__ float ut[64][16];
    const int bh = blockIdx.x;
    const int b = bh / Hh, h = bh % Hh;
    const int g0 = blockIdx.y * 16;
    const int tid = threadIdx.x;
    const int r = tid >> 2, dq = (tid & 3) * 4;
    for (int e = tid; e < 1024; e += 256) ((float*)S)[e] = 0.f;
    __syncthreads();
    for (int c = 0; c < 16; ++c) {
        const size_t base = ((size_t)(bh * 16 + c)) * 4096;
        for (int e4 = tid; e4 < 1024; e4 += 256) {
            int rr = e4 >> 4, d4 = (e4 & 15) * 4;
            *(float4*)&t0[rr][d4] = *(const float4*)&W[base + rr * 64 + d4];
            *(float4*)&t1[rr][d4] = *(const float4*)&Qs[base + rr * 64 + d4];
        }
        const float4 uv = *(const float4*)&U[base + r * 64 + g0 + dq];
        __syncthreads();
        float4 o1 = make_float4(0.f, 0.f, 0.f, 0.f);
        float4 utv = uv;
#pragma unroll 4
        for (int m = 0; m < 64; m += 4) {
            float wv[4], qv[4];
            *(float4*)&wv[0] = *(const float4*)&t0[r][m];
            *(float4*)&qv[0] = *(const float4*)&t1[r][m];
#pragma unroll
            for (int mm = 0; mm < 4; ++mm) {
                const float4 sv = *(const float4*)&S[m + mm][dq];
                utv.x -= wv[mm] * sv.x; utv.y -= wv[mm] * sv.y;
                utv.z -= wv[mm] * sv.z; utv.w -= wv[mm] * sv.w;
                o1.x += qv[mm] * sv.x; o1.y += qv[mm] * sv.y;
                o1.z += qv[mm] * sv.z; o1.w += qv[mm] * sv.w;
            }
        }
        *(float4*)&ut[r][dq] = utv;
        __syncthreads();
        for (int e4 = tid; e4 < 1024; e4 += 256) {
            int rr = e4 >> 4, d4 = (e4 & 15) * 4;
            *(float4*)&t0[rr][d4] = *(const float4*)&At[base + rr * 64 + d4];
            *(float4*)&t1[rr][d4] = *(const float4*)&KnT[base + rr * 64 + d4];
        }
        __syncthreads();
        float4 o2 = o1;
        float4 sacc = *(const float4*)&S[r][dq];
#pragma unroll 4
        for (int m = 0; m < 64; m += 4) {
            float av[4], kv[4];
            *(float4*)&av[0] = *(const float4*)&t0[r][m];
            *(float4*)&kv[0] = *(const float4*)&t1[r][m];
#pragma unroll
            for (int mm = 0; mm < 4; ++mm) {
                const float4 uvm = *(const float4*)&ut[m + mm][dq];
                o2.x += av[mm] * uvm.x; o2.y += av[mm] * uvm.y;
                o2.z += av[mm] * uvm.z; o2.w += av[mm] * uvm.w;
                sacc.x += kv[mm] * uvm.x; sacc.y += kv[mm] * uvm.y;
                sacc.z += kv[mm] * uvm.z; sacc.w += kv[mm] * uvm.w;
            }
        }
        *(float4*)&S[r][dq] = sacc;
        const size_t orow = ((size_t)(b * Nn + c * 64 + r)) * Cc + h * 64 + g0 + dq;
        *(float4*)&delta[orow] = o2;
        __syncthreads();
    }
}

// ---------------- FIR + head-mix + prune softmax + gates + entropies ----------
// One block per (b, 4 consecutive n). No global atomics: per-block ent slot.
__global__ __launch_bounds__(256) void paths_kernel(const float* __restrict__ qkv,
        const float* __restrict__ delta, const float* __restrict__ wsp,
        const float* __restrict__ gl, const float* __restrict__ mixw,
        const float* __restrict__ idst, const float* __restrict__ firsT,
        const float* __restrict__ firlT, float* __restrict__ context,
        float* __restrict__ entslots) {
    __shared__ float vt[10][768];
    __shared__ float fsb[768], flb[768];
    __shared__ float wts4[4][60], gate4[4][12], idg4[4][12];
    __shared__ float entb[48];
    const int blk = blockIdx.x;
    const int b = blk >> 8, n0 = (blk & 255) * 4;
    const int tid = threadIdx.x;

    // stage v rows n0-6 .. n0+3
    for (int t = tid; t < 1920; t += 256) {
        int row = t / 192, c4 = (t % 192) * 4;
        int np = n0 - 6 + row;
        float4 v = make_float4(0.f, 0.f, 0.f, 0.f);
        if (np >= 0) v = *(const float4*)&qkv[((size_t)((b << 10) + np)) * 2304 + 1536 + c4];
        *(float4*)&vt[row][c4] = v;
    }
    // gates (48 threads: 4 n x 12 h)
    if (tid < 48) {
        int ni = tid / 12, h = tid % 12;
        int bn = (b << 10) + n0 + ni;
        const float* pb = &wsp[(size_t)bn * 1664 + 1536];
        float lg[5]; float mx = -1e30f;
#pragma unroll
        for (int p = 0; p < 5; ++p) { lg[p] = pb[h * 5 + p]; mx = fmaxf(mx, lg[p]); }
        float sum = 0.f;
#pragma unroll
        for (int p = 0; p < 5; ++p) { lg[p] = __expf(lg[p] - mx); sum += lg[p]; }
        float e1 = 0.f;
#pragma unroll
        for (int p = 0; p < 5; ++p) {
            float wv = lg[p] / sum;
            wts4[ni][h * 5 + p] = wv;
            e1 += wv * logf(wv + 1e-8f);
        }
        float g = sigmoidf_(gl[(size_t)bn * 128 + h]);
        gate4[ni][h] = g;
        float e2 = g * logf(g + 1e-8f) + (1.f - g) * logf(1.f - g + 1e-8f);
        idg4[ni][h] = sigmoidf_(pb[60 + h]) * sigmoidf_(idst[h]);
        entb[tid] = e1 + e2;
    }
    // FIR weights in registers (hoisted across ni)
    float4 wl[7], wsv[3];
    if (tid < 192) {
        int c4 = tid * 4;
#pragma unroll
        for (int t = 0; t < 7; ++t) wl[t] = *(const float4*)&firlT[t * 768 + c4];
#pragma unroll
        for (int t = 0; t < 3; ++t) wsv[t] = *(const float4*)&firsT[t * 768 + c4];
    }
    __syncthreads();

#pragma unroll 1
    for (int ni = 0; ni < 4; ++ni) {
        if (tid < 192) {
            int c4 = tid * 4;
            float4 as = make_float4(0.f, 0.f, 0.f, 0.f);
            float4 al = make_float4(0.f, 0.f, 0.f, 0.f);
#pragma unroll
            for (int t = 0; t < 7; ++t) {
                float4 vv = *(const float4*)&vt[ni + t][c4];
                al.x += wl[t].x * vv.x; al.y += wl[t].y * vv.y;
                al.z += wl[t].z * vv.z; al.w += wl[t].w * vv.w;
                if (t >= 4) {
                    as.x += wsv[t - 4].x * vv.x; as.y += wsv[t - 4].y * vv.y;
                    as.z += wsv[t - 4].z * vv.z; as.w += wsv[t - 4].w * vv.w;
                }
            }
            *(float4*)&fsb[c4] = as;
            *(float4*)&flb[c4] = al;
        }
        __syncthreads();
        if (tid < 192) {
            int c4 = tid * 4;
            int h = c4 >> 6, d = c4 & 63;
            float4 ms = *(const float4*)&fsb[c4];
            float4 ml = *(const float4*)&flb[c4];
#pragma unroll
            for (int hh = 0; hh < 12; ++hh) {
                float mw = mixw[hh * 12 + h];
                float4 fsv = *(const float4*)&fsb[hh * 64 + d];
                float4 flv = *(const float4*)&flb[hh * 64 + d];
                ms.x += mw * fsv.x; ms.y += mw * fsv.y;
                ms.z += mw * fsv.z; ms.w += mw * fsv.w;
                ml.x += mw * flv.x; ml.y += mw * flv.y;
                ml.z += mw * flv.z; ml.w += mw * flv.w;
            }
            int bn = (b << 10) + n0 + ni;
            float4 dl = *(const float4*)&delta[(size_t)bn * 768 + c4];
            float4 iv = *(const float4*)&wsp[(size_t)bn * 1664 + c4];
            float4 vv = *(const float4*)&vt[ni + 6][c4];
            float ig = idg4[ni][h];
            const float* wp = &wts4[ni][h * 5];
            float4 pr;
            pr.x = ms.x * wp[0] + ml.x * wp[1] + dl.x * wp[2] + vv.x * wp[3] + iv.x * ig * wp[4];
            pr.y = ms.y * wp[0] + ml.y * wp[1] + dl.y * wp[2] + vv.y * wp[3] + iv.y * ig * wp[4];
            pr.z = ms.z * wp[0] + ml.z * wp[1] + dl.z * wp[2] + vv.z * wp[3] + iv.z * ig * wp[4];
            pr.w = ms.w * wp[0] + ml.w * wp[1] + dl.w * wp[2] + vv.w * wp[3] + iv.w * ig * wp[4];
            float g = gate4[ni][h];
            pr.x *= g; pr.y *= g; pr.z *= g; pr.w *= g;
            *(float4*)&context[(size_t)bn * 768 + c4] = pr;
        }
        __syncthreads();
    }
    if (tid == 0) {
        float s = 0.f;
#pragma unroll
        for (int i = 0; i < 48; ++i) s += entb[i];
        entslots[blk] = s;
    }
}

__global__ __launch_bounds__(256) void finalize_kernel(const float* __restrict__ slots,
        float* __restrict__ out) {
    __shared__ float red[256];
    const int tid = threadIdx.x;
    float s = 0.f;
    for (int i = tid; i < 1024; i += 256) s += slots[i];
    red[tid] = s;
    __syncthreads();
    for (int off = 128; off > 0; off >>= 1) {
        if (tid < off) red[tid] += red[tid + off];
        __syncthreads();
    }
    if (tid == 0) out[OUT_ELEMS] = -red[0] * (1.f / 49152.f);
}

extern "C" void kernel_launch(void* const* d_in, const int* in_sizes, int n_in,
                              void* d_out, int out_size, void* d_ws, size_t ws_size,
                              hipStream_t stream) {
    const float* x        = (const float*)d_in[0];
    const float* w_qkv    = (const float*)d_in[1];
    const float* w_proj   = (const float*)d_in[2];
    const float* b_proj   = (const float*)d_in[3];
    const float* fir_s_w  = (const float*)d_in[4];
    const float* fir_l_w  = (const float*)d_in[5];
    const float* mixw     = (const float*)d_in[6];
    const float* w_prune  = (const float*)d_in[7];
    const float* b_prune  = (const float*)d_in[8];
    const float* w_g1     = (const float*)d_in[9];
    const float* b_g1     = (const float*)d_in[10];
    const float* w_g2     = (const float*)d_in[11];
    const float* b_g2     = (const float*)d_in[12];
    const float* w_id     = (const float*)d_in[13];
    const float* id_st    = (const float*)d_in[14];
    const float* w_idgate = (const float*)d_in[15];
    const float* b_idgate = (const float*)d_in[16];
    float* out = (float*)d_out;
    float* ws  = (float*)d_ws;

    float* qkv   = ws + WS_QKV;
    float* wsp   = ws + WS_WSP;
    float* gl    = ws + WS_GL;
    float* Qs    = ws + WS_QS;
    float* KnT   = ws + WS_KNT;
    float* Ub    = ws + WS_U;
    float* Wb    = ws + WS_W;
    float* Atb   = ws + WS_AT;
    float* delta = ws + WS_DELTA;
    float* ctx   = ws + WS_CTX;
    float* ent   = ws + WS_ENT;
    float* firsT = ws + WS_FIRST;
    float* firlT = ws + WS_FIRLT;
    float* cbias = ws + WS_CBIAS;
    float* gbias = ws + WS_GBIAS;
    short* wsh   = (short*)(ws + WS_BF16);
    short* xb     = wsh + SH_XB;
    short* wqkvT  = wsh + SH_WQKVT;
    short* wcatT  = wsh + SH_WCATT;
    short* g2T    = wsh + SH_G2T;
    short* wprojT = wsh + SH_WPROJT;
    short* hdnb   = wsh + SH_HDNB;
    short* ctxb   = wsh + SH_CTXB;

    // conversions + prep
    convert_x_kernel<<<dim3(3072), 256, 0, stream>>>(x, xb, 786432);
    convert_w_kernel<<<dim3(12, 36, 4), 256, 0, stream>>>(w_qkv, w_id, w_g1, w_proj,
                                                          wqkvT, wcatT, wprojT);
    prep_kernel<<<dim3(384), 256, 0, stream>>>(w_prune, w_idgate, b_prune, b_idgate,
                                               b_g1, b_g2, w_g2, fir_s_w, fir_l_w,
                                               wcatT, g2T, cbias, gbias, firsT, firlT);
    // projections (all bf16 MFMA)
    gemm_mfma<<<dim3(18, 32), 256, 0, stream>>>(xb, wqkvT, nullptr, qkv, BN, 2304, 768,
                                                0, 0, nullptr);
    gemm_mfma<<<dim3(13, 32), 256, 0, stream>>>(xb, wcatT, cbias, wsp, BN, 1664, 768,
                                                768, 1536, hdnb);
    gemm_mfma<<<dim3(1, 32), 256, 0, stream>>>(hdnb, g2T, gbias, gl, BN, 128, 768,
                                               0, 0, nullptr);
    // delta rule (beta == 1 identically: softmax row-sums)
    pre_kernel<<<dim3(BH * NC), 256, 0, stream>>>(qkv, Qs, KnT, Ub, Wb, Atb);
    scan_kernel<<<dim3(BH, 4), 256, 0, stream>>>(Qs, KnT, Ub, Wb, Atb, delta);
    // FIR + mix + prune + gates + entropies
    paths_kernel<<<dim3(1024), 256, 0, stream>>>(qkv, delta, wsp, gl, mixw, id_st,
                                                 firsT, firlT, ctx, ent);
    // output projection
    convert_x_kernel<<<dim3(3072), 256, 0, stream>>>(ctx, ctxb, 786432);
    gemm_mfma<<<dim3(6, 32), 256, 0, stream>>>(ctxb, wprojT, b_proj, out, BN, 768, 768,
                                               0, 0, nullptr);
    finalize_kernel<<<1, 256, 0, stream>>>(ent, out);
}

// Round 5
// 312.117 us; speedup vs baseline: 3.8229x; 1.1897x over previous
//
#include <hip/hip_runtime.h>
#include <hip/hip_bf16.h>
#include <math.h>

// Problem dims (fixed by setup_inputs)
#define Bz 4
#define Nn 1024
#define Cc 768
#define Hh 12
#define Dd 64
#define BN 4096          // B*N
#define NC 16            // chunks per sequence
#define BH 48            // B*H
#define OUT_ELEMS 3145728  // BN*C

// ---------------- workspace layout (floats) ----------------
#define WS_QKV     0u          // [BN][2304]
#define WS_WSP     9437184u    // fused wide gemm out [BN][1664]: idout|hdn|plig(+pad)
#define WS_GL      16252928u   // gate logits [BN][128] (12 used)
#define WS_QS      16777216u   // (shorts) Qsb16 | Kntb16  (768 tiles x 4096 bf16 each)
#define WS_KNT     19922944u   // (shorts) Wb16 | Atb16
#define WS_U       23068672u   // f32 [768 tiles][4096]
#define WS_DELTA   32505856u
#define WS_CTX     35651584u
#define WS_ENT     38797312u   // [1024] per-block entropy slots
#define WS_FIRST   38798336u   // firsT [3][768]
#define WS_FIRLT   38800640u   // firlT [7][768]
#define WS_CBIAS   38806016u   // [1664]
#define WS_GBIAS   38807680u   // [128]
#define WS_BF16    38807808u   // float offset; shorts region starts here
// short offsets within the bf16 region:
#define SH_XB      0u          // [BN][768]
#define SH_WQKVT   3145728u    // [2304][768]
#define SH_WCATT   4915200u    // [1664][768]: w_idT | w_g1T | wcombT(72)+pad
#define SH_G2T     6193152u    // [128][768]
#define SH_WPROJT  6291456u    // [768][768]
#define SH_HDNB    6881280u    // [BN][768]
#define SH_CTXB    10027008u   // [BN][768]

typedef __attribute__((ext_vector_type(8))) short bf16x8;
typedef __attribute__((ext_vector_type(4))) float f32x4;

__device__ __forceinline__ float sigmoidf_(float x) { return 1.f / (1.f + __expf(-x)); }
__device__ __forceinline__ float geluf_(float x) {
    float t = tanhf(0.7978845608028654f * (x + 0.044715f * x * x * x));
    return 0.5f * x * (1.f + t);
}
__device__ __forceinline__ short bf16c(float f) {
    union { float f; unsigned u; } a; a.f = f;
    unsigned r = a.u + 0x7fffu + ((a.u >> 16) & 1u);
    return (short)(r >> 16);
}
__device__ __forceinline__ void gload16(const void* g, void* l) {
    __builtin_amdgcn_global_load_lds(
        (const __attribute__((address_space(1))) unsigned*)g,
        (__attribute__((address_space(3))) unsigned*)l, 16, 0, 0);
}
// MFMA fragment read from a 64x64 bf16 LDS array with per-row XOR granule swizzle.
__device__ __forceinline__ bf16x8 frag_(const short* arr, int row, int kc, int quad) {
    return *(const bf16x8*)&arr[row * 64 + (((kc * 4 + quad) ^ (row & 7)) << 3)];
}

// ---------------- f32 -> bf16 row-preserving convert ----------------
__global__ __launch_bounds__(256) void convert_x_kernel(const float* __restrict__ src,
        short* __restrict__ dst, int n4) {
    int i = blockIdx.x * 256 + threadIdx.x;
    if (i < n4) {
        float4 v = *(const float4*)&src[(size_t)i * 4];
        short4 o;
        o.x = bf16c(v.x); o.y = bf16c(v.y); o.z = bf16c(v.z); o.w = bf16c(v.w);
        *(short4*)&dst[(size_t)i * 4] = o;
    }
}

// ---------------- weight transpose + bf16 convert: W[K,Nw] -> WT[Nw,K] ------
__global__ __launch_bounds__(256) void convert_w_kernel(const float* __restrict__ w_qkv,
        const float* __restrict__ w_id, const float* __restrict__ w_g1,
        const float* __restrict__ w_proj, short* __restrict__ wqkvT,
        short* __restrict__ wcatT, short* __restrict__ wprojT) {
    __shared__ float t[64][65];
    const int z = blockIdx.z;
    const float* src; short* dst; int Nw;
    if (z == 0)      { src = w_qkv;  dst = wqkvT;              Nw = 2304; }
    else if (z == 1) { src = w_id;   dst = wcatT;              Nw = 768; }
    else if (z == 2) { src = w_g1;   dst = wcatT + 768 * 768;  Nw = 768; }
    else             { src = w_proj; dst = wprojT;             Nw = 768; }
    const int n0 = blockIdx.y * 64;
    if (n0 >= Nw) return;
    const int k0 = blockIdx.x * 64;
    const int tid = threadIdx.x;
    for (int e = tid; e < 1024; e += 256) {
        int r = e >> 4, c4 = (e & 15) * 4;
        float4 v = *(const float4*)&src[(size_t)(k0 + r) * Nw + n0 + c4];
        t[c4 + 0][r] = v.x; t[c4 + 1][r] = v.y;
        t[c4 + 2][r] = v.z; t[c4 + 3][r] = v.w;
    }
    __syncthreads();
    for (int e = tid; e < 1024; e += 256) {
        int r = e >> 4, c4 = (e & 15) * 4;
        short4 o;
        o.x = bf16c(t[r][c4 + 0]); o.y = bf16c(t[r][c4 + 1]);
        o.z = bf16c(t[r][c4 + 2]); o.w = bf16c(t[r][c4 + 3]);
        *(short4*)&dst[(size_t)(n0 + r) * 768 + k0 + c4] = o;
    }
}

// ---------------- small prep: wcombT into wcatT tail, g2T, biases, FIR^T -----
__global__ __launch_bounds__(256) void prep_kernel(const float* __restrict__ wp,
        const float* __restrict__ wig, const float* __restrict__ bp,
        const float* __restrict__ big, const float* __restrict__ bg1,
        const float* __restrict__ bg2, const float* __restrict__ wg2,
        const float* __restrict__ firs, const float* __restrict__ firl,
        short* __restrict__ wcatT, short* __restrict__ g2T,
        float* __restrict__ cbias, float* __restrict__ gbias,
        float* __restrict__ firsT, float* __restrict__ firlT) {
    int i = blockIdx.x * 256 + threadIdx.x;
    if (i < 98304) {
        int r = i / 768, k = i % 768;
        float wv = 0.f;
        if (r < 60) wv = wp[k * 60 + r];
        else if (r < 72) wv = wig[k * 12 + (r - 60)];
        wcatT[(size_t)(1536 + r) * 768 + k] = (r < 72) ? bf16c(wv) : (short)0;
        g2T[(size_t)r * 768 + k] = (r < 12) ? bf16c(wg2[k * 12 + r]) : (short)0;
    }
    if (i < 1664) {
        float bv = 0.f;
        if (i >= 768 && i < 1536) bv = bg1[i - 768];
        else if (i >= 1536 && i < 1596) bv = bp[i - 1536];
        else if (i >= 1596 && i < 1608) bv = big[i - 1596];
        cbias[i] = bv;
    }
    if (i < 128) gbias[i] = (i < 12) ? bg2[i] : 0.f;
    if (i < 2304) { int t = i / 768, e = i % 768; firsT[t * 768 + e] = firs[e * 3 + t]; }
    if (i < 5376) { int t = i / 768, e = i % 768; firlT[t * 768 + e] = firl[e * 7 + t]; }
}

// ---------------- bf16 MFMA GEMM: C[M,N] = A[M,K] @ BT[N,K]^T + bias ---------
__global__ __launch_bounds__(256) void gemm_mfma(const short* __restrict__ A,
        const short* __restrict__ BT, const float* __restrict__ bias,
        float* __restrict__ C, int M, int N, int K, int glo, int ghi,
        short* __restrict__ C2) {
    __shared__ short As[128 * 64];
    __shared__ short Bs[128 * 64];
    const int tid = threadIdx.x;
    const int lane = tid & 63, w = tid >> 6;
    const int quad = lane >> 4, l15 = lane & 15;
    const int row0 = blockIdx.y * 128, col0 = blockIdx.x * 128;
    const int wm = (w >> 1) * 64, wn = (w & 1) * 64;

    int srow[4]; int scol[4];
#pragma unroll
    for (int i = 0; i < 4; ++i) {
        int G = (w * 4 + i) * 64 + lane;
        int row = G >> 3, g = G & 7;
        srow[i] = row;
        scol[i] = (g ^ (row & 7)) * 8;
    }
    int aoff[4][2], boff[4][2];
#pragma unroll
    for (int mi = 0; mi < 4; ++mi)
#pragma unroll
        for (int kk = 0; kk < 2; ++kk) {
            int ra = wm + mi * 16 + l15;
            aoff[mi][kk] = ra * 128 + (((kk * 4 + quad) ^ (ra & 7)) * 16);
            int rb = wn + mi * 16 + l15;
            boff[mi][kk] = rb * 128 + (((kk * 4 + quad) ^ (rb & 7)) * 16);
        }

    f32x4 acc[4][4];
#pragma unroll
    for (int mi = 0; mi < 4; ++mi)
#pragma unroll
        for (int ni = 0; ni < 4; ++ni) acc[mi][ni] = (f32x4)0.f;

    for (int k0 = 0; k0 < K; k0 += 64) {
#pragma unroll
        for (int i = 0; i < 4; ++i) {
            gload16(&A[(size_t)(row0 + srow[i]) * K + k0 + scol[i]], &As[(w * 4 + i) * 512]);
            gload16(&BT[(size_t)(col0 + srow[i]) * K + k0 + scol[i]], &Bs[(w * 4 + i) * 512]);
        }
        __syncthreads();
#pragma unroll
        for (int kk = 0; kk < 2; ++kk) {
            bf16x8 af[4], bfr[4];
#pragma unroll
            for (int mi = 0; mi < 4; ++mi)
                af[mi] = *(const bf16x8*)((const char*)As + aoff[mi][kk]);
#pragma unroll
            for (int ni = 0; ni < 4; ++ni)
                bfr[ni] = *(const bf16x8*)((const char*)Bs + boff[ni][kk]);
#pragma unroll
            for (int mi = 0; mi < 4; ++mi)
#pragma unroll
                for (int ni = 0; ni < 4; ++ni)
                    acc[mi][ni] = __builtin_amdgcn_mfma_f32_16x16x32_bf16(
                        af[mi], bfr[ni], acc[mi][ni], 0, 0, 0);
        }
        __syncthreads();
    }
#pragma unroll
    for (int ni = 0; ni < 4; ++ni) {
        int col = col0 + wn + ni * 16 + l15;
        float bv = bias ? bias[col] : 0.f;
        bool gel = (col >= glo) && (col < ghi);
#pragma unroll
        for (int mi = 0; mi < 4; ++mi) {
#pragma unroll
            for (int r = 0; r < 4; ++r) {
                int row = row0 + wm + mi * 16 + quad * 4 + r;
                float v = acc[mi][ni][r] + bv;
                if (gel) v = geluf_(v);
                C[(size_t)row * N + col] = v;
                if (C2 && gel) C2[(size_t)row * 768 + (col - glo)] = bf16c(v);
            }
        }
    }
}

// ---------------- delta-rule preprocessing (MFMA + blocked inversion) --------
// Outputs (per 64x64 chunk tile, bf16 row-major): Qsb16 [r][d], Kntb16 [d][r],
// Wb16 [r][d], Atb16 [r][d] (tril); U f32 [r][64].
__global__ __launch_bounds__(256) void pre_kernel(const float* __restrict__ qkv,
        short* __restrict__ Qsb16, short* __restrict__ Kntb16, float* __restrict__ U,
        short* __restrict__ Wb16, short* __restrict__ Atb16) {
    __shared__ float ts[64][68];
    __shared__ float zbuf[16][68];
    __shared__ short kn[4096];
    __shared__ short knt[4096];
    __shared__ short qsb[4096];
    __shared__ short vtb[4096];
    __shared__ short tb[4096];
    const int blk = blockIdx.x;
    const int c = blk & 15, bh = blk >> 4;
    const int b = bh / Hh, h = bh % Hh;
    const int tid = threadIdx.x;
    const int lane = tid & 63, w = tid >> 6;
    const int quad = lane >> 4, l15 = lane & 15;
    const int r = tid >> 2, d0 = (tid & 3) * 16;
    const size_t rowbase = ((size_t)(b * Nn + c * 64)) * (3 * Cc) + h * 64;
    const size_t base2 = (size_t)blk * 4096;

    {
        float kf[16];
        const float* kp = &qkv[rowbase + (size_t)r * 2304 + 768 + d0];
#pragma unroll
        for (int t4 = 0; t4 < 4; ++t4) {
            float4 v = *(const float4*)&kp[t4 * 4];
            kf[t4 * 4 + 0] = v.x; kf[t4 * 4 + 1] = v.y;
            kf[t4 * 4 + 2] = v.z; kf[t4 * 4 + 3] = v.w;
        }
        float ss = 0.f;
#pragma unroll
        for (int t = 0; t < 16; ++t) ss += kf[t] * kf[t];
        ss += __shfl_xor(ss, 1);
        ss += __shfl_xor(ss, 2);
        float invn = 1.f / (sqrtf(ss) + 1e-6f);
#pragma unroll
        for (int t = 0; t < 16; ++t) kf[t] *= invn;
        bf16x8 g0, g1;
#pragma unroll
        for (int t = 0; t < 8; ++t) { g0[t] = bf16c(kf[t]); g1[t] = bf16c(kf[8 + t]); }
        int gb = d0 >> 3;
        *(bf16x8*)&kn[r * 64 + (((gb + 0) ^ (r & 7)) << 3)] = g0;
        *(bf16x8*)&kn[r * 64 + (((gb + 1) ^ (r & 7)) << 3)] = g1;
#pragma unroll
        for (int t = 0; t < 16; ++t) {
            int d = d0 + t;
            knt[d * 64 + (((r >> 3) ^ (d & 7)) << 3) + (r & 7)] = bf16c(kf[t]);
        }
    }
    {
        float qf[16];
        const float* qp = &qkv[rowbase + (size_t)r * 2304 + d0];
#pragma unroll
        for (int t4 = 0; t4 < 4; ++t4) {
            float4 v = *(const float4*)&qp[t4 * 4];
            qf[t4 * 4 + 0] = v.x * 0.125f; qf[t4 * 4 + 1] = v.y * 0.125f;
            qf[t4 * 4 + 2] = v.z * 0.125f; qf[t4 * 4 + 3] = v.w * 0.125f;
        }
        bf16x8 g0, g1;
#pragma unroll
        for (int t = 0; t < 8; ++t) { g0[t] = bf16c(qf[t]); g1[t] = bf16c(qf[8 + t]); }
        int gb = d0 >> 3;
        *(bf16x8*)&qsb[r * 64 + (((gb + 0) ^ (r & 7)) << 3)] = g0;
        *(bf16x8*)&qsb[r * 64 + (((gb + 1) ^ (r & 7)) << 3)] = g1;
    }
    {
        const float* vp = &qkv[rowbase + (size_t)r * 2304 + 1536 + d0];
#pragma unroll
        for (int t4 = 0; t4 < 4; ++t4) {
            float4 v = *(const float4*)&vp[t4 * 4];
            int d = d0 + t4 * 4;
            vtb[(d + 0) * 64 + (((r >> 3) ^ ((d + 0) & 7)) << 3) + (r & 7)] = bf16c(v.x);
            vtb[(d + 1) * 64 + (((r >> 3) ^ ((d + 1) & 7)) << 3) + (r & 7)] = bf16c(v.y);
            vtb[(d + 2) * 64 + (((r >> 3) ^ ((d + 2) & 7)) << 3) + (r & 7)] = bf16c(v.z);
            vtb[(d + 3) * 64 + (((r >> 3) ^ ((d + 3) & 7)) << 3) + (r & 7)] = bf16c(v.w);
        }
    }
    __syncthreads();

    // de-swizzled copies of qsb/knt -> plain bf16 global tiles
    for (int e = tid; e < 512; e += 256) {
        int row = e >> 3, gl = e & 7;
        *(bf16x8*)&Qsb16[base2 + row * 64 + ((gl ^ (row & 7)) << 3)] =
            *(const bf16x8*)&qsb[row * 64 + (gl << 3)];
        *(bf16x8*)&Kntb16[base2 + row * 64 + ((gl ^ (row & 7)) << 3)] =
            *(const bf16x8*)&knt[row * 64 + (gl << 3)];
    }

    {
        const int ar = w * 16 + l15;
        bf16x8 aK0 = frag_(kn, ar, 0, quad), aK1 = frag_(kn, ar, 1, quad);
        bf16x8 aQ0 = frag_(qsb, ar, 0, quad), aQ1 = frag_(qsb, ar, 1, quad);
        f32x4 accA[4], accT[4];
#pragma unroll
        for (int ni = 0; ni < 4; ++ni) {
            int br = ni * 16 + l15;
            bf16x8 b0 = frag_(kn, br, 0, quad), b1 = frag_(kn, br, 1, quad);
            accA[ni] = __builtin_amdgcn_mfma_f32_16x16x32_bf16(aK0, b0, (f32x4)0.f, 0, 0, 0);
            accA[ni] = __builtin_amdgcn_mfma_f32_16x16x32_bf16(aK1, b1, accA[ni], 0, 0, 0);
            accT[ni] = __builtin_amdgcn_mfma_f32_16x16x32_bf16(aQ0, b0, (f32x4)0.f, 0, 0, 0);
            accT[ni] = __builtin_amdgcn_mfma_f32_16x16x32_bf16(aQ1, b1, accT[ni], 0, 0, 0);
        }
#pragma unroll
        for (int ni = 0; ni < 4; ++ni)
#pragma unroll
            for (int reg = 0; reg < 4; ++reg) {
                int row = w * 16 + quad * 4 + reg;
                int col = ni * 16 + l15;
                ts[row][col] = (col < row) ? accA[ni][reg] : 0.f;
                Atb16[base2 + (size_t)row * 64 + col] =
                    (col <= row) ? bf16c(accT[ni][reg]) : (short)0;
            }
    }
    __syncthreads();

    {
        const int R0 = w * 16;
        if (lane < 16) {
            const int j = lane;
#pragma unroll 1
            for (int i = 0; i < 16; ++i) {
                float s = 0.f;
                for (int m = 0; m < i; ++m) s += ts[R0 + i][R0 + m] * ts[R0 + m][R0 + j];
                ts[R0 + i][R0 + j] = ((j == i) ? 1.f : 0.f) - s;
            }
        }
    }
    __syncthreads();
#pragma unroll 1
    for (int I = 1; I < 4; ++I) {
        const int ncol = I * 16;
        for (int e = tid; e < 16 * ncol; e += 256) {
            int i = e / ncol, jj = e % ncol;
            float s = 0.f;
            for (int m = jj; m < ncol; ++m) s += ts[ncol + i][m] * ts[m][jj];
            zbuf[i][jj] = s;
        }
        __syncthreads();
        for (int e = tid; e < 16 * ncol; e += 256) {
            int i = e / ncol, jj = e % ncol;
            float s = 0.f;
            for (int ml = 0; ml <= i; ++ml) s += ts[ncol + i][ncol + ml] * zbuf[ml][jj];
            ts[ncol + i][jj] = -s;
        }
        __syncthreads();
    }
    for (int e = tid; e < 512; e += 256) {
        int row = e >> 3, g = e & 7;
        bf16x8 o;
#pragma unroll
        for (int t = 0; t < 8; ++t) o[t] = bf16c(ts[row][g * 8 + t]);
        *(bf16x8*)&tb[row * 64 + ((g ^ (row & 7)) << 3)] = o;
    }
    __syncthreads();

    {
        const int ar = w * 16 + l15;
        bf16x8 aT0 = frag_(tb, ar, 0, quad), aT1 = frag_(tb, ar, 1, quad);
        f32x4 accW[4], accU[4];
#pragma unroll
        for (int ni = 0; ni < 4; ++ni) {
            int br = ni * 16 + l15;
            bf16x8 b0 = frag_(knt, br, 0, quad), b1 = frag_(knt, br, 1, quad);
            bf16x8 c0 = frag_(vtb, br, 0, quad), c1 = frag_(vtb, br, 1, quad);
            accW[ni] = __builtin_amdgcn_mfma_f32_16x16x32_bf16(aT0, b0, (f32x4)0.f, 0, 0, 0);
            accW[ni] = __builtin_amdgcn_mfma_f32_16x16x32_bf16(aT1, b1, accW[ni], 0, 0, 0);
            accU[ni] = __builtin_amdgcn_mfma_f32_16x16x32_bf16(aT0, c0, (f32x4)0.f, 0, 0, 0);
            accU[ni] = __builtin_amdgcn_mfma_f32_16x16x32_bf16(aT1, c1, accU[ni], 0, 0, 0);
        }
#pragma unroll
        for (int ni = 0; ni < 4; ++ni)
#pragma unroll
            for (int reg = 0; reg < 4; ++reg) {
                int row = w * 16 + quad * 4 + reg;
                int col = ni * 16 + l15;
                Wb16[base2 + (size_t)row * 64 + col] = bf16c(accW[ni][reg]);
                U[base2 + (size_t)row * 64 + col] = accU[ni][reg];
            }
    }
}

// ---------------- MFMA chunk scan: one block per (b,h,dv-quarter) -------------
// S held as f32 MFMA accumulators; tiles read as register fragments straight
// from global (prefetched one chunk ahead); only S^T / ut^T go through LDS.
#define LOADF(cc, F, UU) {                                                     \
    size_t tb_ = ((size_t)(bh * 16 + (cc))) * 4096;                            \
    F##0 = *(const bf16x8*)&Wb16[tb_ + off0];                                  \
    F##1 = *(const bf16x8*)&Wb16[tb_ + off1];                                  \
    F##2 = *(const bf16x8*)&Qsb16[tb_ + off0];                                 \
    F##3 = *(const bf16x8*)&Qsb16[tb_ + off1];                                 \
    F##4 = *(const bf16x8*)&Atb16[tb_ + off0];                                 \
    F##5 = *(const bf16x8*)&Atb16[tb_ + off1];                                 \
    F##6 = *(const bf16x8*)&Kntb16[tb_ + off0];                                \
    F##7 = *(const bf16x8*)&Kntb16[tb_ + off1];                                \
    UU##0 = U[tb_ + urow + 0 * 64]; UU##1 = U[tb_ + urow + 1 * 64];            \
    UU##2 = U[tb_ + urow + 2 * 64]; UU##3 = U[tb_ + urow + 3 * 64]; }

#define BODY(c, F, UU, FN, UN) {                                               \
    int cn_ = ((c) + 1 < 16) ? (c) + 1 : 0;                                    \
    LOADF(cn_, FN, UN);                                                        \
    bf16x8 st0 = *(const bf16x8*)&ST[stoff0];                                  \
    bf16x8 st1 = *(const bf16x8*)&ST[stoff1];                                  \
    bf16x8 nw0, nw1;                                                           \
    _Pragma("unroll") for (int t_ = 0; t_ < 8; ++t_) {                         \
        nw0[t_] = F##0[t_] ^ (short)0x8000;                                    \
        nw1[t_] = F##1[t_] ^ (short)0x8000; }                                  \
    f32x4 ut = {UU##0, UU##1, UU##2, UU##3};                                   \
    ut = __builtin_amdgcn_mfma_f32_16x16x32_bf16(nw0, st0, ut, 0, 0, 0);       \
    ut = __builtin_amdgcn_mfma_f32_16x16x32_bf16(nw1, st1, ut, 0, 0, 0);       \
    f32x4 o = (f32x4)0.f;                                                      \
    o = __builtin_amdgcn_mfma_f32_16x16x32_bf16(F##2, st0, o, 0, 0, 0);        \
    o = __builtin_amdgcn_mfma_f32_16x16x32_bf16(F##3, st1, o, 0, 0, 0);        \
    _Pragma("unroll") for (int j_ = 0; j_ < 4; ++j_) {                         \
        int rr_ = R0 + quad * 4 + j_;                                          \
        UT[l15 * 64 + (((rr_ >> 3) ^ (l15 & 7)) << 3) + (rr_ & 7)] = bf16c(ut[j_]); } \
    __syncthreads();                                                           \
    bf16x8 uf0 = *(const bf16x8*)&UT[stoff0];                                  \
    bf16x8 uf1 = *(const bf16x8*)&UT[stoff1];                                  \
    o = __builtin_amdgcn_mfma_f32_16x16x32_bf16(F##4, uf0, o, 0, 0, 0);        \
    o = __builtin_amdgcn_mfma_f32_16x16x32_bf16(F##5, uf1, o, 0, 0, 0);        \
    S = __builtin_amdgcn_mfma_f32_16x16x32_bf16(F##6, uf0, S, 0, 0, 0);        \
    S = __builtin_amdgcn_mfma_f32_16x16x32_bf16(F##7, uf1, S, 0, 0, 0);        \
    _Pragma("unroll") for (int j_ = 0; j_ < 4; ++j_)                           \
        delta[obase + (size_t)((c) * 64 + j_) * 768] = o[j_];                  \
    _Pragma("unroll") for (int j_ = 0; j_ < 4; ++j_) {                         \
        int dd_ = R0 + quad * 4 + j_;                                          \
        ST[l15 * 64 + (((dd_ >> 3) ^ (l15 & 7)) << 3) + (dd_ & 7)] = bf16c(S[j_]); } \
    __syncthreads(); }

__global__ __launch_bounds__(256) void scan_kernel(const short* __restrict__ Qsb16,
        const short* __restrict__ Kntb16, const float* __restrict__ U,
        const short* __restrict__ Wb16, const short* __restrict__ Atb16,
        float* __restrict__ delta) {
    __shared__ short ST[1024];  // S^T bf16 [dv 16][d 64], granule-swizzled
    __shared__ short UT[1024];  // ut^T bf16 [dv 16][r 64]
    const int bh = blockIdx.x;
    const int b = bh / Hh, h = bh % Hh;
    const int g0 = blockIdx.y * 16;
    const int tid = threadIdx.x;
    const int lane = tid & 63, w = tid >> 6;
    const int quad = lane >> 4, l15 = lane & 15;
    const int R0 = w * 16;
    const int off0 = (R0 + l15) * 64 + quad * 8;
    const int off1 = off0 + 32;
    const int urow = (R0 + quad * 4) * 64 + g0 + l15;
    const int stoff0 = l15 * 64 + ((quad ^ (l15 & 7)) << 3);
    const int stoff1 = l15 * 64 + (((4 + quad) ^ (l15 & 7)) << 3);
    const size_t obase = ((size_t)(b * Nn + R0 + quad * 4)) * 768 + h * 64 + g0 + l15;

    for (int e = tid; e < 512; e += 256) ((int*)ST)[e] = 0;
    f32x4 S = (f32x4)0.f;
    bf16x8 fA0, fA1, fA2, fA3, fA4, fA5, fA6, fA7;
    bf16x8 fB0, fB1, fB2, fB3, fB4, fB5, fB6, fB7;
    float uA0, uA1, uA2, uA3, uB0, uB1, uB2, uB3;
    LOADF(0, fA, uA);
    __syncthreads();
#pragma unroll 1
    for (int c = 0; c < 16; c += 2) {
        BODY(c, fA, uA, fB, uB);
        BODY(c + 1, fB, uB, fA, uA);
    }
}

// ---------------- FIR + head-mix + prune softmax + gates + entropies ----------
__global__ __launch_bounds__(256) void paths_kernel(const float* __restrict__ qkv,
        const float* __restrict__ delta, const float* __restrict__ wsp,
        const float* __restrict__ gl, const float* __restrict__ mixw,
        const float* __restrict__ idst, const float* __restrict__ firsT,
        const float* __restrict__ firlT, float* __restrict__ context,
        float* __restrict__ entslots) {
    __shared__ float vt[10][768];
    __shared__ float fsb[768], flb[768];
    __shared__ float wts4[4][60], gate4[4][12], idg4[4][12];
    __shared__ float entb[48];
    const int blk = blockIdx.x;
    const int b = blk >> 8, n0 = (blk & 255) * 4;
    const int tid = threadIdx.x;

    for (int t = tid; t < 1920; t += 256) {
        int row = t / 192, c4 = (t % 192) * 4;
        int np = n0 - 6 + row;
        float4 v = make_float4(0.f, 0.f, 0.f, 0.f);
        if (np >= 0) v = *(const float4*)&qkv[((size_t)((b << 10) + np)) * 2304 + 1536 + c4];
        *(float4*)&vt[row][c4] = v;
    }
    if (tid < 48) {
        int ni = tid / 12, h = tid % 12;
        int bn = (b << 10) + n0 + ni;
        const float* pb = &wsp[(size_t)bn * 1664 + 1536];
        float lg[5]; float mx = -1e30f;
#pragma unroll
        for (int p = 0; p < 5; ++p) { lg[p] = pb[h * 5 + p]; mx = fmaxf(mx, lg[p]); }
        float sum = 0.f;
#pragma unroll
        for (int p = 0; p < 5; ++p) { lg[p] = __expf(lg[p] - mx); sum += lg[p]; }
        float e1 = 0.f;
#pragma unroll
        for (int p = 0; p < 5; ++p) {
            float wv = lg[p] / sum;
            wts4[ni][h * 5 + p] = wv;
            e1 += wv * logf(wv + 1e-8f);
        }
        float g = sigmoidf_(gl[(size_t)bn * 128 + h]);
        gate4[ni][h] = g;
        float e2 = g * logf(g + 1e-8f) + (1.f - g) * logf(1.f - g + 1e-8f);
        idg4[ni][h] = sigmoidf_(pb[60 + h]) * sigmoidf_(idst[h]);
        entb[tid] = e1 + e2;
    }
    float4 wl[7], wsv[3];
    if (tid < 192) {
        int c4 = tid * 4;
#pragma unroll
        for (int t = 0; t < 7; ++t) wl[t] = *(const float4*)&firlT[t * 768 + c4];
#pragma unroll
        for (int t = 0; t < 3; ++t) wsv[t] = *(const float4*)&firsT[t * 768 + c4];
    }
    __syncthreads();

#pragma unroll 1
    for (int ni = 0; ni < 4; ++ni) {
        if (tid < 192) {
            int c4 = tid * 4;
            float4 as = make_float4(0.f, 0.f, 0.f, 0.f);
            float4 al = make_float4(0.f, 0.f, 0.f, 0.f);
#pragma unroll
            for (int t = 0; t < 7; ++t) {
                float4 vv = *(const float4*)&vt[ni + t][c4];
                al.x += wl[t].x * vv.x; al.y += wl[t].y * vv.y;
                al.z += wl[t].z * vv.z; al.w += wl[t].w * vv.w;
                if (t >= 4) {
                    as.x += wsv[t - 4].x * vv.x; as.y += wsv[t - 4].y * vv.y;
                    as.z += wsv[t - 4].z * vv.z; as.w += wsv[t - 4].w * vv.w;
                }
            }
            *(float4*)&fsb[c4] = as;
            *(float4*)&flb[c4] = al;
        }
        __syncthreads();
        if (tid < 192) {
            int c4 = tid * 4;
            int h = c4 >> 6, d = c4 & 63;
            float4 ms = *(const float4*)&fsb[c4];
            float4 ml = *(const float4*)&flb[c4];
#pragma unroll
            for (int hh = 0; hh < 12; ++hh) {
                float mw = mixw[hh * 12 + h];
                float4 fsv = *(const float4*)&fsb[hh * 64 + d];
                float4 flv = *(const float4*)&flb[hh * 64 + d];
                ms.x += mw * fsv.x; ms.y += mw * fsv.y;
                ms.z += mw * fsv.z; ms.w += mw * fsv.w;
                ml.x += mw * flv.x; ml.y += mw * flv.y;
                ml.z += mw * flv.z; ml.w += mw * flv.w;
            }
            int bn = (b << 10) + n0 + ni;
            float4 dl = *(const float4*)&delta[(size_t)bn * 768 + c4];
            float4 iv = *(const float4*)&wsp[(size_t)bn * 1664 + c4];
            float4 vv = *(const float4*)&vt[ni + 6][c4];
            float ig = idg4[ni][h];
            const float* wp = &wts4[ni][h * 5];
            float4 pr;
            pr.x = ms.x * wp[0] + ml.x * wp[1] + dl.x * wp[2] + vv.x * wp[3] + iv.x * ig * wp[4];
            pr.y = ms.y * wp[0] + ml.y * wp[1] + dl.y * wp[2] + vv.y * wp[3] + iv.y * ig * wp[4];
            pr.z = ms.z * wp[0] + ml.z * wp[1] + dl.z * wp[2] + vv.z * wp[3] + iv.z * ig * wp[4];
            pr.w = ms.w * wp[0] + ml.w * wp[1] + dl.w * wp[2] + vv.w * wp[3] + iv.w * ig * wp[4];
            float g = gate4[ni][h];
            pr.x *= g; pr.y *= g; pr.z *= g; pr.w *= g;
            *(float4*)&context[(size_t)bn * 768 + c4] = pr;
        }
        __syncthreads();
    }
    if (tid == 0) {
        float s = 0.f;
#pragma unroll
        for (int i = 0; i < 48; ++i) s += entb[i];
        entslots[blk] = s;
    }
}

__global__ __launch_bounds__(256) void finalize_kernel(const float* __restrict__ slots,
        float* __restrict__ out) {
    __shared__ float red[256];
    const int tid = threadIdx.x;
    float s = 0.f;
    for (int i = tid; i < 1024; i += 256) s += slots[i];
    red[tid] = s;
    __syncthreads();
    for (int off = 128; off > 0; off >>= 1) {
        if (tid < off) red[tid] += red[tid + off];
        __syncthreads();
    }
    if (tid == 0) out[OUT_ELEMS] = -red[0] * (1.f / 49152.f);
}

extern "C" void kernel_launch(void* const* d_in, const int* in_sizes, int n_in,
                              void* d_out, int out_size, void* d_ws, size_t ws_size,
                              hipStream_t stream) {
    const float* x        = (const float*)d_in[0];
    const float* w_qkv    = (const float*)d_in[1];
    const float* w_proj   = (const float*)d_in[2];
    const float* b_proj   = (const float*)d_in[3];
    const float* fir_s_w  = (const float*)d_in[4];
    const float* fir_l_w  = (const float*)d_in[5];
    const float* mixw     = (const float*)d_in[6];
    const float* w_prune  = (const float*)d_in[7];
    const float* b_prune  = (const float*)d_in[8];
    const float* w_g1     = (const float*)d_in[9];
    const float* b_g1     = (const float*)d_in[10];
    const float* w_g2     = (const float*)d_in[11];
    const float* b_g2     = (const float*)d_in[12];
    const float* w_id     = (const float*)d_in[13];
    const float* id_st    = (const float*)d_in[14];
    const float* w_idgate = (const float*)d_in[15];
    const float* b_idgate = (const float*)d_in[16];
    float* out = (float*)d_out;
    float* ws  = (float*)d_ws;

    float* qkv   = ws + WS_QKV;
    float* wsp   = ws + WS_WSP;
    float* gl    = ws + WS_GL;
    short* Qsb16  = (short*)(ws + WS_QS);
    short* Kntb16 = Qsb16 + 3145728;
    short* Wb16   = (short*)(ws + WS_KNT);
    short* Atb16  = Wb16 + 3145728;
    float* Ub    = ws + WS_U;
    float* delta = ws + WS_DELTA;
    float* ctx   = ws + WS_CTX;
    float* ent   = ws + WS_ENT;
    float* firsT = ws + WS_FIRST;
    float* firlT = ws + WS_FIRLT;
    float* cbias = ws + WS_CBIAS;
    float* gbias = ws + WS_GBIAS;
    short* wsh   = (short*)(ws + WS_BF16);
    short* xb     = wsh + SH_XB;
    short* wqkvT  = wsh + SH_WQKVT;
    short* wcatT  = wsh + SH_WCATT;
    short* g2T    = wsh + SH_G2T;
    short* wprojT = wsh + SH_WPROJT;
    short* hdnb   = wsh + SH_HDNB;
    short* ctxb   = wsh + SH_CTXB;

    // conversions + prep
    convert_x_kernel<<<dim3(3072), 256, 0, stream>>>(x, xb, 786432);
    convert_w_kernel<<<dim3(12, 36, 4), 256, 0, stream>>>(w_qkv, w_id, w_g1, w_proj,
                                                          wqkvT, wcatT, wprojT);
    prep_kernel<<<dim3(384), 256, 0, stream>>>(w_prune, w_idgate, b_prune, b_idgate,
                                               b_g1, b_g2, w_g2, fir_s_w, fir_l_w,
                                               wcatT, g2T, cbias, gbias, firsT, firlT);
    // projections (all bf16 MFMA)
    gemm_mfma<<<dim3(18, 32), 256, 0, stream>>>(xb, wqkvT, nullptr, qkv, BN, 2304, 768,
                                                0, 0, nullptr);
    gemm_mfma<<<dim3(13, 32), 256, 0, stream>>>(xb, wcatT, cbias, wsp, BN, 1664, 768,
                                                768, 1536, hdnb);
    gemm_mfma<<<dim3(1, 32), 256, 0, stream>>>(hdnb, g2T, gbias, gl, BN, 128, 768,
                                               0, 0, nullptr);
    // delta rule (beta == 1 identically: softmax row-sums)
    pre_kernel<<<dim3(BH * NC), 256, 0, stream>>>(qkv, Qsb16, Kntb16, Ub, Wb16, Atb16);
    scan_kernel<<<dim3(BH, 4), 256, 0, stream>>>(Qsb16, Kntb16, Ub, Wb16, Atb16, delta);
    // FIR + mix + prune + gates + entropies
    paths_kernel<<<dim3(1024), 256, 0, stream>>>(qkv, delta, wsp, gl, mixw, id_st,
                                                 firsT, firlT, ctx, ent);
    // output projection
    convert_x_kernel<<<dim3(3072), 256, 0, stream>>>(ctx, ctxb, 786432);
    gemm_mfma<<<dim3(6, 32), 256, 0, stream>>>(ctxb, wprojT, b_proj, out, BN, 768, 768,
                                               0, 0, nullptr);
    finalize_kernel<<<1, 256, 0, stream>>>(ent, out);
}

// Round 6
// 286.213 us; speedup vs baseline: 4.1689x; 1.0905x over previous
//
#include <hip/hip_runtime.h>
#include <hip/hip_bf16.h>
#include <math.h>

// Problem dims (fixed by setup_inputs)
#define Bz 4
#define Nn 1024
#define Cc 768
#define Hh 12
#define Dd 64
#define BN 4096          // B*N
#define NC 16            // chunks per sequence
#define BH 48            // B*H
#define OUT_ELEMS 3145728  // BN*C

// ---------------- workspace layout (floats) ----------------
#define WS_QKV     0u          // [BN][2304]
#define WS_WSP     9437184u    // fused wide gemm out [BN][1664]: idout|hdn|plig(+pad)
#define WS_GL      16252928u   // gate logits [BN][128] (12 used)
#define WS_QS      16777216u   // (shorts) Qsb16 | Kntb16  (768 tiles x 4096 bf16 each)
#define WS_KNT     19922944u   // (shorts) Wb16 | Atb16
#define WS_U       23068672u   // f32 [768 tiles][4096]
#define WS_DELTA   32505856u
#define WS_ENT     38797312u   // [1024] per-block entropy slots
#define WS_FIRST   38798336u   // firsT [3][768]
#define WS_FIRLT   38800640u   // firlT [7][768]
#define WS_CBIAS   38806016u   // [1664]
#define WS_GBIAS   38807680u   // [128]
#define WS_BF16    38807808u   // float offset; shorts region starts here
// short offsets within the bf16 region:
#define SH_XB      0u          // [BN][768]
#define SH_WQKVT   3145728u    // [2304][768]
#define SH_WCATT   4915200u    // [1664][768]: w_idT | w_g1T | wcombT(72)+pad
#define SH_G2T     6193152u    // [128][768]
#define SH_WPROJT  6291456u    // [768][768]
#define SH_HDNB    6881280u    // [BN][768]
#define SH_CTXB    10027008u   // [BN][768]

typedef __attribute__((ext_vector_type(8))) short bf16x8;
typedef __attribute__((ext_vector_type(4))) float f32x4;

__device__ __forceinline__ float sigmoidf_(float x) { return 1.f / (1.f + __expf(-x)); }
__device__ __forceinline__ float geluf_(float x) {
    float t = tanhf(0.7978845608028654f * (x + 0.044715f * x * x * x));
    return 0.5f * x * (1.f + t);
}
__device__ __forceinline__ short bf16c(float f) {
    union { float f; unsigned u; } a; a.f = f;
    unsigned r = a.u + 0x7fffu + ((a.u >> 16) & 1u);
    return (short)(r >> 16);
}
__device__ __forceinline__ void gload16(const void* g, void* l) {
    __builtin_amdgcn_global_load_lds(
        (const __attribute__((address_space(1))) unsigned*)g,
        (__attribute__((address_space(3))) unsigned*)l, 16, 0, 0);
}
// MFMA fragment read from a 64x64 bf16 LDS array with per-row XOR granule swizzle.
__device__ __forceinline__ bf16x8 frag_(const short* arr, int row, int kc, int quad) {
    return *(const bf16x8*)&arr[row * 64 + (((kc * 4 + quad) ^ (row & 7)) << 3)];
}

// ---------------- f32 -> bf16 row-preserving convert ----------------
__global__ __launch_bounds__(256) void convert_x_kernel(const float* __restrict__ src,
        short* __restrict__ dst, int n4) {
    int i = blockIdx.x * 256 + threadIdx.x;
    if (i < n4) {
        float4 v = *(const float4*)&src[(size_t)i * 4];
        short4 o;
        o.x = bf16c(v.x); o.y = bf16c(v.y); o.z = bf16c(v.z); o.w = bf16c(v.w);
        *(short4*)&dst[(size_t)i * 4] = o;
    }
}

// -------- weight transpose + bf16 convert (z=0..3) + merged prep (z=4) -------
__global__ __launch_bounds__(256) void convert_w_kernel(const float* __restrict__ w_qkv,
        const float* __restrict__ w_id, const float* __restrict__ w_g1,
        const float* __restrict__ w_proj, short* __restrict__ wqkvT,
        short* __restrict__ wcatT, short* __restrict__ wprojT,
        const float* __restrict__ wp, const float* __restrict__ wig,
        const float* __restrict__ bp, const float* __restrict__ big,
        const float* __restrict__ bg1, const float* __restrict__ bg2,
        const float* __restrict__ wg2, const float* __restrict__ firs,
        const float* __restrict__ firl, short* __restrict__ g2T,
        float* __restrict__ cbias, float* __restrict__ gbias,
        float* __restrict__ firsT, float* __restrict__ firlT) {
    __shared__ float t[64][65];
    const int z = blockIdx.z;
    const int tid = threadIdx.x;
    if (z == 4) {
        int i = (blockIdx.y * 12 + blockIdx.x) * 256 + tid;
        if (i < 98304) {
            int r = i / 768, k = i % 768;
            float wv = 0.f;
            if (r < 60) wv = wp[k * 60 + r];
            else if (r < 72) wv = wig[k * 12 + (r - 60)];
            wcatT[(size_t)(1536 + r) * 768 + k] = (r < 72) ? bf16c(wv) : (short)0;
            g2T[(size_t)r * 768 + k] = (r < 12) ? bf16c(wg2[k * 12 + r]) : (short)0;
        }
        if (i < 1664) {
            float bv = 0.f;
            if (i >= 768 && i < 1536) bv = bg1[i - 768];
            else if (i >= 1536 && i < 1596) bv = bp[i - 1536];
            else if (i >= 1596 && i < 1608) bv = big[i - 1596];
            cbias[i] = bv;
        }
        if (i < 128) gbias[i] = (i < 12) ? bg2[i] : 0.f;
        if (i < 2304) { int tt = i / 768, e = i % 768; firsT[tt * 768 + e] = firs[e * 3 + tt]; }
        if (i < 5376) { int tt = i / 768, e = i % 768; firlT[tt * 768 + e] = firl[e * 7 + tt]; }
        return;
    }
    const float* src; short* dst; int Nw;
    if (z == 0)      { src = w_qkv;  dst = wqkvT;              Nw = 2304; }
    else if (z == 1) { src = w_id;   dst = wcatT;              Nw = 768; }
    else if (z == 2) { src = w_g1;   dst = wcatT + 768 * 768;  Nw = 768; }
    else             { src = w_proj; dst = wprojT;             Nw = 768; }
    const int n0 = blockIdx.y * 64;
    if (n0 >= Nw) return;
    const int k0 = blockIdx.x * 64;
    for (int e = tid; e < 1024; e += 256) {
        int r = e >> 4, c4 = (e & 15) * 4;
        float4 v = *(const float4*)&src[(size_t)(k0 + r) * Nw + n0 + c4];
        t[c4 + 0][r] = v.x; t[c4 + 1][r] = v.y;
        t[c4 + 2][r] = v.z; t[c4 + 3][r] = v.w;
    }
    __syncthreads();
    for (int e = tid; e < 1024; e += 256) {
        int r = e >> 4, c4 = (e & 15) * 4;
        short4 o;
        o.x = bf16c(t[r][c4 + 0]); o.y = bf16c(t[r][c4 + 1]);
        o.z = bf16c(t[r][c4 + 2]); o.w = bf16c(t[r][c4 + 3]);
        *(short4*)&dst[(size_t)(n0 + r) * 768 + k0 + c4] = o;
    }
}

// ---------------- bf16 MFMA GEMM: C[M,N] = A[M,K] @ BT[N,K]^T + bias ---------
__global__ __launch_bounds__(256) void gemm_mfma(const short* __restrict__ A,
        const short* __restrict__ BT, const float* __restrict__ bias,
        float* __restrict__ C, int M, int N, int K, int glo, int ghi,
        short* __restrict__ C2) {
    __shared__ short As[128 * 64];
    __shared__ short Bs[128 * 64];
    const int tid = threadIdx.x;
    const int lane = tid & 63, w = tid >> 6;
    const int quad = lane >> 4, l15 = lane & 15;
    const int row0 = blockIdx.y * 128, col0 = blockIdx.x * 128;
    const int wm = (w >> 1) * 64, wn = (w & 1) * 64;

    int srow[4]; int scol[4];
#pragma unroll
    for (int i = 0; i < 4; ++i) {
        int G = (w * 4 + i) * 64 + lane;
        int row = G >> 3, g = G & 7;
        srow[i] = row;
        scol[i] = (g ^ (row & 7)) * 8;
    }
    int aoff[4][2], boff[4][2];
#pragma unroll
    for (int mi = 0; mi < 4; ++mi)
#pragma unroll
        for (int kk = 0; kk < 2; ++kk) {
            int ra = wm + mi * 16 + l15;
            aoff[mi][kk] = ra * 128 + (((kk * 4 + quad) ^ (ra & 7)) * 16);
            int rb = wn + mi * 16 + l15;
            boff[mi][kk] = rb * 128 + (((kk * 4 + quad) ^ (rb & 7)) * 16);
        }

    f32x4 acc[4][4];
#pragma unroll
    for (int mi = 0; mi < 4; ++mi)
#pragma unroll
        for (int ni = 0; ni < 4; ++ni) acc[mi][ni] = (f32x4)0.f;

    for (int k0 = 0; k0 < K; k0 += 64) {
#pragma unroll
        for (int i = 0; i < 4; ++i) {
            gload16(&A[(size_t)(row0 + srow[i]) * K + k0 + scol[i]], &As[(w * 4 + i) * 512]);
            gload16(&BT[(size_t)(col0 + srow[i]) * K + k0 + scol[i]], &Bs[(w * 4 + i) * 512]);
        }
        __syncthreads();
#pragma unroll
        for (int kk = 0; kk < 2; ++kk) {
            bf16x8 af[4], bfr[4];
#pragma unroll
            for (int mi = 0; mi < 4; ++mi)
                af[mi] = *(const bf16x8*)((const char*)As + aoff[mi][kk]);
#pragma unroll
            for (int ni = 0; ni < 4; ++ni)
                bfr[ni] = *(const bf16x8*)((const char*)Bs + boff[ni][kk]);
#pragma unroll
            for (int mi = 0; mi < 4; ++mi)
#pragma unroll
                for (int ni = 0; ni < 4; ++ni)
                    acc[mi][ni] = __builtin_amdgcn_mfma_f32_16x16x32_bf16(
                        af[mi], bfr[ni], acc[mi][ni], 0, 0, 0);
        }
        __syncthreads();
    }
#pragma unroll
    for (int ni = 0; ni < 4; ++ni) {
        int col = col0 + wn + ni * 16 + l15;
        float bv = bias ? bias[col] : 0.f;
        bool gel = (col >= glo) && (col < ghi);
#pragma unroll
        for (int mi = 0; mi < 4; ++mi) {
#pragma unroll
            for (int r = 0; r < 4; ++r) {
                int row = row0 + wm + mi * 16 + quad * 4 + r;
                float v = acc[mi][ni][r] + bv;
                if (gel) v = geluf_(v);
                C[(size_t)row * N + col] = v;
                if (C2 && gel) C2[(size_t)row * 768 + (col - glo)] = bf16c(v);
            }
        }
    }
}

// ---------------- delta-rule preprocessing (MFMA + blocked inversion) --------
// Outputs (per 64x64 chunk tile, bf16 row-major): Qsb16 [r][d], Kntb16 [d][r],
// Wb16 [r][d], Atb16 [r][d] (tril); U f32 [r][64].
// LDS 50176B (3 blocks/CU); all global stores except Qsb16 deferred to tail.
__global__ __launch_bounds__(256) void pre_kernel(const float* __restrict__ qkv,
        short* __restrict__ Qsb16, short* __restrict__ Kntb16, float* __restrict__ U,
        short* __restrict__ Wb16, short* __restrict__ Atb16) {
    __shared__ __align__(16) char smem[50176];
    float (*ts)[68] = (float (*)[68])smem;               // 17408 B
    short* kn  = (short*)(smem + 17408);                 // 8192 B
    short* knt = (short*)(smem + 25600);                 // 8192 B
    short* qsb = (short*)(smem + 33792);                 // 8192 B
    short* vtb = (short*)(smem + 41984);                 // 8192 B
    float (*zbuf)[68] = (float (*)[68])(smem + 17408);   // overlays kn (dead after B)
    short* tb  = (short*)(smem + 33792);                 // overlays qsb (dead after B)
    const int blk = blockIdx.x;
    const int c = blk & 15, bh = blk >> 4;
    const int b = bh / Hh, h = bh % Hh;
    const int tid = threadIdx.x;
    const int lane = tid & 63, w = tid >> 6;
    const int quad = lane >> 4, l15 = lane & 15;
    const int r = tid >> 2, d0 = (tid & 3) * 16;
    const size_t rowbase = ((size_t)(b * Nn + c * 64)) * (3 * Cc) + h * 64;
    const size_t base2 = (size_t)blk * 4096;

    // ---- Phase A: load q/k/v, normalize k, fill LDS; Qsb16 straight to global
    {
        float4 qq[4], kq[4], vq[4];
        const float* bp_ = &qkv[rowbase + (size_t)r * 2304 + d0];
#pragma unroll
        for (int t4 = 0; t4 < 4; ++t4) qq[t4] = *(const float4*)&bp_[t4 * 4];
#pragma unroll
        for (int t4 = 0; t4 < 4; ++t4) kq[t4] = *(const float4*)&bp_[768 + t4 * 4];
#pragma unroll
        for (int t4 = 0; t4 < 4; ++t4) vq[t4] = *(const float4*)&bp_[1536 + t4 * 4];

        float kf[16];
#pragma unroll
        for (int t4 = 0; t4 < 4; ++t4) {
            kf[t4 * 4 + 0] = kq[t4].x; kf[t4 * 4 + 1] = kq[t4].y;
            kf[t4 * 4 + 2] = kq[t4].z; kf[t4 * 4 + 3] = kq[t4].w;
        }
        float ss = 0.f;
#pragma unroll
        for (int t = 0; t < 16; ++t) ss += kf[t] * kf[t];
        ss += __shfl_xor(ss, 1);
        ss += __shfl_xor(ss, 2);
        float invn = 1.f / (sqrtf(ss) + 1e-6f);
#pragma unroll
        for (int t = 0; t < 16; ++t) kf[t] *= invn;
        {
            bf16x8 g0, g1;
#pragma unroll
            for (int t = 0; t < 8; ++t) { g0[t] = bf16c(kf[t]); g1[t] = bf16c(kf[8 + t]); }
            int gb = d0 >> 3;
            *(bf16x8*)&kn[r * 64 + (((gb + 0) ^ (r & 7)) << 3)] = g0;
            *(bf16x8*)&kn[r * 64 + (((gb + 1) ^ (r & 7)) << 3)] = g1;
#pragma unroll
            for (int t = 0; t < 16; ++t) {
                int d = d0 + t;
                knt[d * 64 + (((r >> 3) ^ (d & 7)) << 3) + (r & 7)] = bf16c(kf[t]);
            }
        }
        {
            float qf[16];
#pragma unroll
            for (int t4 = 0; t4 < 4; ++t4) {
                qf[t4 * 4 + 0] = qq[t4].x * 0.125f; qf[t4 * 4 + 1] = qq[t4].y * 0.125f;
                qf[t4 * 4 + 2] = qq[t4].z * 0.125f; qf[t4 * 4 + 3] = qq[t4].w * 0.125f;
            }
            bf16x8 g0, g1;
#pragma unroll
            for (int t = 0; t < 8; ++t) { g0[t] = bf16c(qf[t]); g1[t] = bf16c(qf[8 + t]); }
            int gb = d0 >> 3;
            *(bf16x8*)&qsb[r * 64 + (((gb + 0) ^ (r & 7)) << 3)] = g0;
            *(bf16x8*)&qsb[r * 64 + (((gb + 1) ^ (r & 7)) << 3)] = g1;
            // plain row-major global copy straight from regs
            *(bf16x8*)&Qsb16[base2 + r * 64 + d0] = g0;
            *(bf16x8*)&Qsb16[base2 + r * 64 + d0 + 8] = g1;
        }
#pragma unroll
        for (int t4 = 0; t4 < 4; ++t4) {
            int d = d0 + t4 * 4;
            vtb[(d + 0) * 64 + (((r >> 3) ^ ((d + 0) & 7)) << 3) + (r & 7)] = bf16c(vq[t4].x);
            vtb[(d + 1) * 64 + (((r >> 3) ^ ((d + 1) & 7)) << 3) + (r & 7)] = bf16c(vq[t4].y);
            vtb[(d + 2) * 64 + (((r >> 3) ^ ((d + 2) & 7)) << 3) + (r & 7)] = bf16c(vq[t4].z);
            vtb[(d + 3) * 64 + (((r >> 3) ^ ((d + 3) & 7)) << 3) + (r & 7)] = bf16c(vq[t4].w);
        }
    }
    __syncthreads();

    // ---- Phase B: A_full = Kn Kn^T -> ts (tril,-1); accT = Qs Kn^T kept in regs
    f32x4 accT[4];
    {
        const int ar = w * 16 + l15;
        bf16x8 aK0 = frag_(kn, ar, 0, quad), aK1 = frag_(kn, ar, 1, quad);
        bf16x8 aQ0 = frag_(qsb, ar, 0, quad), aQ1 = frag_(qsb, ar, 1, quad);
        f32x4 accA[4];
#pragma unroll
        for (int ni = 0; ni < 4; ++ni) {
            int br = ni * 16 + l15;
            bf16x8 b0 = frag_(kn, br, 0, quad), b1 = frag_(kn, br, 1, quad);
            accA[ni] = __builtin_amdgcn_mfma_f32_16x16x32_bf16(aK0, b0, (f32x4)0.f, 0, 0, 0);
            accA[ni] = __builtin_amdgcn_mfma_f32_16x16x32_bf16(aK1, b1, accA[ni], 0, 0, 0);
            accT[ni] = __builtin_amdgcn_mfma_f32_16x16x32_bf16(aQ0, b0, (f32x4)0.f, 0, 0, 0);
            accT[ni] = __builtin_amdgcn_mfma_f32_16x16x32_bf16(aQ1, b1, accT[ni], 0, 0, 0);
        }
#pragma unroll
        for (int ni = 0; ni < 4; ++ni)
#pragma unroll
            for (int reg = 0; reg < 4; ++reg) {
                int row = w * 16 + quad * 4 + reg;
                int col = ni * 16 + l15;
                ts[row][col] = (col < row) ? accA[ni][reg] : 0.f;
            }
    }
    __syncthreads();

    // ---- Phase C1: invert 4 diagonal 16x16 unit-lower blocks, one per wave ----
    // 64 lanes: j = lane&15 column, s = lane>>4 m-slice; shfl-reduce partials.
    {
        const int R0 = w * 16;
        const int j = lane & 15, s = lane >> 4;
#pragma unroll 1
        for (int i = 0; i < 16; ++i) {
            float p = 0.f;
            for (int m = s; m < i; m += 4)
                p += ts[R0 + i][R0 + m] * ts[R0 + m][R0 + j];
            p += __shfl_xor(p, 16);
            p += __shfl_xor(p, 32);
            if (s == 0) ts[R0 + i][R0 + j] = ((j == i) ? 1.f : 0.f) - p;
        }
    }
    __syncthreads();
    // ---- Phase C2: off-diagonal block rows I=1..3 ----
#pragma unroll 1
    for (int I = 1; I < 4; ++I) {
        const int ncol = I * 16;
        for (int e = tid; e < 16 * ncol; e += 256) {
            int i = e / ncol, jj = e % ncol;
            float s = 0.f;
            for (int m = jj; m < ncol; ++m) s += ts[ncol + i][m] * ts[m][jj];
            zbuf[i][jj] = s;
        }
        __syncthreads();
        for (int e = tid; e < 16 * ncol; e += 256) {
            int i = e / ncol, jj = e % ncol;
            float s = 0.f;
            for (int ml = 0; ml <= i; ++ml) s += ts[ncol + i][ncol + ml] * zbuf[ml][jj];
            ts[ncol + i][jj] = -s;
        }
        __syncthreads();
    }
    // ---- convert T -> bf16 tb (qsb overlay) ----
    for (int e = tid; e < 512; e += 256) {
        int row = e >> 3, g = e & 7;
        bf16x8 o;
#pragma unroll
        for (int t = 0; t < 8; ++t) o[t] = bf16c(ts[row][g * 8 + t]);
        *(bf16x8*)&tb[row * 64 + ((g ^ (row & 7)) << 3)] = o;
    }
    __syncthreads();

    // ---- Phase D: W = T@Kn, U = T@V ----
    f32x4 accW[4], accU[4];
    {
        const int ar = w * 16 + l15;
        bf16x8 aT0 = frag_(tb, ar, 0, quad), aT1 = frag_(tb, ar, 1, quad);
#pragma unroll
        for (int ni = 0; ni < 4; ++ni) {
            int br = ni * 16 + l15;
            bf16x8 b0 = frag_(knt, br, 0, quad), b1 = frag_(knt, br, 1, quad);
            bf16x8 c0 = frag_(vtb, br, 0, quad), c1 = frag_(vtb, br, 1, quad);
            accW[ni] = __builtin_amdgcn_mfma_f32_16x16x32_bf16(aT0, b0, (f32x4)0.f, 0, 0, 0);
            accW[ni] = __builtin_amdgcn_mfma_f32_16x16x32_bf16(aT1, b1, accW[ni], 0, 0, 0);
            accU[ni] = __builtin_amdgcn_mfma_f32_16x16x32_bf16(aT0, c0, (f32x4)0.f, 0, 0, 0);
            accU[ni] = __builtin_amdgcn_mfma_f32_16x16x32_bf16(aT1, c1, accU[ni], 0, 0, 0);
        }
    }
    // ---- Tail: all remaining global stores in one burst ----
#pragma unroll
    for (int ni = 0; ni < 4; ++ni)
#pragma unroll
        for (int reg = 0; reg < 4; ++reg) {
            int row = w * 16 + quad * 4 + reg;
            int col = ni * 16 + l15;
            Wb16[base2 + (size_t)row * 64 + col] = bf16c(accW[ni][reg]);
            U[base2 + (size_t)row * 64 + col] = accU[ni][reg];
            Atb16[base2 + (size_t)row * 64 + col] =
                (col <= row) ? bf16c(accT[ni][reg]) : (short)0;
        }
    for (int e = tid; e < 512; e += 256) {
        int row = e >> 3, gl = e & 7;
        *(bf16x8*)&Kntb16[base2 + row * 64 + ((gl ^ (row & 7)) << 3)] =
            *(const bf16x8*)&knt[row * 64 + (gl << 3)];
    }
}

// ---------------- MFMA chunk scan: one block per (b,h,dv-quarter) -------------
#define LOADF(cc, F, UU) {                                                     \
    size_t tb_ = ((size_t)(bh * 16 + (cc))) * 4096;                            \
    F##0 = *(const bf16x8*)&Wb16[tb_ + off0];                                  \
    F##1 = *(const bf16x8*)&Wb16[tb_ + off1];                                  \
    F##2 = *(const bf16x8*)&Qsb16[tb_ + off0];                                 \
    F##3 = *(const bf16x8*)&Qsb16[tb_ + off1];                                 \
    F##4 = *(const bf16x8*)&Atb16[tb_ + off0];                                 \
    F##5 = *(const bf16x8*)&Atb16[tb_ + off1];                                 \
    F##6 = *(const bf16x8*)&Kntb16[tb_ + off0];                                \
    F##7 = *(const bf16x8*)&Kntb16[tb_ + off1];                                \
    UU##0 = U[tb_ + urow + 0 * 64]; UU##1 = U[tb_ + urow + 1 * 64];            \
    UU##2 = U[tb_ + urow + 2 * 64]; UU##3 = U[tb_ + urow + 3 * 64]; }

#define BODY(c, F, UU, FN, UN) {                                               \
    int cn_ = ((c) + 1 < 16) ? (c) + 1 : 0;                                    \
    LOADF(cn_, FN, UN);                                                        \
    bf16x8 st0 = *(const bf16x8*)&ST[stoff0];                                  \
    bf16x8 st1 = *(const bf16x8*)&ST[stoff1];                                  \
    bf16x8 nw0, nw1;                                                           \
    _Pragma("unroll") for (int t_ = 0; t_ < 8; ++t_) {                         \
        nw0[t_] = F##0[t_] ^ (short)0x8000;                                    \
        nw1[t_] = F##1[t_] ^ (short)0x8000; }                                  \
    f32x4 ut = {UU##0, UU##1, UU##2, UU##3};                                   \
    ut = __builtin_amdgcn_mfma_f32_16x16x32_bf16(nw0, st0, ut, 0, 0, 0);       \
    ut = __builtin_amdgcn_mfma_f32_16x16x32_bf16(nw1, st1, ut, 0, 0, 0);       \
    f32x4 o = (f32x4)0.f;                                                      \
    o = __builtin_amdgcn_mfma_f32_16x16x32_bf16(F##2, st0, o, 0, 0, 0);        \
    o = __builtin_amdgcn_mfma_f32_16x16x32_bf16(F##3, st1, o, 0, 0, 0);        \
    _Pragma("unroll") for (int j_ = 0; j_ < 4; ++j_) {                         \
        int rr_ = R0 + quad * 4 + j_;                                          \
        UT[l15 * 64 + (((rr_ >> 3) ^ (l15 & 7)) << 3) + (rr_ & 7)] = bf16c(ut[j_]); } \
    __syncthreads();                                                           \
    bf16x8 uf0 = *(const bf16x8*)&UT[stoff0];                                  \
    bf16x8 uf1 = *(const bf16x8*)&UT[stoff1];                                  \
    o = __builtin_amdgcn_mfma_f32_16x16x32_bf16(F##4, uf0, o, 0, 0, 0);        \
    o = __builtin_amdgcn_mfma_f32_16x16x32_bf16(F##5, uf1, o, 0, 0, 0);        \
    S = __builtin_amdgcn_mfma_f32_16x16x32_bf16(F##6, uf0, S, 0, 0, 0);        \
    S = __builtin_amdgcn_mfma_f32_16x16x32_bf16(F##7, uf1, S, 0, 0, 0);        \
    _Pragma("unroll") for (int j_ = 0; j_ < 4; ++j_)                           \
        delta[obase + (size_t)((c) * 64 + j_) * 768] = o[j_];                  \
    _Pragma("unroll") for (int j_ = 0; j_ < 4; ++j_) {                         \
        int dd_ = R0 + quad * 4 + j_;                                          \
        ST[l15 * 64 + (((dd_ >> 3) ^ (l15 & 7)) << 3) + (dd_ & 7)] = bf16c(S[j_]); } \
    __syncthreads(); }

__global__ __launch_bounds__(256) void scan_kernel(const short* __restrict__ Qsb16,
        const short* __restrict__ Kntb16, const float* __restrict__ U,
        const short* __restrict__ Wb16, const short* __restrict__ Atb16,
        float* __restrict__ delta) {
    __shared__ short ST[1024];
    __shared__ short UT[1024];
    const int bh = blockIdx.x;
    const int b = bh / Hh, h = bh % Hh;
    const int g0 = blockIdx.y * 16;
    const int tid = threadIdx.x;
    const int lane = tid & 63, w = tid >> 6;
    const int quad = lane >> 4, l15 = lane & 15;
    const int R0 = w * 16;
    const int off0 = (R0 + l15) * 64 + quad * 8;
    const int off1 = off0 + 32;
    const int urow = (R0 + quad * 4) * 64 + g0 + l15;
    const int stoff0 = l15 * 64 + ((quad ^ (l15 & 7)) << 3);
    const int stoff1 = l15 * 64 + (((4 + quad) ^ (l15 & 7)) << 3);
    const size_t obase = ((size_t)(b * Nn + R0 + quad * 4)) * 768 + h * 64 + g0 + l15;

    for (int e = tid; e < 512; e += 256) ((int*)ST)[e] = 0;
    f32x4 S = (f32x4)0.f;
    bf16x8 fA0, fA1, fA2, fA3, fA4, fA5, fA6, fA7;
    bf16x8 fB0, fB1, fB2, fB3, fB4, fB5, fB6, fB7;
    float uA0, uA1, uA2, uA3, uB0, uB1, uB2, uB3;
    LOADF(0, fA, uA);
    __syncthreads();
#pragma unroll 1
    for (int c = 0; c < 16; c += 2) {
        BODY(c, fA, uA, fB, uB);
        BODY(c + 1, fB, uB, fA, uA);
    }
}

// ---------------- FIR + head-mix + prune softmax + gates + entropies ----------
// Writes context directly as bf16 (ctxb) for the final GEMM.
__global__ __launch_bounds__(256) void paths_kernel(const float* __restrict__ qkv,
        const float* __restrict__ delta, const float* __restrict__ wsp,
        const float* __restrict__ gl, const float* __restrict__ mixw,
        const float* __restrict__ idst, const float* __restrict__ firsT,
        const float* __restrict__ firlT, short* __restrict__ ctxb,
        float* __restrict__ entslots) {
    __shared__ float vt[10][768];
    __shared__ float fsb[768], flb[768];
    __shared__ float wts4[4][60], gate4[4][12], idg4[4][12];
    __shared__ float entb[48];
    const int blk = blockIdx.x;
    const int b = blk >> 8, n0 = (blk & 255) * 4;
    const int tid = threadIdx.x;

    for (int t = tid; t < 1920; t += 256) {
        int row = t / 192, c4 = (t % 192) * 4;
        int np = n0 - 6 + row;
        float4 v = make_float4(0.f, 0.f, 0.f, 0.f);
        if (np >= 0) v = *(const float4*)&qkv[((size_t)((b << 10) + np)) * 2304 + 1536 + c4];
        *(float4*)&vt[row][c4] = v;
    }
    if (tid < 48) {
        int ni = tid / 12, h = tid % 12;
        int bn = (b << 10) + n0 + ni;
        const float* pb = &wsp[(size_t)bn * 1664 + 1536];
        float lg[5]; float mx = -1e30f;
#pragma unroll
        for (int p = 0; p < 5; ++p) { lg[p] = pb[h * 5 + p]; mx = fmaxf(mx, lg[p]); }
        float sum = 0.f;
#pragma unroll
        for (int p = 0; p < 5; ++p) { lg[p] = __expf(lg[p] - mx); sum += lg[p]; }
        float e1 = 0.f;
#pragma unroll
        for (int p = 0; p < 5; ++p) {
            float wv = lg[p] / sum;
            wts4[ni][h * 5 + p] = wv;
            e1 += wv * logf(wv + 1e-8f);
        }
        float g = sigmoidf_(gl[(size_t)bn * 128 + h]);
        gate4[ni][h] = g;
        float e2 = g * logf(g + 1e-8f) + (1.f - g) * logf(1.f - g + 1e-8f);
        idg4[ni][h] = sigmoidf_(pb[60 + h]) * sigmoidf_(idst[h]);
        entb[tid] = e1 + e2;
    }
    float4 wl[7], wsv[3];
    if (tid < 192) {
        int c4 = tid * 4;
#pragma unroll
        for (int t = 0; t < 7; ++t) wl[t] = *(const float4*)&firlT[t * 768 + c4];
#pragma unroll
        for (int t = 0; t < 3; ++t) wsv[t] = *(const float4*)&firsT[t * 768 + c4];
    }
    __syncthreads();

#pragma unroll 1
    for (int ni = 0; ni < 4; ++ni) {
        if (tid < 192) {
            int c4 = tid * 4;
            float4 as = make_float4(0.f, 0.f, 0.f, 0.f);
            float4 al = make_float4(0.f, 0.f, 0.f, 0.f);
#pragma unroll
            for (int t = 0; t < 7; ++t) {
                float4 vv = *(const float4*)&vt[ni + t][c4];
                al.x += wl[t].x * vv.x; al.y += wl[t].y * vv.y;
                al.z += wl[t].z * vv.z; al.w += wl[t].w * vv.w;
                if (t >= 4) {
                    as.x += wsv[t - 4].x * vv.x; as.y += wsv[t - 4].y * vv.y;
                    as.z += wsv[t - 4].z * vv.z; as.w += wsv[t - 4].w * vv.w;
                }
            }
            *(float4*)&fsb[c4] = as;
            *(float4*)&flb[c4] = al;
        }
        __syncthreads();
        if (tid < 192) {
            int c4 = tid * 4;
            int h = c4 >> 6, d = c4 & 63;
            float4 ms = *(const float4*)&fsb[c4];
            float4 ml = *(const float4*)&flb[c4];
#pragma unroll
            for (int hh = 0; hh < 12; ++hh) {
                float mw = mixw[hh * 12 + h];
                float4 fsv = *(const float4*)&fsb[hh * 64 + d];
                float4 flv = *(const float4*)&flb[hh * 64 + d];
                ms.x += mw * fsv.x; ms.y += mw * fsv.y;
                ms.z += mw * fsv.z; ms.w += mw * fsv.w;
                ml.x += mw * flv.x; ml.y += mw * flv.y;
                ml.z += mw * flv.z; ml.w += mw * flv.w;
            }
            int bn = (b << 10) + n0 + ni;
            float4 dl = *(const float4*)&delta[(size_t)bn * 768 + c4];
            float4 iv = *(const float4*)&wsp[(size_t)bn * 1664 + c4];
            float4 vv = *(const float4*)&vt[ni + 6][c4];
            float ig = idg4[ni][h];
            const float* wp = &wts4[ni][h * 5];
            float4 pr;
            pr.x = ms.x * wp[0] + ml.x * wp[1] + dl.x * wp[2] + vv.x * wp[3] + iv.x * ig * wp[4];
            pr.y = ms.y * wp[0] + ml.y * wp[1] + dl.y * wp[2] + vv.y * wp[3] + iv.y * ig * wp[4];
            pr.z = ms.z * wp[0] + ml.z * wp[1] + dl.z * wp[2] + vv.z * wp[3] + iv.z * ig * wp[4];
            pr.w = ms.w * wp[0] + ml.w * wp[1] + dl.w * wp[2] + vv.w * wp[3] + iv.w * ig * wp[4];
            float g = gate4[ni][h];
            short4 o;
            o.x = bf16c(pr.x * g); o.y = bf16c(pr.y * g);
            o.z = bf16c(pr.z * g); o.w = bf16c(pr.w * g);
            *(short4*)&ctxb[(size_t)bn * 768 + c4] = o;
        }
        __syncthreads();
    }
    if (tid == 0) {
        float s = 0.f;
#pragma unroll
        for (int i = 0; i < 48; ++i) s += entb[i];
        entslots[blk] = s;
    }
}

__global__ __launch_bounds__(256) void finalize_kernel(const float* __restrict__ slots,
        float* __restrict__ out) {
    __shared__ float red[256];
    const int tid = threadIdx.x;
    float s = 0.f;
    for (int i = tid; i < 1024; i += 256) s += slots[i];
    red[tid] = s;
    __syncthreads();
    for (int off = 128; off > 0; off >>= 1) {
        if (tid < off) red[tid] += red[tid + off];
        __syncthreads();
    }
    if (tid == 0) out[OUT_ELEMS] = -red[0] * (1.f / 49152.f);
}

extern "C" void kernel_launch(void* const* d_in, const int* in_sizes, int n_in,
                              void* d_out, int out_size, void* d_ws, size_t ws_size,
                              hipStream_t stream) {
    const float* x        = (const float*)d_in[0];
    const float* w_qkv    = (const float*)d_in[1];
    const float* w_proj   = (const float*)d_in[2];
    const float* b_proj   = (const float*)d_in[3];
    const float* fir_s_w  = (const float*)d_in[4];
    const float* fir_l_w  = (const float*)d_in[5];
    const float* mixw     = (const float*)d_in[6];
    const float* w_prune  = (const float*)d_in[7];
    const float* b_prune  = (const float*)d_in[8];
    const float* w_g1     = (const float*)d_in[9];
    const float* b_g1     = (const float*)d_in[10];
    const float* w_g2     = (const float*)d_in[11];
    const float* b_g2     = (const float*)d_in[12];
    const float* w_id     = (const float*)d_in[13];
    const float* id_st    = (const float*)d_in[14];
    const float* w_idgate = (const float*)d_in[15];
    const float* b_idgate = (const float*)d_in[16];
    float* out = (float*)d_out;
    float* ws  = (float*)d_ws;

    float* qkv   = ws + WS_QKV;
    float* wsp   = ws + WS_WSP;
    float* gl    = ws + WS_GL;
    short* Qsb16  = (short*)(ws + WS_QS);
    short* Kntb16 = Qsb16 + 3145728;
    short* Wb16   = (short*)(ws + WS_KNT);
    short* Atb16  = Wb16 + 3145728;
    float* Ub    = ws + WS_U;
    float* delta = ws + WS_DELTA;
    float* ent   = ws + WS_ENT;
    float* firsT = ws + WS_FIRST;
    float* firlT = ws + WS_FIRLT;
    float* cbias = ws + WS_CBIAS;
    float* gbias = ws + WS_GBIAS;
    short* wsh   = (short*)(ws + WS_BF16);
    short* xb     = wsh + SH_XB;
    short* wqkvT  = wsh + SH_WQKVT;
    short* wcatT  = wsh + SH_WCATT;
    short* g2T    = wsh + SH_G2T;
    short* wprojT = wsh + SH_WPROJT;
    short* hdnb   = wsh + SH_HDNB;
    short* ctxb   = wsh + SH_CTXB;

    // conversions + prep (z=4 plane does the small-weight prep)
    convert_x_kernel<<<dim3(3072), 256, 0, stream>>>(x, xb, 786432);
    convert_w_kernel<<<dim3(12, 36, 5), 256, 0, stream>>>(w_qkv, w_id, w_g1, w_proj,
            wqkvT, wcatT, wprojT, w_prune, w_idgate, b_prune, b_idgate, b_g1, b_g2,
            w_g2, fir_s_w, fir_l_w, g2T, cbias, gbias, firsT, firlT);
    // projections (all bf16 MFMA)
    gemm_mfma<<<dim3(18, 32), 256, 0, stream>>>(xb, wqkvT, nullptr, qkv, BN, 2304, 768,
                                                0, 0, nullptr);
    gemm_mfma<<<dim3(13, 32), 256, 0, stream>>>(xb, wcatT, cbias, wsp, BN, 1664, 768,
                                                768, 1536, hdnb);
    gemm_mfma<<<dim3(1, 32), 256, 0, stream>>>(hdnb, g2T, gbias, gl, BN, 128, 768,
                                               0, 0, nullptr);
    // delta rule (beta == 1 identically: softmax row-sums)
    pre_kernel<<<dim3(BH * NC), 256, 0, stream>>>(qkv, Qsb16, Kntb16, Ub, Wb16, Atb16);
    scan_kernel<<<dim3(BH, 4), 256, 0, stream>>>(Qsb16, Kntb16, Ub, Wb16, Atb16, delta);
    // FIR + mix + prune + gates + entropies (writes bf16 context directly)
    paths_kernel<<<dim3(1024), 256, 0, stream>>>(qkv, delta, wsp, gl, mixw, id_st,
                                                 firsT, firlT, ctxb, ent);
    // output projection
    gemm_mfma<<<dim3(6, 32), 256, 0, stream>>>(ctxb, wprojT, b_proj, out, BN, 768, 768,
                                               0, 0, nullptr);
    finalize_kernel<<<1, 256, 0, stream>>>(ent, out);
}

// Round 7
// 273.456 us; speedup vs baseline: 4.3634x; 1.0467x over previous
//
#include <hip/hip_runtime.h>
#include <hip/hip_bf16.h>
#include <math.h>

// Problem dims (fixed by setup_inputs)
#define Bz 4
#define Nn 1024
#define Cc 768
#define Hh 12
#define Dd 64
#define BN 4096          // B*N
#define NC 16            // chunks per sequence
#define BH 48            // B*H
#define OUT_ELEMS 3145728  // BN*C

// ---------------- workspace layout ----------------
// float offsets:
#define WS_U       0u          // f32 [768 tiles][4096]
#define WS_PLIG    3145728u    // f32 [BN][128] (72 used: prune60|idgate12)
#define WS_GL      3670016u    // f32 [BN][128] (12 used)
#define WS_ENT     4194304u    // [1024]
#define WS_FIRST   4195328u    // [3][768]
#define WS_FIRLT   4197632u    // [7][768]
#define WS_CBIAS   4203008u    // [3968]
#define WS_GBIAS   4206976u    // [128]
#define WS_SH      4207104u    // shorts region starts here (float offset)
// short offsets within the bf16 region:
#define SH_XB      0u          // [BN][768]
#define SH_QKVB    3145728u    // [BN][2304]
#define SH_IDOUT   12582912u   // [BN][768]
#define SH_HDNB    15728640u   // [BN][768]
#define SH_CTXB    18874368u   // [BN][768]
#define SH_DELTA   22020096u   // [BN][768]
#define SH_QS      25165824u   // [768 tiles][4096]
#define SH_KNT     28311552u
#define SH_W       31457280u
#define SH_AT      34603008u
#define SH_WCAT2T  37748736u   // [3968][768]: wqkvT|w_idT|w_g1T|wcombT(72)+pad
#define SH_G2T     40796160u   // [128][768]
#define SH_WPROJT  40894464u   // [768][768]

typedef __attribute__((ext_vector_type(8))) short bf16x8;
typedef __attribute__((ext_vector_type(4))) float f32x4;

__device__ __forceinline__ float sigmoidf_(float x) { return 1.f / (1.f + __expf(-x)); }
__device__ __forceinline__ float geluf_(float x) {
    float t = tanhf(0.7978845608028654f * (x + 0.044715f * x * x * x));
    return 0.5f * x * (1.f + t);
}
__device__ __forceinline__ short bf16c(float f) {
    union { float f; unsigned u; } a; a.f = f;
    unsigned r = a.u + 0x7fffu + ((a.u >> 16) & 1u);
    return (short)(r >> 16);
}
__device__ __forceinline__ float b2f(short s) {
    union { float f; unsigned u; } a;
    a.u = ((unsigned)(unsigned short)s) << 16;
    return a.f;
}
__device__ __forceinline__ void gload16(const void* g, void* l) {
    __builtin_amdgcn_global_load_lds(
        (const __attribute__((address_space(1))) unsigned*)g,
        (__attribute__((address_space(3))) unsigned*)l, 16, 0, 0);
}
// MFMA fragment read from a 64x64 bf16 LDS array with per-row XOR granule swizzle.
__device__ __forceinline__ bf16x8 frag_(const short* arr, int row, int kc, int quad) {
    return *(const bf16x8*)&arr[row * 64 + (((kc * 4 + quad) ^ (row & 7)) << 3)];
}

// ---------------- f32 -> bf16 row-preserving convert ----------------
__global__ __launch_bounds__(256) void convert_x_kernel(const float* __restrict__ src,
        short* __restrict__ dst, int n4) {
    int i = blockIdx.x * 256 + threadIdx.x;
    if (i < n4) {
        float4 v = *(const float4*)&src[(size_t)i * 4];
        short4 o;
        o.x = bf16c(v.x); o.y = bf16c(v.y); o.z = bf16c(v.z); o.w = bf16c(v.w);
        *(short4*)&dst[(size_t)i * 4] = o;
    }
}

// -------- weight transpose + bf16 convert (z=0..3) + merged prep (z=4) -------
__global__ __launch_bounds__(256) void convert_w_kernel(const float* __restrict__ w_qkv,
        const float* __restrict__ w_id, const float* __restrict__ w_g1,
        const float* __restrict__ w_proj, short* __restrict__ wcat2T,
        short* __restrict__ wprojT,
        const float* __restrict__ wp, const float* __restrict__ wig,
        const float* __restrict__ bp, const float* __restrict__ big,
        const float* __restrict__ bg1, const float* __restrict__ bg2,
        const float* __restrict__ wg2, const float* __restrict__ firs,
        const float* __restrict__ firl, short* __restrict__ g2T,
        float* __restrict__ cbias, float* __restrict__ gbias,
        float* __restrict__ firsT, float* __restrict__ firlT) {
    __shared__ float t[64][65];
    const int z = blockIdx.z;
    const int tid = threadIdx.x;
    if (z == 4) {
        int i = (blockIdx.y * 12 + blockIdx.x) * 256 + tid;
        if (i < 98304) {
            int r = i / 768, k = i % 768;
            float wv = 0.f;
            if (r < 60) wv = wp[k * 60 + r];
            else if (r < 72) wv = wig[k * 12 + (r - 60)];
            wcat2T[(size_t)(3840 + r) * 768 + k] = (r < 72) ? bf16c(wv) : (short)0;
            g2T[(size_t)r * 768 + k] = (r < 12) ? bf16c(wg2[k * 12 + r]) : (short)0;
        }
        if (i < 3968) {
            float bv = 0.f;
            if (i >= 3072 && i < 3840) bv = bg1[i - 3072];
            else if (i >= 3840 && i < 3900) bv = bp[i - 3840];
            else if (i >= 3900 && i < 3912) bv = big[i - 3900];
            cbias[i] = bv;
        }
        if (i < 128) gbias[i] = (i < 12) ? bg2[i] : 0.f;
        if (i < 2304) { int tt = i / 768, e = i % 768; firsT[tt * 768 + e] = firs[e * 3 + tt]; }
        if (i < 5376) { int tt = i / 768, e = i % 768; firlT[tt * 768 + e] = firl[e * 7 + tt]; }
        return;
    }
    const float* src; short* dst; int Nw;
    if (z == 0)      { src = w_qkv;  dst = wcat2T;               Nw = 2304; }
    else if (z == 1) { src = w_id;   dst = wcat2T + 2304 * 768;  Nw = 768; }
    else if (z == 2) { src = w_g1;   dst = wcat2T + 3072 * 768;  Nw = 768; }
    else             { src = w_proj; dst = wprojT;               Nw = 768; }
    const int n0 = blockIdx.y * 64;
    if (n0 >= Nw) return;
    const int k0 = blockIdx.x * 64;
    for (int e = tid; e < 1024; e += 256) {
        int r = e >> 4, c4 = (e & 15) * 4;
        float4 v = *(const float4*)&src[(size_t)(k0 + r) * Nw + n0 + c4];
        t[c4 + 0][r] = v.x; t[c4 + 1][r] = v.y;
        t[c4 + 2][r] = v.z; t[c4 + 3][r] = v.w;
    }
    __syncthreads();
    for (int e = tid; e < 1024; e += 256) {
        int r = e >> 4, c4 = (e & 15) * 4;
        short4 o;
        o.x = bf16c(t[r][c4 + 0]); o.y = bf16c(t[r][c4 + 1]);
        o.z = bf16c(t[r][c4 + 2]); o.w = bf16c(t[r][c4 + 3]);
        *(short4*)&dst[(size_t)(n0 + r) * 768 + k0 + c4] = o;
    }
}

// ---------------- shared MFMA K-loop core (128x128 tile, BK=64) --------------
#define GEMM_CORE(APTR, BPTR, KDIM)                                            \
    __shared__ short As[128 * 64];                                             \
    __shared__ short Bs[128 * 64];                                             \
    const int tid = threadIdx.x;                                               \
    const int lane = tid & 63, w = tid >> 6;                                   \
    const int quad = lane >> 4, l15 = lane & 15;                               \
    const int row0 = blockIdx.y * 128, col0 = blockIdx.x * 128;                \
    const int wm = (w >> 1) * 64, wn = (w & 1) * 64;                           \
    int srow[4]; int scol[4];                                                  \
    _Pragma("unroll") for (int i = 0; i < 4; ++i) {                            \
        int G = (w * 4 + i) * 64 + lane;                                       \
        int row = G >> 3, g = G & 7;                                           \
        srow[i] = row;                                                         \
        scol[i] = (g ^ (row & 7)) * 8;                                         \
    }                                                                          \
    int aoff[4][2], boff[4][2];                                                \
    _Pragma("unroll") for (int mi = 0; mi < 4; ++mi)                           \
        _Pragma("unroll") for (int kk = 0; kk < 2; ++kk) {                     \
            int ra = wm + mi * 16 + l15;                                       \
            aoff[mi][kk] = ra * 128 + (((kk * 4 + quad) ^ (ra & 7)) * 16);     \
            int rb = wn + mi * 16 + l15;                                       \
            boff[mi][kk] = rb * 128 + (((kk * 4 + quad) ^ (rb & 7)) * 16);     \
        }                                                                      \
    f32x4 acc[4][4];                                                           \
    _Pragma("unroll") for (int mi = 0; mi < 4; ++mi)                           \
        _Pragma("unroll") for (int ni = 0; ni < 4; ++ni) acc[mi][ni] = (f32x4)0.f; \
    for (int k0 = 0; k0 < (KDIM); k0 += 64) {                                  \
        _Pragma("unroll") for (int i = 0; i < 4; ++i) {                        \
            gload16(&(APTR)[(size_t)(row0 + srow[i]) * (KDIM) + k0 + scol[i]], \
                    &As[(w * 4 + i) * 512]);                                   \
            gload16(&(BPTR)[(size_t)(col0 + srow[i]) * (KDIM) + k0 + scol[i]], \
                    &Bs[(w * 4 + i) * 512]);                                   \
        }                                                                      \
        __syncthreads();                                                       \
        _Pragma("unroll") for (int kk = 0; kk < 2; ++kk) {                     \
            bf16x8 af[4], bfr[4];                                              \
            _Pragma("unroll") for (int mi = 0; mi < 4; ++mi)                   \
                af[mi] = *(const bf16x8*)((const char*)As + aoff[mi][kk]);     \
            _Pragma("unroll") for (int ni = 0; ni < 4; ++ni)                   \
                bfr[ni] = *(const bf16x8*)((const char*)Bs + boff[ni][kk]);    \
            _Pragma("unroll") for (int mi = 0; mi < 4; ++mi)                   \
                _Pragma("unroll") for (int ni = 0; ni < 4; ++ni)               \
                    acc[mi][ni] = __builtin_amdgcn_mfma_f32_16x16x32_bf16(     \
                        af[mi], bfr[ni], acc[mi][ni], 0, 0, 0);                \
        }                                                                      \
        __syncthreads();                                                       \
    }

// ---------------- fused main projection: x @ [wqkv|w_id|w_g1|wcomb] ----------
// N=3968, K=768. Outputs: qkvb bf16 [BN][2304], idoutb bf16 [BN][768],
// hdnb bf16 [BN][768] (gelu), plig f32 [BN][128].
__global__ __launch_bounds__(256) void gemm_main(const short* __restrict__ A,
        const short* __restrict__ BT, const float* __restrict__ bias,
        short* __restrict__ qkvb, short* __restrict__ idoutb,
        short* __restrict__ hdnb, float* __restrict__ plig) {
    GEMM_CORE(A, BT, 768)
#pragma unroll
    for (int ni = 0; ni < 4; ++ni) {
        int col = col0 + wn + ni * 16 + l15;
        float bv = bias[col];
#pragma unroll
        for (int mi = 0; mi < 4; ++mi) {
#pragma unroll
            for (int r = 0; r < 4; ++r) {
                int row = row0 + wm + mi * 16 + quad * 4 + r;
                float v = acc[mi][ni][r] + bv;
                if (col < 2304) {
                    qkvb[(size_t)row * 2304 + col] = bf16c(v);
                } else if (col < 3072) {
                    idoutb[(size_t)row * 768 + (col - 2304)] = bf16c(v);
                } else if (col < 3840) {
                    hdnb[(size_t)row * 768 + (col - 3072)] = bf16c(geluf_(v));
                } else {
                    plig[(size_t)row * 128 + (col - 3840)] = v;
                }
            }
        }
    }
}

// ---------------- generic bf16 MFMA GEMM: C f32 = A @ BT^T + bias ------------
__global__ __launch_bounds__(256) void gemm_mfma(const short* __restrict__ A,
        const short* __restrict__ BT, const float* __restrict__ bias,
        float* __restrict__ C, int M, int N, int K) {
    GEMM_CORE(A, BT, K)
#pragma unroll
    for (int ni = 0; ni < 4; ++ni) {
        int col = col0 + wn + ni * 16 + l15;
        float bv = bias ? bias[col] : 0.f;
#pragma unroll
        for (int mi = 0; mi < 4; ++mi) {
#pragma unroll
            for (int r = 0; r < 4; ++r) {
                int row = row0 + wm + mi * 16 + quad * 4 + r;
                C[(size_t)row * N + col] = acc[mi][ni][r] + bv;
            }
        }
    }
}

// ---------------- delta-rule preprocessing (MFMA + blocked inversion) --------
// Input qkvb bf16. Outputs per 64x64 chunk tile: Qsb16/Kntb16/Wb16/Atb16 bf16
// row-major, U f32. LDS 50176B; global stores deferred to tail.
__global__ __launch_bounds__(256) void pre_kernel(const short* __restrict__ qkvb,
        short* __restrict__ Qsb16, short* __restrict__ Kntb16, float* __restrict__ U,
        short* __restrict__ Wb16, short* __restrict__ Atb16) {
    __shared__ __align__(16) char smem[50176];
    float (*ts)[68] = (float (*)[68])smem;               // 17408 B
    short* kn  = (short*)(smem + 17408);                 // 8192 B
    short* knt = (short*)(smem + 25600);                 // 8192 B
    short* qsb = (short*)(smem + 33792);                 // 8192 B
    short* vtb = (short*)(smem + 41984);                 // 8192 B
    float (*zbuf)[68] = (float (*)[68])(smem + 17408);   // overlays kn (dead after B)
    short* tb  = (short*)(smem + 33792);                 // overlays qsb (dead after B)
    const int blk = blockIdx.x;
    const int c = blk & 15, bh = blk >> 4;
    const int b = bh / Hh, h = bh % Hh;
    const int tid = threadIdx.x;
    const int lane = tid & 63, w = tid >> 6;
    const int quad = lane >> 4, l15 = lane & 15;
    const int r = tid >> 2, d0 = (tid & 3) * 16;
    const size_t rowb = ((size_t)(b * Nn + c * 64)) * 2304 + h * 64;
    const size_t base2 = (size_t)blk * 4096;

    // ---- Phase A: bf16 loads; k-norm; fill LDS; Qsb16 straight to global ----
    {
        const short* qp = &qkvb[rowb + (size_t)r * 2304 + d0];
        bf16x8 qb0 = *(const bf16x8*)&qp[0],    qb1 = *(const bf16x8*)&qp[8];
        bf16x8 kb0 = *(const bf16x8*)&qp[768],  kb1 = *(const bf16x8*)&qp[776];
        bf16x8 vb0 = *(const bf16x8*)&qp[1536], vb1 = *(const bf16x8*)&qp[1544];

        float kf[16];
#pragma unroll
        for (int t = 0; t < 8; ++t) { kf[t] = b2f(kb0[t]); kf[8 + t] = b2f(kb1[t]); }
        float ss = 0.f;
#pragma unroll
        for (int t = 0; t < 16; ++t) ss += kf[t] * kf[t];
        ss += __shfl_xor(ss, 1);
        ss += __shfl_xor(ss, 2);
        float invn = 1.f / (sqrtf(ss) + 1e-6f);
        {
            bf16x8 g0, g1;
#pragma unroll
            for (int t = 0; t < 8; ++t) {
                g0[t] = bf16c(kf[t] * invn); g1[t] = bf16c(kf[8 + t] * invn);
            }
            int gb = d0 >> 3;
            *(bf16x8*)&kn[r * 64 + (((gb + 0) ^ (r & 7)) << 3)] = g0;
            *(bf16x8*)&kn[r * 64 + (((gb + 1) ^ (r & 7)) << 3)] = g1;
#pragma unroll
            for (int t = 0; t < 8; ++t) {
                int d = d0 + t;
                knt[d * 64 + (((r >> 3) ^ (d & 7)) << 3) + (r & 7)] = g0[t];
                int d2 = d0 + 8 + t;
                knt[d2 * 64 + (((r >> 3) ^ (d2 & 7)) << 3) + (r & 7)] = g1[t];
            }
        }
        {
            bf16x8 g0, g1;
#pragma unroll
            for (int t = 0; t < 8; ++t) {
                g0[t] = bf16c(b2f(qb0[t]) * 0.125f);
                g1[t] = bf16c(b2f(qb1[t]) * 0.125f);
            }
            int gb = d0 >> 3;
            *(bf16x8*)&qsb[r * 64 + (((gb + 0) ^ (r & 7)) << 3)] = g0;
            *(bf16x8*)&qsb[r * 64 + (((gb + 1) ^ (r & 7)) << 3)] = g1;
            *(bf16x8*)&Qsb16[base2 + r * 64 + d0] = g0;
            *(bf16x8*)&Qsb16[base2 + r * 64 + d0 + 8] = g1;
        }
#pragma unroll
        for (int t = 0; t < 8; ++t) {
            int d = d0 + t;
            vtb[d * 64 + (((r >> 3) ^ (d & 7)) << 3) + (r & 7)] = vb0[t];
            int d2 = d0 + 8 + t;
            vtb[d2 * 64 + (((r >> 3) ^ (d2 & 7)) << 3) + (r & 7)] = vb1[t];
        }
    }
    __syncthreads();

    // ---- Phase B: A_full = Kn Kn^T -> ts (tril,-1); accT = Qs Kn^T in regs ---
    f32x4 accT[4];
    {
        const int ar = w * 16 + l15;
        bf16x8 aK0 = frag_(kn, ar, 0, quad), aK1 = frag_(kn, ar, 1, quad);
        bf16x8 aQ0 = frag_(qsb, ar, 0, quad), aQ1 = frag_(qsb, ar, 1, quad);
        f32x4 accA[4];
#pragma unroll
        for (int ni = 0; ni < 4; ++ni) {
            int br = ni * 16 + l15;
            bf16x8 b0 = frag_(kn, br, 0, quad), b1 = frag_(kn, br, 1, quad);
            accA[ni] = __builtin_amdgcn_mfma_f32_16x16x32_bf16(aK0, b0, (f32x4)0.f, 0, 0, 0);
            accA[ni] = __builtin_amdgcn_mfma_f32_16x16x32_bf16(aK1, b1, accA[ni], 0, 0, 0);
            accT[ni] = __builtin_amdgcn_mfma_f32_16x16x32_bf16(aQ0, b0, (f32x4)0.f, 0, 0, 0);
            accT[ni] = __builtin_amdgcn_mfma_f32_16x16x32_bf16(aQ1, b1, accT[ni], 0, 0, 0);
        }
#pragma unroll
        for (int ni = 0; ni < 4; ++ni)
#pragma unroll
            for (int reg = 0; reg < 4; ++reg) {
                int row = w * 16 + quad * 4 + reg;
                int col = ni * 16 + l15;
                ts[row][col] = (col < row) ? accA[ni][reg] : 0.f;
            }
    }
    __syncthreads();

    // ---- Phase C1: 4 diagonal 16x16 unit-lower inversions, one per wave ------
    {
        const int R0 = w * 16;
        const int j = lane & 15, s = lane >> 4;
#pragma unroll 1
        for (int i = 0; i < 16; ++i) {
            float p = 0.f;
            for (int m = s; m < i; m += 4)
                p += ts[R0 + i][R0 + m] * ts[R0 + m][R0 + j];
            p += __shfl_xor(p, 16);
            p += __shfl_xor(p, 32);
            if (s == 0) ts[R0 + i][R0 + j] = ((j == i) ? 1.f : 0.f) - p;
        }
    }
    __syncthreads();
    // ---- Phase C2: off-diagonal block rows I=1..3 ----
#pragma unroll 1
    for (int I = 1; I < 4; ++I) {
        const int ncol = I * 16;
        for (int e = tid; e < 16 * ncol; e += 256) {
            int i = e / ncol, jj = e % ncol;
            float s = 0.f;
            for (int m = jj; m < ncol; ++m) s += ts[ncol + i][m] * ts[m][jj];
            zbuf[i][jj] = s;
        }
        __syncthreads();
        for (int e = tid; e < 16 * ncol; e += 256) {
            int i = e / ncol, jj = e % ncol;
            float s = 0.f;
            for (int ml = 0; ml <= i; ++ml) s += ts[ncol + i][ncol + ml] * zbuf[ml][jj];
            ts[ncol + i][jj] = -s;
        }
        __syncthreads();
    }
    // ---- convert T -> bf16 tb (qsb overlay) ----
    for (int e = tid; e < 512; e += 256) {
        int row = e >> 3, g = e & 7;
        bf16x8 o;
#pragma unroll
        for (int t = 0; t < 8; ++t) o[t] = bf16c(ts[row][g * 8 + t]);
        *(bf16x8*)&tb[row * 64 + ((g ^ (row & 7)) << 3)] = o;
    }
    __syncthreads();

    // ---- Phase D: W = T@Kn, U = T@V ----
    f32x4 accW[4], accU[4];
    {
        const int ar = w * 16 + l15;
        bf16x8 aT0 = frag_(tb, ar, 0, quad), aT1 = frag_(tb, ar, 1, quad);
#pragma unroll
        for (int ni = 0; ni < 4; ++ni) {
            int br = ni * 16 + l15;
            bf16x8 b0 = frag_(knt, br, 0, quad), b1 = frag_(knt, br, 1, quad);
            bf16x8 c0 = frag_(vtb, br, 0, quad), c1 = frag_(vtb, br, 1, quad);
            accW[ni] = __builtin_amdgcn_mfma_f32_16x16x32_bf16(aT0, b0, (f32x4)0.f, 0, 0, 0);
            accW[ni] = __builtin_amdgcn_mfma_f32_16x16x32_bf16(aT1, b1, accW[ni], 0, 0, 0);
            accU[ni] = __builtin_amdgcn_mfma_f32_16x16x32_bf16(aT0, c0, (f32x4)0.f, 0, 0, 0);
            accU[ni] = __builtin_amdgcn_mfma_f32_16x16x32_bf16(aT1, c1, accU[ni], 0, 0, 0);
        }
    }
    // ---- Tail: all remaining global stores ----
#pragma unroll
    for (int ni = 0; ni < 4; ++ni)
#pragma unroll
        for (int reg = 0; reg < 4; ++reg) {
            int row = w * 16 + quad * 4 + reg;
            int col = ni * 16 + l15;
            Wb16[base2 + (size_t)row * 64 + col] = bf16c(accW[ni][reg]);
            U[base2 + (size_t)row * 64 + col] = accU[ni][reg];
            Atb16[base2 + (size_t)row * 64 + col] =
                (col <= row) ? bf16c(accT[ni][reg]) : (short)0;
        }
    for (int e = tid; e < 512; e += 256) {
        int row = e >> 3, gl = e & 7;
        *(bf16x8*)&Kntb16[base2 + row * 64 + ((gl ^ (row & 7)) << 3)] =
            *(const bf16x8*)&knt[row * 64 + (gl << 3)];
    }
}

// ---------------- MFMA chunk scan: one block per (b,h,dv-quarter) -------------
#define LOADF(cc, F, UU) {                                                     \
    size_t tb_ = ((size_t)(bh * 16 + (cc))) * 4096;                            \
    F##0 = *(const bf16x8*)&Wb16[tb_ + off0];                                  \
    F##1 = *(const bf16x8*)&Wb16[tb_ + off1];                                  \
    F##2 = *(const bf16x8*)&Qsb16[tb_ + off0];                                 \
    F##3 = *(const bf16x8*)&Qsb16[tb_ + off1];                                 \
    F##4 = *(const bf16x8*)&Atb16[tb_ + off0];                                 \
    F##5 = *(const bf16x8*)&Atb16[tb_ + off1];                                 \
    F##6 = *(const bf16x8*)&Kntb16[tb_ + off0];                                \
    F##7 = *(const bf16x8*)&Kntb16[tb_ + off1];                                \
    UU##0 = U[tb_ + urow + 0 * 64]; UU##1 = U[tb_ + urow + 1 * 64];            \
    UU##2 = U[tb_ + urow + 2 * 64]; UU##3 = U[tb_ + urow + 3 * 64]; }

#define BODY(c, F, UU, FN, UN) {                                               \
    int cn_ = ((c) + 1 < 16) ? (c) + 1 : 0;                                    \
    LOADF(cn_, FN, UN);                                                        \
    bf16x8 st0 = *(const bf16x8*)&ST[stoff0];                                  \
    bf16x8 st1 = *(const bf16x8*)&ST[stoff1];                                  \
    bf16x8 nw0, nw1;                                                           \
    _Pragma("unroll") for (int t_ = 0; t_ < 8; ++t_) {                         \
        nw0[t_] = F##0[t_] ^ (short)0x8000;                                    \
        nw1[t_] = F##1[t_] ^ (short)0x8000; }                                  \
    f32x4 ut = {UU##0, UU##1, UU##2, UU##3};                                   \
    ut = __builtin_amdgcn_mfma_f32_16x16x32_bf16(nw0, st0, ut, 0, 0, 0);       \
    ut = __builtin_amdgcn_mfma_f32_16x16x32_bf16(nw1, st1, ut, 0, 0, 0);       \
    f32x4 o = (f32x4)0.f;                                                      \
    o = __builtin_amdgcn_mfma_f32_16x16x32_bf16(F##2, st0, o, 0, 0, 0);        \
    o = __builtin_amdgcn_mfma_f32_16x16x32_bf16(F##3, st1, o, 0, 0, 0);        \
    _Pragma("unroll") for (int j_ = 0; j_ < 4; ++j_) {                         \
        int rr_ = R0 + quad * 4 + j_;                                          \
        UT[l15 * 64 + (((rr_ >> 3) ^ (l15 & 7)) << 3) + (rr_ & 7)] = bf16c(ut[j_]); } \
    __syncthreads();                                                           \
    bf16x8 uf0 = *(const bf16x8*)&UT[stoff0];                                  \
    bf16x8 uf1 = *(const bf16x8*)&UT[stoff1];                                  \
    o = __builtin_amdgcn_mfma_f32_16x16x32_bf16(F##4, uf0, o, 0, 0, 0);        \
    o = __builtin_amdgcn_mfma_f32_16x16x32_bf16(F##5, uf1, o, 0, 0, 0);        \
    S = __builtin_amdgcn_mfma_f32_16x16x32_bf16(F##6, uf0, S, 0, 0, 0);        \
    S = __builtin_amdgcn_mfma_f32_16x16x32_bf16(F##7, uf1, S, 0, 0, 0);        \
    _Pragma("unroll") for (int j_ = 0; j_ < 4; ++j_)                           \
        deltab[obase + (size_t)((c) * 64 + j_) * 768] = bf16c(o[j_]);          \
    _Pragma("unroll") for (int j_ = 0; j_ < 4; ++j_) {                         \
        int dd_ = R0 + quad * 4 + j_;                                          \
        ST[l15 * 64 + (((dd_ >> 3) ^ (l15 & 7)) << 3) + (dd_ & 7)] = bf16c(S[j_]); } \
    __syncthreads(); }

__global__ __launch_bounds__(256) void scan_kernel(const short* __restrict__ Qsb16,
        const short* __restrict__ Kntb16, const float* __restrict__ U,
        const short* __restrict__ Wb16, const short* __restrict__ Atb16,
        short* __restrict__ deltab) {
    __shared__ short ST[1024];
    __shared__ short UT[1024];
    const int bh = blockIdx.x;
    const int b = bh / Hh, h = bh % Hh;
    const int g0 = blockIdx.y * 16;
    const int tid = threadIdx.x;
    const int lane = tid & 63, w = tid >> 6;
    const int quad = lane >> 4, l15 = lane & 15;
    const int R0 = w * 16;
    const int off0 = (R0 + l15) * 64 + quad * 8;
    const int off1 = off0 + 32;
    const int urow = (R0 + quad * 4) * 64 + g0 + l15;
    const int stoff0 = l15 * 64 + ((quad ^ (l15 & 7)) << 3);
    const int stoff1 = l15 * 64 + (((4 + quad) ^ (l15 & 7)) << 3);
    const size_t obase = ((size_t)(b * Nn + R0 + quad * 4)) * 768 + h * 64 + g0 + l15;

    for (int e = tid; e < 512; e += 256) ((int*)ST)[e] = 0;
    f32x4 S = (f32x4)0.f;
    bf16x8 fA0, fA1, fA2, fA3, fA4, fA5, fA6, fA7;
    bf16x8 fB0, fB1, fB2, fB3, fB4, fB5, fB6, fB7;
    float uA0, uA1, uA2, uA3, uB0, uB1, uB2, uB3;
    LOADF(0, fA, uA);
    __syncthreads();
#pragma unroll 1
    for (int c = 0; c < 16; c += 2) {
        BODY(c, fA, uA, fB, uB);
        BODY(c + 1, fB, uB, fA, uA);
    }
}

// ---------------- FIR + head-mix + prune softmax + gates + entropies ----------
__global__ __launch_bounds__(256) void paths_kernel(const short* __restrict__ qkvb,
        const short* __restrict__ deltab, const short* __restrict__ idoutb,
        const float* __restrict__ plig, const float* __restrict__ gl,
        const float* __restrict__ mixw, const float* __restrict__ idst,
        const float* __restrict__ firsT, const float* __restrict__ firlT,
        short* __restrict__ ctxb, float* __restrict__ entslots) {
    __shared__ float vt[10][768];
    __shared__ float fsb[768], flb[768];
    __shared__ float wts4[4][60], gate4[4][12], idg4[4][12];
    __shared__ float entb[48];
    const int blk = blockIdx.x;
    const int b = blk >> 8, n0 = (blk & 255) * 4;
    const int tid = threadIdx.x;

    // stage v rows n0-6 .. n0+3 (bf16 -> f32)
    for (int t = tid; t < 960; t += 256) {
        int row = t / 96, c8 = (t % 96) * 8;
        int np = n0 - 6 + row;
        float4 lo = make_float4(0.f, 0.f, 0.f, 0.f);
        float4 hi = make_float4(0.f, 0.f, 0.f, 0.f);
        if (np >= 0) {
            bf16x8 vv = *(const bf16x8*)&qkvb[((size_t)((b << 10) + np)) * 2304 + 1536 + c8];
            lo.x = b2f(vv[0]); lo.y = b2f(vv[1]); lo.z = b2f(vv[2]); lo.w = b2f(vv[3]);
            hi.x = b2f(vv[4]); hi.y = b2f(vv[5]); hi.z = b2f(vv[6]); hi.w = b2f(vv[7]);
        }
        *(float4*)&vt[row][c8] = lo;
        *(float4*)&vt[row][c8 + 4] = hi;
    }
    if (tid < 48) {
        int ni = tid / 12, h = tid % 12;
        int bn = (b << 10) + n0 + ni;
        const float* pb = &plig[(size_t)bn * 128];
        float lg[5]; float mx = -1e30f;
#pragma unroll
        for (int p = 0; p < 5; ++p) { lg[p] = pb[h * 5 + p]; mx = fmaxf(mx, lg[p]); }
        float sum = 0.f;
#pragma unroll
        for (int p = 0; p < 5; ++p) { lg[p] = __expf(lg[p] - mx); sum += lg[p]; }
        float e1 = 0.f;
#pragma unroll
        for (int p = 0; p < 5; ++p) {
            float wv = lg[p] / sum;
            wts4[ni][h * 5 + p] = wv;
            e1 += wv * logf(wv + 1e-8f);
        }
        float g = sigmoidf_(gl[(size_t)bn * 128 + h]);
        gate4[ni][h] = g;
        float e2 = g * logf(g + 1e-8f) + (1.f - g) * logf(1.f - g + 1e-8f);
        idg4[ni][h] = sigmoidf_(pb[60 + h]) * sigmoidf_(idst[h]);
        entb[tid] = e1 + e2;
    }
    float4 wl[7], wsv[3];
    if (tid < 192) {
        int c4 = tid * 4;
#pragma unroll
        for (int t = 0; t < 7; ++t) wl[t] = *(const float4*)&firlT[t * 768 + c4];
#pragma unroll
        for (int t = 0; t < 3; ++t) wsv[t] = *(const float4*)&firsT[t * 768 + c4];
    }
    __syncthreads();

#pragma unroll 1
    for (int ni = 0; ni < 4; ++ni) {
        if (tid < 192) {
            int c4 = tid * 4;
            float4 as = make_float4(0.f, 0.f, 0.f, 0.f);
            float4 al = make_float4(0.f, 0.f, 0.f, 0.f);
#pragma unroll
            for (int t = 0; t < 7; ++t) {
                float4 vv = *(const float4*)&vt[ni + t][c4];
                al.x += wl[t].x * vv.x; al.y += wl[t].y * vv.y;
                al.z += wl[t].z * vv.z; al.w += wl[t].w * vv.w;
                if (t >= 4) {
                    as.x += wsv[t - 4].x * vv.x; as.y += wsv[t - 4].y * vv.y;
                    as.z += wsv[t - 4].z * vv.z; as.w += wsv[t - 4].w * vv.w;
                }
            }
            *(float4*)&fsb[c4] = as;
            *(float4*)&flb[c4] = al;
        }
        __syncthreads();
        if (tid < 192) {
            int c4 = tid * 4;
            int h = c4 >> 6, d = c4 & 63;
            float4 ms = *(const float4*)&fsb[c4];
            float4 ml = *(const float4*)&flb[c4];
#pragma unroll
            for (int hh = 0; hh < 12; ++hh) {
                float mw = mixw[hh * 12 + h];
                float4 fsv = *(const float4*)&fsb[hh * 64 + d];
                float4 flv = *(const float4*)&flb[hh * 64 + d];
                ms.x += mw * fsv.x; ms.y += mw * fsv.y;
                ms.z += mw * fsv.z; ms.w += mw * fsv.w;
                ml.x += mw * flv.x; ml.y += mw * flv.y;
                ml.z += mw * flv.z; ml.w += mw * flv.w;
            }
            int bn = (b << 10) + n0 + ni;
            short4 ds = *(const short4*)&deltab[(size_t)bn * 768 + c4];
            short4 is = *(const short4*)&idoutb[(size_t)bn * 768 + c4];
            float4 vv = *(const float4*)&vt[ni + 6][c4];
            float ig = idg4[ni][h];
            const float* wp = &wts4[ni][h * 5];
            float4 pr;
            pr.x = ms.x * wp[0] + ml.x * wp[1] + b2f(ds.x) * wp[2] + vv.x * wp[3] + b2f(is.x) * ig * wp[4];
            pr.y = ms.y * wp[0] + ml.y * wp[1] + b2f(ds.y) * wp[2] + vv.y * wp[3] + b2f(is.y) * ig * wp[4];
            pr.z = ms.z * wp[0] + ml.z * wp[1] + b2f(ds.z) * wp[2] + vv.z * wp[3] + b2f(is.z) * ig * wp[4];
            pr.w = ms.w * wp[0] + ml.w * wp[1] + b2f(ds.w) * wp[2] + vv.w * wp[3] + b2f(is.w) * ig * wp[4];
            float g = gate4[ni][h];
            short4 o;
            o.x = bf16c(pr.x * g); o.y = bf16c(pr.y * g);
            o.z = bf16c(pr.z * g); o.w = bf16c(pr.w * g);
            *(short4*)&ctxb[(size_t)bn * 768 + c4] = o;
        }
        __syncthreads();
    }
    if (tid == 0) {
        float s = 0.f;
#pragma unroll
        for (int i = 0; i < 48; ++i) s += entb[i];
        entslots[blk] = s;
    }
}

__global__ __launch_bounds__(256) void finalize_kernel(const float* __restrict__ slots,
        float* __restrict__ out) {
    __shared__ float red[256];
    const int tid = threadIdx.x;
    float s = 0.f;
    for (int i = tid; i < 1024; i += 256) s += slots[i];
    red[tid] = s;
    __syncthreads();
    for (int off = 128; off > 0; off >>= 1) {
        if (tid < off) red[tid] += red[tid + off];
        __syncthreads();
    }
    if (tid == 0) out[OUT_ELEMS] = -red[0] * (1.f / 49152.f);
}

extern "C" void kernel_launch(void* const* d_in, const int* in_sizes, int n_in,
                              void* d_out, int out_size, void* d_ws, size_t ws_size,
                              hipStream_t stream) {
    const float* x        = (const float*)d_in[0];
    const float* w_qkv    = (const float*)d_in[1];
    const float* w_proj   = (const float*)d_in[2];
    const float* b_proj   = (const float*)d_in[3];
    const float* fir_s_w  = (const float*)d_in[4];
    const float* fir_l_w  = (const float*)d_in[5];
    const float* mixw     = (const float*)d_in[6];
    const float* w_prune  = (const float*)d_in[7];
    const float* b_prune  = (const float*)d_in[8];
    const float* w_g1     = (const float*)d_in[9];
    const float* b_g1     = (const float*)d_in[10];
    const float* w_g2     = (const float*)d_in[11];
    const float* b_g2     = (const float*)d_in[12];
    const float* w_id     = (const float*)d_in[13];
    const float* id_st    = (const float*)d_in[14];
    const float* w_idgate = (const float*)d_in[15];
    const float* b_idgate = (const float*)d_in[16];
    float* out = (float*)d_out;
    float* ws  = (float*)d_ws;

    float* Ub    = ws + WS_U;
    float* plig  = ws + WS_PLIG;
    float* gl    = ws + WS_GL;
    float* ent   = ws + WS_ENT;
    float* firsT = ws + WS_FIRST;
    float* firlT = ws + WS_FIRLT;
    float* cbias = ws + WS_CBIAS;
    float* gbias = ws + WS_GBIAS;
    short* wsh   = (short*)(ws + WS_SH);
    short* xb      = wsh + SH_XB;
    short* qkvb    = wsh + SH_QKVB;
    short* idoutb  = wsh + SH_IDOUT;
    short* hdnb    = wsh + SH_HDNB;
    short* ctxb    = wsh + SH_CTXB;
    short* deltab  = wsh + SH_DELTA;
    short* Qsb16   = wsh + SH_QS;
    short* Kntb16  = wsh + SH_KNT;
    short* Wb16    = wsh + SH_W;
    short* Atb16   = wsh + SH_AT;
    short* wcat2T  = wsh + SH_WCAT2T;
    short* g2T     = wsh + SH_G2T;
    short* wprojT  = wsh + SH_WPROJT;

    // conversions + prep
    convert_x_kernel<<<dim3(3072), 256, 0, stream>>>(x, xb, 786432);
    convert_w_kernel<<<dim3(12, 36, 5), 256, 0, stream>>>(w_qkv, w_id, w_g1, w_proj,
            wcat2T, wprojT, w_prune, w_idgate, b_prune, b_idgate, b_g1, b_g2,
            w_g2, fir_s_w, fir_l_w, g2T, cbias, gbias, firsT, firlT);
    // fused main projection: qkv | idout | gelu-hdn | prune+idgate logits
    gemm_main<<<dim3(31, 32), 256, 0, stream>>>(xb, wcat2T, cbias,
                                                qkvb, idoutb, hdnb, plig);
    // gate MLP second layer
    gemm_mfma<<<dim3(1, 32), 256, 0, stream>>>(hdnb, g2T, gbias, gl, BN, 128, 768);
    // delta rule (beta == 1 identically: softmax row-sums)
    pre_kernel<<<dim3(BH * NC), 256, 0, stream>>>(qkvb, Qsb16, Kntb16, Ub, Wb16, Atb16);
    scan_kernel<<<dim3(BH, 4), 256, 0, stream>>>(Qsb16, Kntb16, Ub, Wb16, Atb16, deltab);
    // FIR + mix + prune + gates + entropies (writes bf16 context directly)
    paths_kernel<<<dim3(1024), 256, 0, stream>>>(qkvb, deltab, idoutb, plig, gl,
                                                 mixw, id_st, firsT, firlT, ctxb, ent);
    // output projection
    gemm_mfma<<<dim3(6, 32), 256, 0, stream>>>(ctxb, wprojT, b_proj, out, BN, 768, 768);
    finalize_kernel<<<1, 256, 0, stream>>>(ent, out);
}

// Round 8
// 257.476 us; speedup vs baseline: 4.6342x; 1.0621x over previous
//
#include <hip/hip_runtime.h>
#include <hip/hip_bf16.h>
#include <math.h>

// Problem dims (fixed by setup_inputs)
#define Bz 4
#define Nn 1024
#define Cc 768
#define Hh 12
#define Dd 64
#define BN 4096          // B*N
#define NC 16            // chunks per sequence
#define BH 48            // B*H
#define OUT_ELEMS 3145728  // BN*C

// ---------------- workspace layout ----------------
// float offsets:
#define WS_U       0u          // f32 [768 tiles][4096]
#define WS_PLIG    3145728u    // f32 [BN][128] (72 used: prune60|idgate12)
#define WS_GL      3670016u    // f32 [BN][128] (12 used)
#define WS_ENT     4194304u    // [1024]
#define WS_FIRST   4195328u    // [3][768]
#define WS_FIRLT   4197632u    // [7][768]
#define WS_CBIAS   4203008u    // [3968]
#define WS_GBIAS   4206976u    // [128]
#define WS_SH      4207104u    // shorts region starts here (float offset)
// short offsets within the bf16 region:
#define SH_XB      0u          // [BN][768]
#define SH_QKVB    3145728u    // [BN][2304]
#define SH_IDOUT   12582912u   // [BN][768]
#define SH_HDNB    15728640u   // [BN][768]
#define SH_CTXB    18874368u   // [BN][768]
#define SH_DELTA   22020096u   // [BN][768]
#define SH_QS      25165824u   // [768 tiles][4096]
#define SH_KNT     28311552u
#define SH_W       31457280u
#define SH_AT      34603008u
#define SH_WCAT2T  37748736u   // [3968][768]: wqkvT|w_idT|w_g1T|wcombT(72)+pad
#define SH_G2T     40796160u   // [128][768]
#define SH_WPROJT  40894464u   // [768][768]

typedef __attribute__((ext_vector_type(8))) short bf16x8;
typedef __attribute__((ext_vector_type(4))) float f32x4;

__device__ __forceinline__ float sigmoidf_(float x) { return 1.f / (1.f + __expf(-x)); }
__device__ __forceinline__ float geluf_(float x) {
    float t = tanhf(0.7978845608028654f * (x + 0.044715f * x * x * x));
    return 0.5f * x * (1.f + t);
}
__device__ __forceinline__ short bf16c(float f) {
    union { float f; unsigned u; } a; a.f = f;
    unsigned r = a.u + 0x7fffu + ((a.u >> 16) & 1u);
    return (short)(r >> 16);
}
__device__ __forceinline__ float b2f(short s) {
    union { float f; unsigned u; } a;
    a.u = ((unsigned)(unsigned short)s) << 16;
    return a.f;
}
__device__ __forceinline__ void gload16(const void* g, void* l) {
    __builtin_amdgcn_global_load_lds(
        (const __attribute__((address_space(1))) unsigned*)g,
        (__attribute__((address_space(3))) unsigned*)l, 16, 0, 0);
}
// MFMA fragment read from a 64x64 bf16 LDS array with per-row XOR granule swizzle.
__device__ __forceinline__ bf16x8 frag_(const short* arr, int row, int kc, int quad) {
    return *(const bf16x8*)&arr[row * 64 + (((kc * 4 + quad) ^ (row & 7)) << 3)];
}

// ---------------- f32 -> bf16 row-preserving convert ----------------
__global__ __launch_bounds__(256) void convert_x_kernel(const float* __restrict__ src,
        short* __restrict__ dst, int n4) {
    int i = blockIdx.x * 256 + threadIdx.x;
    if (i < n4) {
        float4 v = *(const float4*)&src[(size_t)i * 4];
        short4 o;
        o.x = bf16c(v.x); o.y = bf16c(v.y); o.z = bf16c(v.z); o.w = bf16c(v.w);
        *(short4*)&dst[(size_t)i * 4] = o;
    }
}

// -------- weight transpose + bf16 convert (z=0..3) + merged prep (z=4) -------
__global__ __launch_bounds__(256) void convert_w_kernel(const float* __restrict__ w_qkv,
        const float* __restrict__ w_id, const float* __restrict__ w_g1,
        const float* __restrict__ w_proj, short* __restrict__ wcat2T,
        short* __restrict__ wprojT,
        const float* __restrict__ wp, const float* __restrict__ wig,
        const float* __restrict__ bp, const float* __restrict__ big,
        const float* __restrict__ bg1, const float* __restrict__ bg2,
        const float* __restrict__ wg2, const float* __restrict__ firs,
        const float* __restrict__ firl, short* __restrict__ g2T,
        float* __restrict__ cbias, float* __restrict__ gbias,
        float* __restrict__ firsT, float* __restrict__ firlT) {
    __shared__ float t[64][65];
    const int z = blockIdx.z;
    const int tid = threadIdx.x;
    if (z == 4) {
        int i = (blockIdx.y * 12 + blockIdx.x) * 256 + tid;
        if (i < 98304) {
            int r = i / 768, k = i % 768;
            float wv = 0.f;
            if (r < 60) wv = wp[k * 60 + r];
            else if (r < 72) wv = wig[k * 12 + (r - 60)];
            wcat2T[(size_t)(3840 + r) * 768 + k] = (r < 72) ? bf16c(wv) : (short)0;
            g2T[(size_t)r * 768 + k] = (r < 12) ? bf16c(wg2[k * 12 + r]) : (short)0;
        }
        if (i < 3968) {
            float bv = 0.f;
            if (i >= 3072 && i < 3840) bv = bg1[i - 3072];
            else if (i >= 3840 && i < 3900) bv = bp[i - 3840];
            else if (i >= 3900 && i < 3912) bv = big[i - 3900];
            cbias[i] = bv;
        }
        if (i < 128) gbias[i] = (i < 12) ? bg2[i] : 0.f;
        if (i < 2304) { int tt = i / 768, e = i % 768; firsT[tt * 768 + e] = firs[e * 3 + tt]; }
        if (i < 5376) { int tt = i / 768, e = i % 768; firlT[tt * 768 + e] = firl[e * 7 + tt]; }
        return;
    }
    const float* src; short* dst; int Nw;
    if (z == 0)      { src = w_qkv;  dst = wcat2T;               Nw = 2304; }
    else if (z == 1) { src = w_id;   dst = wcat2T + 2304 * 768;  Nw = 768; }
    else if (z == 2) { src = w_g1;   dst = wcat2T + 3072 * 768;  Nw = 768; }
    else             { src = w_proj; dst = wprojT;               Nw = 768; }
    const int n0 = blockIdx.y * 64;
    if (n0 >= Nw) return;
    const int k0 = blockIdx.x * 64;
    for (int e = tid; e < 1024; e += 256) {
        int r = e >> 4, c4 = (e & 15) * 4;
        float4 v = *(const float4*)&src[(size_t)(k0 + r) * Nw + n0 + c4];
        t[c4 + 0][r] = v.x; t[c4 + 1][r] = v.y;
        t[c4 + 2][r] = v.z; t[c4 + 3][r] = v.w;
    }
    __syncthreads();
    for (int e = tid; e < 1024; e += 256) {
        int r = e >> 4, c4 = (e & 15) * 4;
        short4 o;
        o.x = bf16c(t[r][c4 + 0]); o.y = bf16c(t[r][c4 + 1]);
        o.z = bf16c(t[r][c4 + 2]); o.w = bf16c(t[r][c4 + 3]);
        *(short4*)&dst[(size_t)(n0 + r) * 768 + k0 + c4] = o;
    }
}

// ---------------- shared MFMA K-loop core (128x128 tile, BK=64) --------------
// XCD-aware tile swizzle (requires gridDim.y == 32, total blocks % 8 == 0):
// dispatch-linear L -> xcd = L&7 (HW round-robin), j = L>>3; XCD x owns the
// compact patch rows 4x..4x+3 (A strips stay L2-resident) x all cols (B
// streamed once per XCD). Bijective -> correctness-independent of HW mapping.
#define GEMM_CORE(APTR, BPTR, KDIM)                                            \
    __shared__ short As[128 * 64];                                             \
    __shared__ short Bs[128 * 64];                                             \
    const int tid = threadIdx.x;                                               \
    const int lane = tid & 63, w = tid >> 6;                                   \
    const int quad = lane >> 4, l15 = lane & 15;                               \
    const int L_ = blockIdx.y * gridDim.x + blockIdx.x;                        \
    const int xcd_ = L_ & 7, j_ = L_ >> 3;                                     \
    const int row0 = (xcd_ * 4 + (j_ & 3)) * 128, col0 = (j_ >> 2) * 128;      \
    const int wm = (w >> 1) * 64, wn = (w & 1) * 64;                           \
    int srow[4]; int scol[4];                                                  \
    _Pragma("unroll") for (int i = 0; i < 4; ++i) {                            \
        int G = (w * 4 + i) * 64 + lane;                                       \
        int row = G >> 3, g = G & 7;                                           \
        srow[i] = row;                                                         \
        scol[i] = (g ^ (row & 7)) * 8;                                         \
    }                                                                          \
    int aoff[4][2], boff[4][2];                                                \
    _Pragma("unroll") for (int mi = 0; mi < 4; ++mi)                           \
        _Pragma("unroll") for (int kk = 0; kk < 2; ++kk) {                     \
            int ra = wm + mi * 16 + l15;                                       \
            aoff[mi][kk] = ra * 128 + (((kk * 4 + quad) ^ (ra & 7)) * 16);     \
            int rb = wn + mi * 16 + l15;                                       \
            boff[mi][kk] = rb * 128 + (((kk * 4 + quad) ^ (rb & 7)) * 16);     \
        }                                                                      \
    f32x4 acc[4][4];                                                           \
    _Pragma("unroll") for (int mi = 0; mi < 4; ++mi)                           \
        _Pragma("unroll") for (int ni = 0; ni < 4; ++ni) acc[mi][ni] = (f32x4)0.f; \
    for (int k0 = 0; k0 < (KDIM); k0 += 64) {                                  \
        _Pragma("unroll") for (int i = 0; i < 4; ++i) {                        \
            gload16(&(APTR)[(size_t)(row0 + srow[i]) * (KDIM) + k0 + scol[i]], \
                    &As[(w * 4 + i) * 512]);                                   \
            gload16(&(BPTR)[(size_t)(col0 + srow[i]) * (KDIM) + k0 + scol[i]], \
                    &Bs[(w * 4 + i) * 512]);                                   \
        }                                                                      \
        __syncthreads();                                                       \
        _Pragma("unroll") for (int kk = 0; kk < 2; ++kk) {                     \
            bf16x8 af[4], bfr[4];                                              \
            _Pragma("unroll") for (int mi = 0; mi < 4; ++mi)                   \
                af[mi] = *(const bf16x8*)((const char*)As + aoff[mi][kk]);     \
            _Pragma("unroll") for (int ni = 0; ni < 4; ++ni)                   \
                bfr[ni] = *(const bf16x8*)((const char*)Bs + boff[ni][kk]);    \
            _Pragma("unroll") for (int mi = 0; mi < 4; ++mi)                   \
                _Pragma("unroll") for (int ni = 0; ni < 4; ++ni)               \
                    acc[mi][ni] = __builtin_amdgcn_mfma_f32_16x16x32_bf16(     \
                        af[mi], bfr[ni], acc[mi][ni], 0, 0, 0);                \
        }                                                                      \
        __syncthreads();                                                       \
    }

// ---------------- fused main projection: x @ [wqkv|w_id|w_g1|wcomb] ----------
// N=3968, K=768. Outputs: qkvb bf16 [BN][2304], idoutb bf16 [BN][768],
// hdnb bf16 [BN][768] (gelu), plig f32 [BN][128].
__global__ __launch_bounds__(256) void gemm_main(const short* __restrict__ A,
        const short* __restrict__ BT, const float* __restrict__ bias,
        short* __restrict__ qkvb, short* __restrict__ idoutb,
        short* __restrict__ hdnb, float* __restrict__ plig) {
    GEMM_CORE(A, BT, 768)
#pragma unroll
    for (int ni = 0; ni < 4; ++ni) {
        int col = col0 + wn + ni * 16 + l15;
        float bv = bias[col];
#pragma unroll
        for (int mi = 0; mi < 4; ++mi) {
#pragma unroll
            for (int r = 0; r < 4; ++r) {
                int row = row0 + wm + mi * 16 + quad * 4 + r;
                float v = acc[mi][ni][r] + bv;
                if (col < 2304) {
                    qkvb[(size_t)row * 2304 + col] = bf16c(v);
                } else if (col < 3072) {
                    idoutb[(size_t)row * 768 + (col - 2304)] = bf16c(v);
                } else if (col < 3840) {
                    hdnb[(size_t)row * 768 + (col - 3072)] = bf16c(geluf_(v));
                } else {
                    plig[(size_t)row * 128 + (col - 3840)] = v;
                }
            }
        }
    }
}

// ---------------- generic bf16 MFMA GEMM: C f32 = A @ BT^T + bias ------------
__global__ __launch_bounds__(256) void gemm_mfma(const short* __restrict__ A,
        const short* __restrict__ BT, const float* __restrict__ bias,
        float* __restrict__ C, int M, int N, int K) {
    GEMM_CORE(A, BT, K)
#pragma unroll
    for (int ni = 0; ni < 4; ++ni) {
        int col = col0 + wn + ni * 16 + l15;
        float bv = bias ? bias[col] : 0.f;
#pragma unroll
        for (int mi = 0; mi < 4; ++mi) {
#pragma unroll
            for (int r = 0; r < 4; ++r) {
                int row = row0 + wm + mi * 16 + quad * 4 + r;
                C[(size_t)row * N + col] = acc[mi][ni][r] + bv;
            }
        }
    }
}

// ---------------- delta-rule preprocessing (MFMA + blocked inversion) --------
// Input qkvb bf16. Outputs per 64x64 chunk tile: Qsb16/Kntb16/Wb16/Atb16 bf16
// row-major, U f32. LDS 50176B; global stores deferred to tail.
__global__ __launch_bounds__(256) void pre_kernel(const short* __restrict__ qkvb,
        short* __restrict__ Qsb16, short* __restrict__ Kntb16, float* __restrict__ U,
        short* __restrict__ Wb16, short* __restrict__ Atb16) {
    __shared__ __align__(16) char smem[50176];
    float (*ts)[68] = (float (*)[68])smem;               // 17408 B
    short* kn  = (short*)(smem + 17408);                 // 8192 B
    short* knt = (short*)(smem + 25600);                 // 8192 B
    short* qsb = (short*)(smem + 33792);                 // 8192 B
    short* vtb = (short*)(smem + 41984);                 // 8192 B
    float (*zbuf)[68] = (float (*)[68])(smem + 17408);   // overlays kn (dead after B)
    short* tb  = (short*)(smem + 33792);                 // overlays qsb (dead after B)
    const int blk = blockIdx.x;
    const int c = blk & 15, bh = blk >> 4;
    const int b = bh / Hh, h = bh % Hh;
    const int tid = threadIdx.x;
    const int lane = tid & 63, w = tid >> 6;
    const int quad = lane >> 4, l15 = lane & 15;
    const int r = tid >> 2, d0 = (tid & 3) * 16;
    const size_t rowb = ((size_t)(b * Nn + c * 64)) * 2304 + h * 64;
    const size_t base2 = (size_t)blk * 4096;

    // ---- Phase A: bf16 loads; k-norm; fill LDS; Qsb16 straight to global ----
    {
        const short* qp = &qkvb[rowb + (size_t)r * 2304 + d0];
        bf16x8 qb0 = *(const bf16x8*)&qp[0],    qb1 = *(const bf16x8*)&qp[8];
        bf16x8 kb0 = *(const bf16x8*)&qp[768],  kb1 = *(const bf16x8*)&qp[776];
        bf16x8 vb0 = *(const bf16x8*)&qp[1536], vb1 = *(const bf16x8*)&qp[1544];

        float kf[16];
#pragma unroll
        for (int t = 0; t < 8; ++t) { kf[t] = b2f(kb0[t]); kf[8 + t] = b2f(kb1[t]); }
        float ss = 0.f;
#pragma unroll
        for (int t = 0; t < 16; ++t) ss += kf[t] * kf[t];
        ss += __shfl_xor(ss, 1);
        ss += __shfl_xor(ss, 2);
        float invn = 1.f / (sqrtf(ss) + 1e-6f);
        {
            bf16x8 g0, g1;
#pragma unroll
            for (int t = 0; t < 8; ++t) {
                g0[t] = bf16c(kf[t] * invn); g1[t] = bf16c(kf[8 + t] * invn);
            }
            int gb = d0 >> 3;
            *(bf16x8*)&kn[r * 64 + (((gb + 0) ^ (r & 7)) << 3)] = g0;
            *(bf16x8*)&kn[r * 64 + (((gb + 1) ^ (r & 7)) << 3)] = g1;
#pragma unroll
            for (int t = 0; t < 8; ++t) {
                int d = d0 + t;
                knt[d * 64 + (((r >> 3) ^ (d & 7)) << 3) + (r & 7)] = g0[t];
                int d2 = d0 + 8 + t;
                knt[d2 * 64 + (((r >> 3) ^ (d2 & 7)) << 3) + (r & 7)] = g1[t];
            }
        }
        {
            bf16x8 g0, g1;
#pragma unroll
            for (int t = 0; t < 8; ++t) {
                g0[t] = bf16c(b2f(qb0[t]) * 0.125f);
                g1[t] = bf16c(b2f(qb1[t]) * 0.125f);
            }
            int gb = d0 >> 3;
            *(bf16x8*)&qsb[r * 64 + (((gb + 0) ^ (r & 7)) << 3)] = g0;
            *(bf16x8*)&qsb[r * 64 + (((gb + 1) ^ (r & 7)) << 3)] = g1;
            *(bf16x8*)&Qsb16[base2 + r * 64 + d0] = g0;
            *(bf16x8*)&Qsb16[base2 + r * 64 + d0 + 8] = g1;
        }
#pragma unroll
        for (int t = 0; t < 8; ++t) {
            int d = d0 + t;
            vtb[d * 64 + (((r >> 3) ^ (d & 7)) << 3) + (r & 7)] = vb0[t];
            int d2 = d0 + 8 + t;
            vtb[d2 * 64 + (((r >> 3) ^ (d2 & 7)) << 3) + (r & 7)] = vb1[t];
        }
    }
    __syncthreads();

    // ---- Phase B: A_full = Kn Kn^T -> ts (tril,-1); accT = Qs Kn^T in regs ---
    f32x4 accT[4];
    {
        const int ar = w * 16 + l15;
        bf16x8 aK0 = frag_(kn, ar, 0, quad), aK1 = frag_(kn, ar, 1, quad);
        bf16x8 aQ0 = frag_(qsb, ar, 0, quad), aQ1 = frag_(qsb, ar, 1, quad);
        f32x4 accA[4];
#pragma unroll
        for (int ni = 0; ni < 4; ++ni) {
            int br = ni * 16 + l15;
            bf16x8 b0 = frag_(kn, br, 0, quad), b1 = frag_(kn, br, 1, quad);
            accA[ni] = __builtin_amdgcn_mfma_f32_16x16x32_bf16(aK0, b0, (f32x4)0.f, 0, 0, 0);
            accA[ni] = __builtin_amdgcn_mfma_f32_16x16x32_bf16(aK1, b1, accA[ni], 0, 0, 0);
            accT[ni] = __builtin_amdgcn_mfma_f32_16x16x32_bf16(aQ0, b0, (f32x4)0.f, 0, 0, 0);
            accT[ni] = __builtin_amdgcn_mfma_f32_16x16x32_bf16(aQ1, b1, accT[ni], 0, 0, 0);
        }
#pragma unroll
        for (int ni = 0; ni < 4; ++ni)
#pragma unroll
            for (int reg = 0; reg < 4; ++reg) {
                int row = w * 16 + quad * 4 + reg;
                int col = ni * 16 + l15;
                ts[row][col] = (col < row) ? accA[ni][reg] : 0.f;
            }
    }
    __syncthreads();

    // ---- Phase C1: 4 diagonal 16x16 unit-lower inversions, one per wave ------
    {
        const int R0 = w * 16;
        const int j = lane & 15, s = lane >> 4;
#pragma unroll 1
        for (int i = 0; i < 16; ++i) {
            float p = 0.f;
            for (int m = s; m < i; m += 4)
                p += ts[R0 + i][R0 + m] * ts[R0 + m][R0 + j];
            p += __shfl_xor(p, 16);
            p += __shfl_xor(p, 32);
            if (s == 0) ts[R0 + i][R0 + j] = ((j == i) ? 1.f : 0.f) - p;
        }
    }
    __syncthreads();
    // ---- Phase C2: off-diagonal block rows I=1..3 ----
#pragma unroll 1
    for (int I = 1; I < 4; ++I) {
        const int ncol = I * 16;
        for (int e = tid; e < 16 * ncol; e += 256) {
            int i = e / ncol, jj = e % ncol;
            float s = 0.f;
            for (int m = jj; m < ncol; ++m) s += ts[ncol + i][m] * ts[m][jj];
            zbuf[i][jj] = s;
        }
        __syncthreads();
        for (int e = tid; e < 16 * ncol; e += 256) {
            int i = e / ncol, jj = e % ncol;
            float s = 0.f;
            for (int ml = 0; ml <= i; ++ml) s += ts[ncol + i][ncol + ml] * zbuf[ml][jj];
            ts[ncol + i][jj] = -s;
        }
        __syncthreads();
    }
    // ---- convert T -> bf16 tb (qsb overlay) ----
    for (int e = tid; e < 512; e += 256) {
        int row = e >> 3, g = e & 7;
        bf16x8 o;
#pragma unroll
        for (int t = 0; t < 8; ++t) o[t] = bf16c(ts[row][g * 8 + t]);
        *(bf16x8*)&tb[row * 64 + ((g ^ (row & 7)) << 3)] = o;
    }
    __syncthreads();

    // ---- Phase D: W = T@Kn, U = T@V ----
    f32x4 accW[4], accU[4];
    {
        const int ar = w * 16 + l15;
        bf16x8 aT0 = frag_(tb, ar, 0, quad), aT1 = frag_(tb, ar, 1, quad);
#pragma unroll
        for (int ni = 0; ni < 4; ++ni) {
            int br = ni * 16 + l15;
            bf16x8 b0 = frag_(knt, br, 0, quad), b1 = frag_(knt, br, 1, quad);
            bf16x8 c0 = frag_(vtb, br, 0, quad), c1 = frag_(vtb, br, 1, quad);
            accW[ni] = __builtin_amdgcn_mfma_f32_16x16x32_bf16(aT0, b0, (f32x4)0.f, 0, 0, 0);
            accW[ni] = __builtin_amdgcn_mfma_f32_16x16x32_bf16(aT1, b1, accW[ni], 0, 0, 0);
            accU[ni] = __builtin_amdgcn_mfma_f32_16x16x32_bf16(aT0, c0, (f32x4)0.f, 0, 0, 0);
            accU[ni] = __builtin_amdgcn_mfma_f32_16x16x32_bf16(aT1, c1, accU[ni], 0, 0, 0);
        }
    }
    // ---- Tail: all remaining global stores ----
#pragma unroll
    for (int ni = 0; ni < 4; ++ni)
#pragma unroll
        for (int reg = 0; reg < 4; ++reg) {
            int row = w * 16 + quad * 4 + reg;
            int col = ni * 16 + l15;
            Wb16[base2 + (size_t)row * 64 + col] = bf16c(accW[ni][reg]);
            U[base2 + (size_t)row * 64 + col] = accU[ni][reg];
            Atb16[base2 + (size_t)row * 64 + col] =
                (col <= row) ? bf16c(accT[ni][reg]) : (short)0;
        }
    for (int e = tid; e < 512; e += 256) {
        int row = e >> 3, gl = e & 7;
        *(bf16x8*)&Kntb16[base2 + row * 64 + ((gl ^ (row & 7)) << 3)] =
            *(const bf16x8*)&knt[row * 64 + (gl << 3)];
    }
}

// ---------------- MFMA chunk scan: one block per (b,h,dv-quarter) -------------
#define LOADF(cc, F, UU) {                                                     \
    size_t tb_ = ((size_t)(bh * 16 + (cc))) * 4096;                            \
    F##0 = *(const bf16x8*)&Wb16[tb_ + off0];                                  \
    F##1 = *(const bf16x8*)&Wb16[tb_ + off1];                                  \
    F##2 = *(const bf16x8*)&Qsb16[tb_ + off0];                                 \
    F##3 = *(const bf16x8*)&Qsb16[tb_ + off1];                                 \
    F##4 = *(const bf16x8*)&Atb16[tb_ + off0];                                 \
    F##5 = *(const bf16x8*)&Atb16[tb_ + off1];                                 \
    F##6 = *(const bf16x8*)&Kntb16[tb_ + off0];                                \
    F##7 = *(const bf16x8*)&Kntb16[tb_ + off1];                                \
    UU##0 = U[tb_ + urow + 0 * 64]; UU##1 = U[tb_ + urow + 1 * 64];            \
    UU##2 = U[tb_ + urow + 2 * 64]; UU##3 = U[tb_ + urow + 3 * 64]; }

#define BODY(c, F, UU, FN, UN) {                                               \
    int cn_ = ((c) + 1 < 16) ? (c) + 1 : 0;                                    \
    LOADF(cn_, FN, UN);                                                        \
    bf16x8 st0 = *(const bf16x8*)&ST[stoff0];                                  \
    bf16x8 st1 = *(const bf16x8*)&ST[stoff1];                                  \
    bf16x8 nw0, nw1;                                                           \
    _Pragma("unroll") for (int t_ = 0; t_ < 8; ++t_) {                         \
        nw0[t_] = F##0[t_] ^ (short)0x8000;                                    \
        nw1[t_] = F##1[t_] ^ (short)0x8000; }                                  \
    f32x4 ut = {UU##0, UU##1, UU##2, UU##3};                                   \
    ut = __builtin_amdgcn_mfma_f32_16x16x32_bf16(nw0, st0, ut, 0, 0, 0);       \
    ut = __builtin_amdgcn_mfma_f32_16x16x32_bf16(nw1, st1, ut, 0, 0, 0);       \
    f32x4 o = (f32x4)0.f;                                                      \
    o = __builtin_amdgcn_mfma_f32_16x16x32_bf16(F##2, st0, o, 0, 0, 0);        \
    o = __builtin_amdgcn_mfma_f32_16x16x32_bf16(F##3, st1, o, 0, 0, 0);        \
    _Pragma("unroll") for (int j_ = 0; j_ < 4; ++j_) {                         \
        int rr_ = R0 + quad * 4 + j_;                                          \
        UT[l15 * 64 + (((rr_ >> 3) ^ (l15 & 7)) << 3) + (rr_ & 7)] = bf16c(ut[j_]); } \
    __syncthreads();                                                           \
    bf16x8 uf0 = *(const bf16x8*)&UT[stoff0];                                  \
    bf16x8 uf1 = *(const bf16x8*)&UT[stoff1];                                  \
    o = __builtin_amdgcn_mfma_f32_16x16x32_bf16(F##4, uf0, o, 0, 0, 0);        \
    o = __builtin_amdgcn_mfma_f32_16x16x32_bf16(F##5, uf1, o, 0, 0, 0);        \
    S = __builtin_amdgcn_mfma_f32_16x16x32_bf16(F##6, uf0, S, 0, 0, 0);        \
    S = __builtin_amdgcn_mfma_f32_16x16x32_bf16(F##7, uf1, S, 0, 0, 0);        \
    _Pragma("unroll") for (int j_ = 0; j_ < 4; ++j_)                           \
        deltab[obase + (size_t)((c) * 64 + j_) * 768] = bf16c(o[j_]);          \
    _Pragma("unroll") for (int j_ = 0; j_ < 4; ++j_) {                         \
        int dd_ = R0 + quad * 4 + j_;                                          \
        ST[l15 * 64 + (((dd_ >> 3) ^ (l15 & 7)) << 3) + (dd_ & 7)] = bf16c(S[j_]); } \
    __syncthreads(); }

__global__ __launch_bounds__(256) void scan_kernel(const short* __restrict__ Qsb16,
        const short* __restrict__ Kntb16, const float* __restrict__ U,
        const short* __restrict__ Wb16, const short* __restrict__ Atb16,
        short* __restrict__ deltab) {
    __shared__ short ST[1024];
    __shared__ short UT[1024];
    const int bh = blockIdx.x;
    const int b = bh / Hh, h = bh % Hh;
    const int g0 = blockIdx.y * 16;
    const int tid = threadIdx.x;
    const int lane = tid & 63, w = tid >> 6;
    const int quad = lane >> 4, l15 = lane & 15;
    const int R0 = w * 16;
    const int off0 = (R0 + l15) * 64 + quad * 8;
    const int off1 = off0 + 32;
    const int urow = (R0 + quad * 4) * 64 + g0 + l15;
    const int stoff0 = l15 * 64 + ((quad ^ (l15 & 7)) << 3);
    const int stoff1 = l15 * 64 + (((4 + quad) ^ (l15 & 7)) << 3);
    const size_t obase = ((size_t)(b * Nn + R0 + quad * 4)) * 768 + h * 64 + g0 + l15;

    for (int e = tid; e < 512; e += 256) ((int*)ST)[e] = 0;
    f32x4 S = (f32x4)0.f;
    bf16x8 fA0, fA1, fA2, fA3, fA4, fA5, fA6, fA7;
    bf16x8 fB0, fB1, fB2, fB3, fB4, fB5, fB6, fB7;
    float uA0, uA1, uA2, uA3, uB0, uB1, uB2, uB3;
    LOADF(0, fA, uA);
    __syncthreads();
#pragma unroll 1
    for (int c = 0; c < 16; c += 2) {
        BODY(c, fA, uA, fB, uB);
        BODY(c + 1, fB, uB, fA, uA);
    }
}

// ---------------- FIR + head-mix + prune softmax + gates + entropies ----------
__global__ __launch_bounds__(256) void paths_kernel(const short* __restrict__ qkvb,
        const short* __restrict__ deltab, const short* __restrict__ idoutb,
        const float* __restrict__ plig, const float* __restrict__ gl,
        const float* __restrict__ mixw, const float* __restrict__ idst,
        const float* __restrict__ firsT, const float* __restrict__ firlT,
        short* __restrict__ ctxb, float* __restrict__ entslots) {
    __shared__ float vt[10][768];
    __shared__ float fsb[768], flb[768];
    __shared__ float wts4[4][60], gate4[4][12], idg4[4][12];
    __shared__ float entb[48];
    const int blk = blockIdx.x;
    const int b = blk >> 8, n0 = (blk & 255) * 4;
    const int tid = threadIdx.x;

    // stage v rows n0-6 .. n0+3 (bf16 -> f32)
    for (int t = tid; t < 960; t += 256) {
        int row = t / 96, c8 = (t % 96) * 8;
        int np = n0 - 6 + row;
        float4 lo = make_float4(0.f, 0.f, 0.f, 0.f);
        float4 hi = make_float4(0.f, 0.f, 0.f, 0.f);
        if (np >= 0) {
            bf16x8 vv = *(const bf16x8*)&qkvb[((size_t)((b << 10) + np)) * 2304 + 1536 + c8];
            lo.x = b2f(vv[0]); lo.y = b2f(vv[1]); lo.z = b2f(vv[2]); lo.w = b2f(vv[3]);
            hi.x = b2f(vv[4]); hi.y = b2f(vv[5]); hi.z = b2f(vv[6]); hi.w = b2f(vv[7]);
        }
        *(float4*)&vt[row][c8] = lo;
        *(float4*)&vt[row][c8 + 4] = hi;
    }
    if (tid < 48) {
        int ni = tid / 12, h = tid % 12;
        int bn = (b << 10) + n0 + ni;
        const float* pb = &plig[(size_t)bn * 128];
        float lg[5]; float mx = -1e30f;
#pragma unroll
        for (int p = 0; p < 5; ++p) { lg[p] = pb[h * 5 + p]; mx = fmaxf(mx, lg[p]); }
        float sum = 0.f;
#pragma unroll
        for (int p = 0; p < 5; ++p) { lg[p] = __expf(lg[p] - mx); sum += lg[p]; }
        float e1 = 0.f;
#pragma unroll
        for (int p = 0; p < 5; ++p) {
            float wv = lg[p] / sum;
            wts4[ni][h * 5 + p] = wv;
            e1 += wv * logf(wv + 1e-8f);
        }
        float g = sigmoidf_(gl[(size_t)bn * 128 + h]);
        gate4[ni][h] = g;
        float e2 = g * logf(g + 1e-8f) + (1.f - g) * logf(1.f - g + 1e-8f);
        idg4[ni][h] = sigmoidf_(pb[60 + h]) * sigmoidf_(idst[h]);
        entb[tid] = e1 + e2;
    }
    float4 wl[7], wsv[3];
    if (tid < 192) {
        int c4 = tid * 4;
#pragma unroll
        for (int t = 0; t < 7; ++t) wl[t] = *(const float4*)&firlT[t * 768 + c4];
#pragma unroll
        for (int t = 0; t < 3; ++t) wsv[t] = *(const float4*)&firsT[t * 768 + c4];
    }
    __syncthreads();

#pragma unroll 1
    for (int ni = 0; ni < 4; ++ni) {
        if (tid < 192) {
            int c4 = tid * 4;
            float4 as = make_float4(0.f, 0.f, 0.f, 0.f);
            float4 al = make_float4(0.f, 0.f, 0.f, 0.f);
#pragma unroll
            for (int t = 0; t < 7; ++t) {
                float4 vv = *(const float4*)&vt[ni + t][c4];
                al.x += wl[t].x * vv.x; al.y += wl[t].y * vv.y;
                al.z += wl[t].z * vv.z; al.w += wl[t].w * vv.w;
                if (t >= 4) {
                    as.x += wsv[t - 4].x * vv.x; as.y += wsv[t - 4].y * vv.y;
                    as.z += wsv[t - 4].z * vv.z; as.w += wsv[t - 4].w * vv.w;
                }
            }
            *(float4*)&fsb[c4] = as;
            *(float4*)&flb[c4] = al;
        }
        __syncthreads();
        if (tid < 192) {
            int c4 = tid * 4;
            int h = c4 >> 6, d = c4 & 63;
            float4 ms = *(const float4*)&fsb[c4];
            float4 ml = *(const float4*)&flb[c4];
#pragma unroll
            for (int hh = 0; hh < 12; ++hh) {
                float mw = mixw[hh * 12 + h];
                float4 fsv = *(const float4*)&fsb[hh * 64 + d];
                float4 flv = *(const float4*)&flb[hh * 64 + d];
                ms.x += mw * fsv.x; ms.y += mw * fsv.y;
                ms.z += mw * fsv.z; ms.w += mw * fsv.w;
                ml.x += mw * flv.x; ml.y += mw * flv.y;
                ml.z += mw * flv.z; ml.w += mw * flv.w;
            }
            int bn = (b << 10) + n0 + ni;
            short4 ds = *(const short4*)&deltab[(size_t)bn * 768 + c4];
            short4 is = *(const short4*)&idoutb[(size_t)bn * 768 + c4];
            float4 vv = *(const float4*)&vt[ni + 6][c4];
            float ig = idg4[ni][h];
            const float* wp = &wts4[ni][h * 5];
            float4 pr;
            pr.x = ms.x * wp[0] + ml.x * wp[1] + b2f(ds.x) * wp[2] + vv.x * wp[3] + b2f(is.x) * ig * wp[4];
            pr.y = ms.y * wp[0] + ml.y * wp[1] + b2f(ds.y) * wp[2] + vv.y * wp[3] + b2f(is.y) * ig * wp[4];
            pr.z = ms.z * wp[0] + ml.z * wp[1] + b2f(ds.z) * wp[2] + vv.z * wp[3] + b2f(is.z) * ig * wp[4];
            pr.w = ms.w * wp[0] + ml.w * wp[1] + b2f(ds.w) * wp[2] + vv.w * wp[3] + b2f(is.w) * ig * wp[4];
            float g = gate4[ni][h];
            short4 o;
            o.x = bf16c(pr.x * g); o.y = bf16c(pr.y * g);
            o.z = bf16c(pr.z * g); o.w = bf16c(pr.w * g);
            *(short4*)&ctxb[(size_t)bn * 768 + c4] = o;
        }
        __syncthreads();
    }
    if (tid == 0) {
        float s = 0.f;
#pragma unroll
        for (int i = 0; i < 48; ++i) s += entb[i];
        entslots[blk] = s;
    }
}

__global__ __launch_bounds__(256) void finalize_kernel(const float* __restrict__ slots,
        float* __restrict__ out) {
    __shared__ float red[256];
    const int tid = threadIdx.x;
    float s = 0.f;
    for (int i = tid; i < 1024; i += 256) s += slots[i];
    red[tid] = s;
    __syncthreads();
    for (int off = 128; off > 0; off >>= 1) {
        if (tid < off) red[tid] += red[tid + off];
        __syncthreads();
    }
    if (tid == 0) out[OUT_ELEMS] = -red[0] * (1.f / 49152.f);
}

extern "C" void kernel_launch(void* const* d_in, const int* in_sizes, int n_in,
                              void* d_out, int out_size, void* d_ws, size_t ws_size,
                              hipStream_t stream) {
    const float* x        = (const float*)d_in[0];
    const float* w_qkv    = (const float*)d_in[1];
    const float* w_proj   = (const float*)d_in[2];
    const float* b_proj   = (const float*)d_in[3];
    const float* fir_s_w  = (const float*)d_in[4];
    const float* fir_l_w  = (const float*)d_in[5];
    const float* mixw     = (const float*)d_in[6];
    const float* w_prune  = (const float*)d_in[7];
    const float* b_prune  = (const float*)d_in[8];
    const float* w_g1     = (const float*)d_in[9];
    const float* b_g1     = (const float*)d_in[10];
    const float* w_g2     = (const float*)d_in[11];
    const float* b_g2     = (const float*)d_in[12];
    const float* w_id     = (const float*)d_in[13];
    const float* id_st    = (const float*)d_in[14];
    const float* w_idgate = (const float*)d_in[15];
    const float* b_idgate = (const float*)d_in[16];
    float* out = (float*)d_out;
    float* ws  = (float*)d_ws;

    float* Ub    = ws + WS_U;
    float* plig  = ws + WS_PLIG;
    float* gl    = ws + WS_GL;
    float* ent   = ws + WS_ENT;
    float* firsT = ws + WS_FIRST;
    float* firlT = ws + WS_FIRLT;
    float* cbias = ws + WS_CBIAS;
    float* gbias = ws + WS_GBIAS;
    short* wsh   = (short*)(ws + WS_SH);
    short* xb      = wsh + SH_XB;
    short* qkvb    = wsh + SH_QKVB;
    short* idoutb  = wsh + SH_IDOUT;
    short* hdnb    = wsh + SH_HDNB;
    short* ctxb    = wsh + SH_CTXB;
    short* deltab  = wsh + SH_DELTA;
    short* Qsb16   = wsh + SH_QS;
    short* Kntb16  = wsh + SH_KNT;
    short* Wb16    = wsh + SH_W;
    short* Atb16   = wsh + SH_AT;
    short* wcat2T  = wsh + SH_WCAT2T;
    short* g2T     = wsh + SH_G2T;
    short* wprojT  = wsh + SH_WPROJT;

    // conversions + prep
    convert_x_kernel<<<dim3(3072), 256, 0, stream>>>(x, xb, 786432);
    convert_w_kernel<<<dim3(12, 36, 5), 256, 0, stream>>>(w_qkv, w_id, w_g1, w_proj,
            wcat2T, wprojT, w_prune, w_idgate, b_prune, b_idgate, b_g1, b_g2,
            w_g2, fir_s_w, fir_l_w, g2T, cbias, gbias, firsT, firlT);
    // fused main projection: qkv | idout | gelu-hdn | prune+idgate logits
    gemm_main<<<dim3(31, 32), 256, 0, stream>>>(xb, wcat2T, cbias,
                                                qkvb, idoutb, hdnb, plig);
    // gate MLP second layer
    gemm_mfma<<<dim3(1, 32), 256, 0, stream>>>(hdnb, g2T, gbias, gl, BN, 128, 768);
    // delta rule (beta == 1 identically: softmax row-sums)
    pre_kernel<<<dim3(BH * NC), 256, 0, stream>>>(qkvb, Qsb16, Kntb16, Ub, Wb16, Atb16);
    scan_kernel<<<dim3(BH, 4), 256, 0, stream>>>(Qsb16, Kntb16, Ub, Wb16, Atb16, deltab);
    // FIR + mix + prune + gates + entropies (writes bf16 context directly)
    paths_kernel<<<dim3(1024), 256, 0, stream>>>(qkvb, deltab, idoutb, plig, gl,
                                                 mixw, id_st, firsT, firlT, ctxb, ent);
    // output projection
    gemm_mfma<<<dim3(6, 32), 256, 0, stream>>>(ctxb, wprojT, b_proj, out, BN, 768, 768);
    finalize_kernel<<<1, 256, 0, stream>>>(ent, out);
}